// Round 1
// baseline (11748.248 us; speedup 1.0000x reference)
//
#include <hip/hip_runtime.h>
#include <math.h>

#define LAYERS 6
#define BBATCH 2
#define TT 512
#define CC 768
#define HH 12
#define NHEAD 64
#define MT (BBATCH*TT)      // 1024 tokens
#define DW 64
#define DA 64
#define DV 32
#define DG 128
#define FF (4*CC)           // 3072

// ---------------- elementwise ----------------

__global__ __launch_bounds__(256) void copy_f(float* __restrict__ dst, const float* __restrict__ src) {
    size_t i = (size_t)blockIdx.x * 256 + threadIdx.x;
    dst[i] = src[i];
}

__global__ __launch_bounds__(256) void add_k(float* __restrict__ x, const float* __restrict__ y) {
    size_t i = (size_t)blockIdx.x * 256 + threadIdx.x;
    x[i] += y[i];
}

__global__ __launch_bounds__(256) void tanh_k(float* __restrict__ p) {
    size_t i = (size_t)blockIdx.x * 256 + threadIdx.x;
    p[i] = tanhf(p[i]);
}

__global__ __launch_bounds__(256) void sig_k(float* __restrict__ p) {
    size_t i = (size_t)blockIdx.x * 256 + threadIdx.x;
    p[i] = 1.f / (1.f + expf(-p[i]));
}

__global__ __launch_bounds__(256) void relusq_k(float* __restrict__ p) {
    size_t i = (size_t)blockIdx.x * 256 + threadIdx.x;
    float v = p[i];
    v = v > 0.f ? v : 0.f;
    p[i] = v * v;
}

// decay = exp(-exp(-softplus(-(w0 + in)) - 0.5))
__global__ __launch_bounds__(256) void wdecay_k(const float* __restrict__ in,
                                                const float* __restrict__ w0,
                                                float* __restrict__ dec) {
    size_t i = (size_t)blockIdx.x * 256 + threadIdx.x;
    int c = (int)(i % CC);
    float z  = w0[c] + in[i];
    float nz = -z;
    float sp = (nz > 20.f) ? nz : log1pf(expf(nz));   // softplus(-z), stable
    float w  = -sp - 0.5f;
    dec[i] = expf(-expf(w));
}

__global__ __launch_bounds__(256) void asig_k(const float* __restrict__ in,
                                              const float* __restrict__ a0,
                                              float* __restrict__ out) {
    size_t i = (size_t)blockIdx.x * 256 + threadIdx.x;
    int c = (int)(i % CC);
    out[i] = 1.f / (1.f + expf(-(a0[c] + in[i])));
}

// v = v + (v_first - v) * sigmoid(v0 + in)
__global__ __launch_bounds__(256) void vblend_k(float* __restrict__ v,
                                                const float* __restrict__ vf,
                                                const float* __restrict__ in,
                                                const float* __restrict__ v0) {
    size_t i = (size_t)blockIdx.x * 256 + threadIdx.x;
    int c = (int)(i % CC);
    float s  = 1.f / (1.f + expf(-(v0[c] + in[i])));
    float vv = v[i];
    v[i] = vv + (vf[i] - vv) * s;
}

// ---------------- layernorm (C=768, one row per 256-thread block) ----------------

__global__ __launch_bounds__(256) void ln_kernel(const float* __restrict__ x,
                                                 const float* __restrict__ w,
                                                 const float* __restrict__ b,
                                                 float* __restrict__ out) {
    int row = blockIdx.x;
    const float* xr = x + (size_t)row * CC;
    int t = threadIdx.x;
    float v0 = xr[t], v1 = xr[t + 256], v2 = xr[t + 512];
    float s  = v0 + v1 + v2;
    float sq = v0 * v0 + v1 * v1 + v2 * v2;
    for (int m = 1; m < 64; m <<= 1) { s += __shfl_xor(s, m); sq += __shfl_xor(sq, m); }
    __shared__ float ss[4], ssq[4];
    int wid = t >> 6;
    if ((t & 63) == 0) { ss[wid] = s; ssq[wid] = sq; }
    __syncthreads();
    s  = ss[0] + ss[1] + ss[2] + ss[3];
    sq = ssq[0] + ssq[1] + ssq[2] + ssq[3];
    float mean = s / (float)CC;
    float var  = sq / (float)CC - mean * mean;
    float inv  = rsqrtf(var + 1e-5f);
    float* orow = out + (size_t)row * CC;
    orow[t]       = (v0 - mean) * inv * w[t]       + b[t];
    orow[t + 256] = (v1 - mean) * inv * w[t + 256] + b[t + 256];
    orow[t + 512] = (v2 - mean) * inv * w[t + 512] + b[t + 512];
}

// ---------------- token-shift mixes ----------------

__global__ __launch_bounds__(256) void mix6_kernel(const float* __restrict__ xln,
    const float* __restrict__ m0, const float* __restrict__ m1, const float* __restrict__ m2,
    const float* __restrict__ m3, const float* __restrict__ m4, const float* __restrict__ m5,
    float* __restrict__ o0, float* __restrict__ o1, float* __restrict__ o2,
    float* __restrict__ o3, float* __restrict__ o4, float* __restrict__ o5) {
    size_t i = (size_t)blockIdx.x * 256 + threadIdx.x;
    int c = (int)(i % CC);
    size_t bt = i / CC;
    int t = (int)(bt % TT);
    float cur  = xln[i];
    float prev = (t == 0) ? 0.f : xln[i - CC];
    float d = prev - cur;
    o0[i] = cur + d * m0[c];
    o1[i] = cur + d * m1[c];
    o2[i] = cur + d * m2[c];
    o3[i] = cur + d * m3[c];
    o4[i] = cur + d * m4[c];
    o5[i] = cur + d * m5[c];
}

__global__ __launch_bounds__(256) void mixc_kernel(const float* __restrict__ xln,
                                                   const float* __restrict__ mu,
                                                   float* __restrict__ o) {
    size_t i = (size_t)blockIdx.x * 256 + threadIdx.x;
    int c = (int)(i % CC);
    size_t bt = i / CC;
    int t = (int)(bt % TT);
    float cur  = xln[i];
    float prev = (t == 0) ? 0.f : xln[i - CC];
    o[i] = cur + (prev - cur) * mu[c];
}

// ---------------- fp32 tiled GEMM: C[M,N] = A[M,K] @ B[K,N] ----------------
// 64x64 tile, K-tile 16, 256 threads, 4x4 per thread. K must be %16, M %64.

__global__ __launch_bounds__(256) void gemm64(const float* __restrict__ A,
                                              const float* __restrict__ Bw,
                                              float* __restrict__ Cm,
                                              int M, int K, int N) {
    __shared__ float As[16][65];
    __shared__ float Bs[16][65];
    int tid = threadIdx.x;
    int tx = tid & 15, ty = tid >> 4;
    int bn = blockIdx.x * 64, bm = blockIdx.y * 64;
    float acc[4][4] = {};
    for (int k0 = 0; k0 < K; k0 += 16) {
#pragma unroll
        for (int it = 0; it < 4; ++it) {
            int idx = tid + 256 * it;
            int r = idx >> 4, c = idx & 15;
            int gm = bm + r, gk = k0 + c;
            As[c][r] = (gm < M) ? A[(size_t)gm * K + gk] : 0.f;
        }
#pragma unroll
        for (int it = 0; it < 4; ++it) {
            int idx = tid + 256 * it;
            int r = idx >> 6, c = idx & 63;
            int gk = k0 + r, gn = bn + c;
            Bs[r][c] = (gn < N) ? Bw[(size_t)gk * N + gn] : 0.f;
        }
        __syncthreads();
#pragma unroll
        for (int kk = 0; kk < 16; ++kk) {
            float av[4], bv[4];
#pragma unroll
            for (int u = 0; u < 4; ++u) av[u] = As[kk][ty * 4 + u];
#pragma unroll
            for (int u = 0; u < 4; ++u) bv[u] = Bs[kk][tx * 4 + u];
#pragma unroll
            for (int u = 0; u < 4; ++u)
#pragma unroll
                for (int w = 0; w < 4; ++w) acc[u][w] += av[u] * bv[w];
        }
        __syncthreads();
    }
#pragma unroll
    for (int u = 0; u < 4; ++u) {
        int gm = bm + ty * 4 + u;
        if (gm >= M) continue;
#pragma unroll
        for (int w = 0; w < 4; ++w) {
            int gn = bn + tx * 4 + w;
            if (gn < N) Cm[(size_t)gm * N + gn] = acc[u][w];
        }
    }
}

// ---------------- kk normalize + k update, produce aa=-kk, bb=kk*a ----------------
// 4 heads per 256-thread block; one wave per (b,t,h); lane = n.

__global__ __launch_bounds__(256) void kk_kernel(float* __restrict__ k,
                                                 const float* __restrict__ a,
                                                 const float* __restrict__ kkw,
                                                 const float* __restrict__ kaw,
                                                 float* __restrict__ aaO,
                                                 float* __restrict__ bbO) {
    int hg   = blockIdx.x * 4 + (threadIdx.x >> 6);   // (b*T + t)*H + h
    int lane = threadIdx.x & 63;
    int bt = hg / HH, h = hg % HH;
    int c = h * 64 + lane;
    size_t off = (size_t)bt * CC + c;
    float kv = k[off];
    float av = a[off];
    float kkv = kv * kkw[c];
    float s = kkv * kkv;
    for (int m = 1; m < 64; m <<= 1) s += __shfl_xor(s, m);
    float inv = 1.f / fmaxf(sqrtf(s), 1e-12f);
    kkv *= inv;
    aaO[off] = -kkv;
    bbO[off] = kkv * av;
    k[off] = kv * (1.f + (av - 1.f) * kaw[c]);
}

// ---------------- wkv7 scan ----------------
// One block per (b,h). 256 threads: row i = tid>>2 (0..63), col group q = tid&3
// owns S[i][16q .. 16q+15] in registers. All 4 q-lanes of a row are in one wave.

__global__ __launch_bounds__(256) void wkv_kernel(const float* __restrict__ r,
                                                  const float* __restrict__ wdec,
                                                  const float* __restrict__ k,
                                                  const float* __restrict__ v,
                                                  const float* __restrict__ aa,
                                                  const float* __restrict__ bb,
                                                  float* __restrict__ y) {
    int bh = blockIdx.x;
    int b = bh / HH, h = bh % HH;
    int tid = threadIdx.x;
    int i = tid >> 2, q = tid & 3;
    float S[16];
#pragma unroll
    for (int j = 0; j < 16; ++j) S[j] = 0.f;
    __shared__ float sh[6][64];
    const size_t base = (size_t)b * TT * CC + (size_t)h * 64;
#pragma unroll 1
    for (int t = 0; t < TT; ++t) {
        size_t off = base + (size_t)t * CC;
        __syncthreads();  // previous iteration done reading sh
        if (tid < 64)        { sh[0][tid]     = r[off + tid];    sh[1][tid]     = wdec[off + tid]; }
        else if (tid < 128)  { int u = tid - 64;  sh[2][u] = k[off + u];  sh[3][u] = v[off + u]; }
        else if (tid < 192)  { int u = tid - 128; sh[4][u] = aa[off + u]; sh[5][u] = bb[off + u]; }
        __syncthreads();
        // sa_i = sum_j S[i][j] * aa[j]
        float part = 0.f;
#pragma unroll
        for (int j = 0; j < 16; ++j) part += S[j] * sh[4][q * 16 + j];
        part += __shfl_xor(part, 1);
        part += __shfl_xor(part, 2);
        float sa = part;
        float vi = sh[3][i];
        float yp = 0.f;
#pragma unroll
        for (int j = 0; j < 16; ++j) {
            int jj = q * 16 + j;
            float s = S[j] * sh[1][jj] + sa * sh[5][jj] + vi * sh[2][jj];
            S[j] = s;
            yp += s * sh[0][jj];
        }
        yp += __shfl_xor(yp, 1);
        yp += __shfl_xor(yp, 2);
        if (q == 0) y[off + i] = yp;
    }
}

// ---------------- groupnorm(heads) + bonus + multiply by g ----------------
// 4 heads per block; one wave per (b,t,h).

__global__ __launch_bounds__(256) void gnbonus_kernel(const float* __restrict__ y,
    const float* __restrict__ r, const float* __restrict__ k, const float* __restrict__ v,
    const float* __restrict__ rk, const float* __restrict__ lw, const float* __restrict__ lb,
    const float* __restrict__ g, float* __restrict__ out) {
    int hg   = blockIdx.x * 4 + (threadIdx.x >> 6);
    int lane = threadIdx.x & 63;
    int bt = hg / HH, h = hg % HH;
    int c = h * 64 + lane;
    size_t off = (size_t)bt * CC + c;
    float yv = y[off];
    float rv = r[off], kv = k[off], vv = v[off];
    float s1 = yv, s2 = yv * yv, s3 = rv * kv * rk[h * 64 + lane];
    for (int m = 1; m < 64; m <<= 1) {
        s1 += __shfl_xor(s1, m);
        s2 += __shfl_xor(s2, m);
        s3 += __shfl_xor(s3, m);
    }
    float mean = s1 * (1.f / 64.f);
    float var  = s2 * (1.f / 64.f) - mean * mean;
    float inv  = rsqrtf(var + 64e-5f);
    float val  = (yv - mean) * inv * lw[c] + lb[c] + s3 * vv;
    out[off] = val * g[off];
}

// ---------------- host ----------------

extern "C" void kernel_launch(void* const* d_in, const int* in_sizes, int n_in,
                              void* d_out, int out_size, void* d_ws, size_t ws_size,
                              hipStream_t stream) {
    (void)in_sizes; (void)n_in; (void)out_size;
    const float* x    = (const float*)d_in[0];
    const float* x_r  = (const float*)d_in[1];
    const float* x_w  = (const float*)d_in[2];
    const float* x_k  = (const float*)d_in[3];
    const float* x_v  = (const float*)d_in[4];
    const float* x_a  = (const float*)d_in[5];
    const float* x_g  = (const float*)d_in[6];
    const float* w0   = (const float*)d_in[7];
    const float* w1   = (const float*)d_in[8];
    const float* w2   = (const float*)d_in[9];
    const float* a0   = (const float*)d_in[10];
    const float* a1   = (const float*)d_in[11];
    const float* a2   = (const float*)d_in[12];
    const float* v0   = (const float*)d_in[13];
    const float* v1   = (const float*)d_in[14];
    const float* v2   = (const float*)d_in[15];
    const float* g1   = (const float*)d_in[16];
    const float* g2   = (const float*)d_in[17];
    const float* k_k  = (const float*)d_in[18];
    const float* k_a  = (const float*)d_in[19];
    const float* r_k  = (const float*)d_in[20];
    const float* W_r  = (const float*)d_in[21];
    const float* W_k  = (const float*)d_in[22];
    const float* W_v  = (const float*)d_in[23];
    const float* W_o  = (const float*)d_in[24];
    const float* ln_x_w = (const float*)d_in[25];
    const float* ln_x_b = (const float*)d_in[26];
    const float* ln1_w  = (const float*)d_in[27];
    const float* ln1_b  = (const float*)d_in[28];
    const float* ln2_w  = (const float*)d_in[29];
    const float* ln2_b  = (const float*)d_in[30];
    const float* c_x_k  = (const float*)d_in[31];
    const float* W_ck   = (const float*)d_in[32];
    const float* W_cv   = (const float*)d_in[33];

    const size_t MC = (size_t)MT * CC;
    float* ws = (float*)d_ws;
    size_t woff = 0;
    auto alloc = [&](size_t n) { float* p = ws + woff; woff += n; return p; };
    float* xln    = alloc(MC);
    float* mx0    = alloc(MC);
    float* mx1    = alloc(MC);
    float* mx2    = alloc(MC);
    float* mx3    = alloc(MC);
    float* mx4    = alloc(MC);
    float* mx5    = alloc(MC);
    float* rbuf   = alloc(MC);
    float* kbuf   = alloc(MC);
    float* vbuf   = alloc(MC);
    float* abuf   = alloc(MC);
    float* gbuf   = alloc(MC);
    float* dbuf   = alloc(MC);
    float* tmp_s  = alloc((size_t)MT * DG);
    float* tmp_c  = alloc(MC);
    float* aab    = alloc(MC);
    float* bbb    = alloc(MC);
    float* ybuf   = alloc(MC);
    float* attb   = alloc(MC);
    float* vfirst = alloc(MC);
    float* hbuf   = alloc((size_t)MT * FF);
    if (woff * sizeof(float) > ws_size) return;  // workspace too small: bail (visible as failure)

    float* xcur = (float*)d_out;
    copy_f<<<MC / 256, 256, 0, stream>>>(xcur, x);

    const int EW = (int)(MC / 256);          // elementwise grid over M*C
    const dim3 gC(CC / 64, MT / 64);         // 12 x 16

    for (int l = 0; l < LAYERS; ++l) {
        size_t oC  = (size_t)l * CC;
        size_t oCC = (size_t)l * CC * CC;

        // ---- time mix ----
        ln_kernel<<<MT, 256, 0, stream>>>(xcur, ln1_w + oC, ln1_b + oC, xln);
        mix6_kernel<<<EW, 256, 0, stream>>>(xln, x_r + oC, x_w + oC, x_k + oC,
                                            x_v + oC, x_a + oC, x_g + oC,
                                            mx0, mx1, mx2, mx3, mx4, mx5);
        gemm64<<<gC, 256, 0, stream>>>(mx0, W_r + oCC, rbuf, MT, CC, CC);
        gemm64<<<gC, 256, 0, stream>>>(mx2, W_k + oCC, kbuf, MT, CC, CC);
        gemm64<<<gC, 256, 0, stream>>>(mx3, W_v + oCC, vbuf, MT, CC, CC);
        // w (decay) path
        gemm64<<<dim3(1, MT / 64), 256, 0, stream>>>(mx1, w1 + (size_t)l * CC * DW, tmp_s, MT, CC, DW);
        tanh_k<<<MT * DW / 256, 256, 0, stream>>>(tmp_s);
        gemm64<<<gC, 256, 0, stream>>>(tmp_s, w2 + (size_t)l * DW * CC, tmp_c, MT, DW, CC);
        wdecay_k<<<EW, 256, 0, stream>>>(tmp_c, w0 + oC, dbuf);
        // a path
        gemm64<<<dim3(1, MT / 64), 256, 0, stream>>>(mx4, a1 + (size_t)l * CC * DA, tmp_s, MT, CC, DA);
        gemm64<<<gC, 256, 0, stream>>>(tmp_s, a2 + (size_t)l * DA * CC, tmp_c, MT, DA, CC);
        asig_k<<<EW, 256, 0, stream>>>(tmp_c, a0 + oC, abuf);
        // v path
        if (l == 0) {
            copy_f<<<EW, 256, 0, stream>>>(vfirst, vbuf);
        } else {
            gemm64<<<dim3(1, MT / 64), 256, 0, stream>>>(mx3, v1 + (size_t)l * CC * DV, tmp_s, MT, CC, DV);
            gemm64<<<gC, 256, 0, stream>>>(tmp_s, v2 + (size_t)l * DV * CC, tmp_c, MT, DV, CC);
            vblend_k<<<EW, 256, 0, stream>>>(vbuf, vfirst, tmp_c, v0 + oC);
        }
        // g path
        gemm64<<<dim3(DG / 64, MT / 64), 256, 0, stream>>>(mx5, g1 + (size_t)l * CC * DG, tmp_s, MT, CC, DG);
        sig_k<<<MT * DG / 256, 256, 0, stream>>>(tmp_s);
        gemm64<<<gC, 256, 0, stream>>>(tmp_s, g2 + (size_t)l * DG * CC, gbuf, MT, DG, CC);
        // kk / k update / aa,bb
        kk_kernel<<<MT * HH / 4, 256, 0, stream>>>(kbuf, abuf, k_k + oC, k_a + oC, aab, bbb);
        // sequential scan
        wkv_kernel<<<BBATCH * HH, 256, 0, stream>>>(rbuf, dbuf, kbuf, vbuf, aab, bbb, ybuf);
        // groupnorm + bonus + *g
        gnbonus_kernel<<<MT * HH / 4, 256, 0, stream>>>(ybuf, rbuf, kbuf, vbuf,
                                                        r_k + (size_t)l * HH * NHEAD,
                                                        ln_x_w + oC, ln_x_b + oC, gbuf, tmp_c);
        gemm64<<<gC, 256, 0, stream>>>(tmp_c, W_o + oCC, attb, MT, CC, CC);
        add_k<<<EW, 256, 0, stream>>>(xcur, attb);

        // ---- channel mix ----
        ln_kernel<<<MT, 256, 0, stream>>>(xcur, ln2_w + oC, ln2_b + oC, xln);
        mixc_kernel<<<EW, 256, 0, stream>>>(xln, c_x_k + oC, mx0);
        gemm64<<<dim3(FF / 64, MT / 64), 256, 0, stream>>>(mx0, W_ck + (size_t)l * CC * FF, hbuf, MT, CC, FF);
        relusq_k<<<MT * FF / 256, 256, 0, stream>>>(hbuf);
        gemm64<<<gC, 256, 0, stream>>>(hbuf, W_cv + (size_t)l * FF * CC, attb, MT, FF, CC);
        add_k<<<EW, 256, 0, stream>>>(xcur, attb);
    }
}

// Round 2
// 5439.811 us; speedup vs baseline: 2.1597x; 2.1597x over previous
//
#include <hip/hip_runtime.h>
#include <hip/hip_bf16.h>
#include <math.h>

#define LAYERS 6
#define BBATCH 2
#define TT 512
#define CC 768
#define HH 12
#define MT (BBATCH*TT)      // 1024 tokens
#define FF (4*CC)           // 3072

typedef __hip_bfloat16 bf16;
typedef __bf16 bf16x8 __attribute__((ext_vector_type(8)));
typedef float f32x4 __attribute__((ext_vector_type(4)));

__device__ inline bf16 f2b(float f) { return __float2bfloat16(f); }

__device__ inline float rl(float v, int l) {
    return __uint_as_float(__builtin_amdgcn_readlane(__float_as_uint(v), l));
}

// ---------------- small utility kernels ----------------

__global__ __launch_bounds__(256) void copy_f(float* __restrict__ dst, const float* __restrict__ src) {
    size_t i = (size_t)blockIdx.x * 256 + threadIdx.x;
    dst[i] = src[i];
}

// ---------------- layernorm (C=768, one row per 256-thread block) ----------------

__global__ __launch_bounds__(256) void ln_kernel(const float* __restrict__ x,
                                                 const float* __restrict__ w,
                                                 const float* __restrict__ b,
                                                 float* __restrict__ out) {
    int row = blockIdx.x;
    const float* xr = x + (size_t)row * CC;
    int t = threadIdx.x;
    float v0 = xr[t], v1 = xr[t + 256], v2 = xr[t + 512];
    float s  = v0 + v1 + v2;
    float sq = v0 * v0 + v1 * v1 + v2 * v2;
    for (int m = 1; m < 64; m <<= 1) { s += __shfl_xor(s, m); sq += __shfl_xor(sq, m); }
    __shared__ float ss[4], ssq[4];
    int wid = t >> 6;
    if ((t & 63) == 0) { ss[wid] = s; ssq[wid] = sq; }
    __syncthreads();
    s  = ss[0] + ss[1] + ss[2] + ss[3];
    sq = ssq[0] + ssq[1] + ssq[2] + ssq[3];
    float mean = s / (float)CC;
    float var  = sq / (float)CC - mean * mean;
    float inv  = rsqrtf(var + 1e-5f);
    float* orow = out + (size_t)row * CC;
    orow[t]       = (v0 - mean) * inv * w[t]       + b[t];
    orow[t + 256] = (v1 - mean) * inv * w[t + 256] + b[t + 256];
    orow[t + 512] = (v2 - mean) * inv * w[t + 512] + b[t + 512];
}

// ---------------- token-shift mixes (fp32 in, bf16 out) ----------------

__global__ __launch_bounds__(256) void mix6_kernel(const float* __restrict__ xln,
    const float* __restrict__ m0, const float* __restrict__ m1, const float* __restrict__ m2,
    const float* __restrict__ m3, const float* __restrict__ m4, const float* __restrict__ m5,
    bf16* __restrict__ o0, bf16* __restrict__ o1, bf16* __restrict__ o2,
    bf16* __restrict__ o3, bf16* __restrict__ o4, bf16* __restrict__ o5) {
    size_t i = (size_t)blockIdx.x * 256 + threadIdx.x;
    int c = (int)(i % CC);
    size_t bt = i / CC;
    int t = (int)(bt % TT);
    float cur  = xln[i];
    float prev = (t == 0) ? 0.f : xln[i - CC];
    float d = prev - cur;
    o0[i] = f2b(cur + d * m0[c]);
    o1[i] = f2b(cur + d * m1[c]);
    o2[i] = f2b(cur + d * m2[c]);
    o3[i] = f2b(cur + d * m3[c]);
    o4[i] = f2b(cur + d * m4[c]);
    o5[i] = f2b(cur + d * m5[c]);
}

__global__ __launch_bounds__(256) void mixc_kernel(const float* __restrict__ xln,
                                                   const float* __restrict__ mu,
                                                   bf16* __restrict__ o) {
    size_t i = (size_t)blockIdx.x * 256 + threadIdx.x;
    int c = (int)(i % CC);
    size_t bt = i / CC;
    int t = (int)(bt % TT);
    float cur  = xln[i];
    float prev = (t == 0) ? 0.f : xln[i - CC];
    o[i] = f2b(cur + (prev - cur) * mu[c]);
}

// ---------------- weight convert + transpose: W[K][N] f32 -> Wt[N][K] bf16 ----------------

struct WPtrs { const float* p[14]; };

__global__ __launch_bounds__(256) void convert_weights(WPtrs wp, bf16* __restrict__ dst) {
    const int KK_[14] = {768,768,768,768, 768,64, 768,64, 768,32, 768,128, 768,3072};
    const int NN_[14] = {768,768,768,768, 64,768, 64,768, 32,768, 128,768, 3072,768};
    const int OFF_[14] = {0,589824,1179648,1769472, 2359296,2408448, 2457600,2506752,
                          2555904,2580480, 2605056,2703360, 2801664,5160960};
    int m = blockIdx.y;
    int Kd = KK_[m], Nd = NN_[m];
    int ntn = Nd >> 5, ntk = Kd >> 5;
    int t = blockIdx.x;
    if (t >= ntn * ntk) return;
    int tn = (t % ntn) * 32, tk = (t / ntn) * 32;
    const float* src = wp.p[m];
    bf16* d = dst + OFF_[m];
    __shared__ float tile[32][33];
    int c = threadIdx.x & 31, r0 = threadIdx.x >> 5;
#pragma unroll
    for (int i = 0; i < 4; ++i) {
        int r = r0 + i * 8;
        tile[r][c] = src[(size_t)(tk + r) * Nd + tn + c];
    }
    __syncthreads();
#pragma unroll
    for (int i = 0; i < 4; ++i) {
        int r = r0 + i * 8;
        d[(size_t)(tn + r) * Kd + tk + c] = f2b(tile[c][r]);
    }
}

// ---------------- bf16 MFMA GEMM: C[M,N] = A[M,K] @ B[K,N], Bt given as [N][K] ----------------
// 256 threads = 4 waves (2x2). BK = 32. global_load_lds(16B) + (row&3) XOR swizzle.
// EPI: 0=f32, 1=bf16, 2=tanh->bf16, 3=sigmoid->bf16, 4=relu^2->bf16,
//      5=add-inplace f32, 6=wdecay f32 (p1=w0), 7=sigmoid(p1+.) f32, 8=vblend (p1=v0,p2=vfirst)

template<int BM, int BN, int EPI>
__global__ __launch_bounds__(256) void gemm_mfma(const __bf16* __restrict__ A,
                                                 const __bf16* __restrict__ Bt,
                                                 float* __restrict__ outF,
                                                 bf16* __restrict__ outH,
                                                 const float* __restrict__ p1,
                                                 const float* __restrict__ p2,
                                                 int M, int N, int K) {
    constexpr int FM = BM / 32, FN = BN / 32;
    constexpr int ABYTES = BM * 64;
    constexpr int TOT = (BM + BN) * 64;
    constexpr int NCHUNK = (TOT + 4095) / 4096;
    __shared__ char smem[2][TOT];
    int tid = threadIdx.x;
    int lane = tid & 63, wid = tid >> 6;
    int bm = blockIdx.y * BM, bn = blockIdx.x * BN;
    int wm = (wid >> 1) * (BM / 2), wn = (wid & 1) * (BN / 2);
    f32x4 acc[FM][FN];
#pragma unroll
    for (int i = 0; i < FM; ++i)
#pragma unroll
        for (int j = 0; j < FN; ++j) acc[i][j] = (f32x4){0.f, 0.f, 0.f, 0.f};

    int nk = K >> 5;

    auto stage = [&](int buf, int k0) {
        char* sb = &smem[buf][0];
#pragma unroll
        for (int c = 0; c < NCHUNK; ++c) {
            int d = c * 4096 + tid * 16;
            if (d < TOT) {
                int isB = d >= ABYTES;
                int dd = isB ? d - ABYTES : d;
                int row = dd >> 6;
                int u = (dd >> 4) & 3;
                int su = u ^ (row & 3);
                const __bf16* src = isB ? (Bt + (size_t)(bn + row) * K + k0 + su * 8)
                                        : (A  + (size_t)(bm + row) * K + k0 + su * 8);
                char* ldst = sb + c * 4096 + (tid & 192) * 16;  // wave-uniform base
                __builtin_amdgcn_global_load_lds(
                    (const __attribute__((address_space(1))) unsigned int*)src,
                    (__attribute__((address_space(3))) unsigned int*)ldst, 16, 0, 0);
            }
        }
    };

    stage(0, 0);
    __syncthreads();
    for (int t = 0; t < nk; ++t) {
        if (t + 1 < nk) stage((t + 1) & 1, (t + 1) * 32);
        const char* sA = &smem[t & 1][0];
        const char* sB = &smem[t & 1][ABYTES];
        int u = lane >> 4, r0 = lane & 15;
        bf16x8 af[FM], bfr[FN];
#pragma unroll
        for (int i = 0; i < FM; ++i) {
            int row = wm + i * 16 + r0;
            int su = u ^ (row & 3);
            af[i] = *(const bf16x8*)(sA + row * 64 + su * 16);
        }
#pragma unroll
        for (int j = 0; j < FN; ++j) {
            int row = wn + j * 16 + r0;
            int su = u ^ (row & 3);
            bfr[j] = *(const bf16x8*)(sB + row * 64 + su * 16);
        }
#pragma unroll
        for (int i = 0; i < FM; ++i)
#pragma unroll
            for (int j = 0; j < FN; ++j)
                acc[i][j] = __builtin_amdgcn_mfma_f32_16x16x32_bf16(af[i], bfr[j], acc[i][j], 0, 0, 0);
        __syncthreads();
    }

    // epilogue: C layout col = lane&15, row = (lane>>4)*4 + q
#pragma unroll
    for (int i = 0; i < FM; ++i) {
#pragma unroll
        for (int j = 0; j < FN; ++j) {
#pragma unroll
            for (int q = 0; q < 4; ++q) {
                int gm = bm + wm + i * 16 + (lane >> 4) * 4 + q;
                int gn = bn + wn + j * 16 + (lane & 15);
                size_t idx = (size_t)gm * N + gn;
                float v = acc[i][j][q];
                if constexpr (EPI == 0) {
                    outF[idx] = v;
                } else if constexpr (EPI == 1) {
                    outH[idx] = f2b(v);
                } else if constexpr (EPI == 2) {
                    outH[idx] = f2b(tanhf(v));
                } else if constexpr (EPI == 3) {
                    outH[idx] = f2b(1.f / (1.f + expf(-v)));
                } else if constexpr (EPI == 4) {
                    float r = fmaxf(v, 0.f);
                    outH[idx] = f2b(r * r);
                } else if constexpr (EPI == 5) {
                    outF[idx] += v;
                } else if constexpr (EPI == 6) {
                    float z = p1[gn] + v;
                    float nz = -z;
                    float sp = (nz > 20.f) ? nz : log1pf(expf(nz));
                    outF[idx] = expf(-expf(-sp - 0.5f));
                } else if constexpr (EPI == 7) {
                    outF[idx] = 1.f / (1.f + expf(-(p1[gn] + v)));
                } else if constexpr (EPI == 8) {
                    float vv = outF[idx];
                    float s = 1.f / (1.f + expf(-(p1[gn] + v)));
                    outF[idx] = vv + (p2[idx] - vv) * s;
                }
            }
        }
    }
}

// ---------------- kk normalize + k update ----------------

__global__ __launch_bounds__(256) void kk_kernel(float* __restrict__ k,
                                                 const float* __restrict__ a,
                                                 const float* __restrict__ kkw,
                                                 const float* __restrict__ kaw,
                                                 float* __restrict__ aaO,
                                                 float* __restrict__ bbO) {
    int hg   = blockIdx.x * 4 + (threadIdx.x >> 6);
    int lane = threadIdx.x & 63;
    int bt = hg / HH, h = hg % HH;
    int c = h * 64 + lane;
    size_t off = (size_t)bt * CC + c;
    float kv = k[off];
    float av = a[off];
    float kkv = kv * kkw[c];
    float s = kkv * kkv;
    for (int m = 1; m < 64; m <<= 1) s += __shfl_xor(s, m);
    float inv = 1.f / fmaxf(sqrtf(s), 1e-12f);
    kkv *= inv;
    aaO[off] = -kkv;
    bbO[off] = kkv * av;
    k[off] = kv * (1.f + (av - 1.f) * kaw[c]);
}

// ---------------- wkv7 scan: one wave per (b,h), row-per-lane, readlane broadcast ----------------

__global__ __launch_bounds__(64) void wkv_kernel(const float* __restrict__ r,
                                                 const float* __restrict__ wd,
                                                 const float* __restrict__ k,
                                                 const float* __restrict__ v,
                                                 const float* __restrict__ aa,
                                                 const float* __restrict__ bb,
                                                 float* __restrict__ y) {
    int bh = blockIdx.x;
    int b = bh / HH, h = bh % HH;
    int lane = threadIdx.x;
    size_t off = (size_t)b * TT * CC + (size_t)h * 64 + lane;
    float S[64];
#pragma unroll
    for (int j = 0; j < 64; ++j) S[j] = 0.f;
    float rv = r[off], wv = wd[off], kv = k[off], vv = v[off], av = aa[off], bv = bb[off];
    for (int t = 0; t < TT; ++t) {
        size_t noff = off + CC;
        float rn = 0.f, wn = 0.f, kn = 0.f, vn = 0.f, an = 0.f, bn2 = 0.f;
        if (t + 1 < TT) {
            rn = r[noff]; wn = wd[noff]; kn = k[noff];
            vn = v[noff]; an = aa[noff]; bn2 = bb[noff];
        }
        // sa_i = sum_j S[i][j] * a_j
        float s0 = 0.f, s1 = 0.f, s2 = 0.f, s3 = 0.f;
#pragma unroll
        for (int j = 0; j < 64; j += 4) {
            s0 = fmaf(S[j + 0], rl(av, j + 0), s0);
            s1 = fmaf(S[j + 1], rl(av, j + 1), s1);
            s2 = fmaf(S[j + 2], rl(av, j + 2), s2);
            s3 = fmaf(S[j + 3], rl(av, j + 3), s3);
        }
        float sa = (s0 + s1) + (s2 + s3);
        float y0 = 0.f, y1 = 0.f, y2 = 0.f, y3 = 0.f;
#pragma unroll
        for (int j = 0; j < 64; j += 4) {
            {
                float sn = fmaf(S[j + 0], rl(wv, j + 0), fmaf(sa, rl(bv, j + 0), vv * rl(kv, j + 0)));
                S[j + 0] = sn; y0 = fmaf(sn, rl(rv, j + 0), y0);
            }
            {
                float sn = fmaf(S[j + 1], rl(wv, j + 1), fmaf(sa, rl(bv, j + 1), vv * rl(kv, j + 1)));
                S[j + 1] = sn; y1 = fmaf(sn, rl(rv, j + 1), y1);
            }
            {
                float sn = fmaf(S[j + 2], rl(wv, j + 2), fmaf(sa, rl(bv, j + 2), vv * rl(kv, j + 2)));
                S[j + 2] = sn; y2 = fmaf(sn, rl(rv, j + 2), y2);
            }
            {
                float sn = fmaf(S[j + 3], rl(wv, j + 3), fmaf(sa, rl(bv, j + 3), vv * rl(kv, j + 3)));
                S[j + 3] = sn; y3 = fmaf(sn, rl(rv, j + 3), y3);
            }
        }
        y[off] = (y0 + y1) + (y2 + y3);
        off = noff;
        rv = rn; wv = wn; kv = kn; vv = vn; av = an; bv = bn2;
    }
}

// ---------------- groupnorm(heads) + bonus + *g  (bf16 out) ----------------

__global__ __launch_bounds__(256) void gnbonus_kernel(const float* __restrict__ y,
    const float* __restrict__ r, const float* __restrict__ k, const float* __restrict__ v,
    const float* __restrict__ rk, const float* __restrict__ lw, const float* __restrict__ lb,
    const float* __restrict__ g, bf16* __restrict__ out) {
    int hg   = blockIdx.x * 4 + (threadIdx.x >> 6);
    int lane = threadIdx.x & 63;
    int bt = hg / HH, h = hg % HH;
    int c = h * 64 + lane;
    size_t off = (size_t)bt * CC + c;
    float yv = y[off];
    float rv = r[off], kv = k[off], vv = v[off];
    float s1 = yv, s2 = yv * yv, s3 = rv * kv * rk[h * 64 + lane];
    for (int m = 1; m < 64; m <<= 1) {
        s1 += __shfl_xor(s1, m);
        s2 += __shfl_xor(s2, m);
        s3 += __shfl_xor(s3, m);
    }
    float mean = s1 * (1.f / 64.f);
    float var  = s2 * (1.f / 64.f) - mean * mean;
    float inv  = rsqrtf(var + 64e-5f);
    float val  = (yv - mean) * inv * lw[c] + lb[c] + s3 * vv;
    out[off] = f2b(val * g[off]);
}

// ---------------- host ----------------

extern "C" void kernel_launch(void* const* d_in, const int* in_sizes, int n_in,
                              void* d_out, int out_size, void* d_ws, size_t ws_size,
                              hipStream_t stream) {
    (void)in_sizes; (void)n_in; (void)out_size;
    const float* x    = (const float*)d_in[0];
    const float* x_r  = (const float*)d_in[1];
    const float* x_w  = (const float*)d_in[2];
    const float* x_k  = (const float*)d_in[3];
    const float* x_v  = (const float*)d_in[4];
    const float* x_a  = (const float*)d_in[5];
    const float* x_g  = (const float*)d_in[6];
    const float* w0   = (const float*)d_in[7];
    const float* w1   = (const float*)d_in[8];
    const float* w2   = (const float*)d_in[9];
    const float* a0   = (const float*)d_in[10];
    const float* a1   = (const float*)d_in[11];
    const float* a2   = (const float*)d_in[12];
    const float* v0   = (const float*)d_in[13];
    const float* v1   = (const float*)d_in[14];
    const float* v2   = (const float*)d_in[15];
    const float* g1   = (const float*)d_in[16];
    const float* g2   = (const float*)d_in[17];
    const float* k_k  = (const float*)d_in[18];
    const float* k_a  = (const float*)d_in[19];
    const float* r_k  = (const float*)d_in[20];
    const float* W_r  = (const float*)d_in[21];
    const float* W_k  = (const float*)d_in[22];
    const float* W_v  = (const float*)d_in[23];
    const float* W_o  = (const float*)d_in[24];
    const float* ln_x_w = (const float*)d_in[25];
    const float* ln_x_b = (const float*)d_in[26];
    const float* ln1_w  = (const float*)d_in[27];
    const float* ln1_b  = (const float*)d_in[28];
    const float* ln2_w  = (const float*)d_in[29];
    const float* ln2_b  = (const float*)d_in[30];
    const float* c_x_k  = (const float*)d_in[31];
    const float* W_ck   = (const float*)d_in[32];
    const float* W_cv   = (const float*)d_in[33];

    const size_t MC = (size_t)MT * CC;
    char* wsb = (char*)d_ws;
    size_t woff = 0;
    auto alloc = [&](size_t bytes) -> void* {
        void* p = wsb + woff;
        woff += (bytes + 255) & ~(size_t)255;
        return p;
    };
    // bf16 weight arena (per-layer, reused)
    const size_t WPL = 7520256;  // elements per layer
    bf16* wbf = (bf16*)alloc(WPL * sizeof(bf16));
    // bf16 activations
    bf16* mx0 = (bf16*)alloc(MC * 2);
    bf16* mx1 = (bf16*)alloc(MC * 2);
    bf16* mx2 = (bf16*)alloc(MC * 2);
    bf16* mx3 = (bf16*)alloc(MC * 2);
    bf16* mx4 = (bf16*)alloc(MC * 2);
    bf16* mx5 = (bf16*)alloc(MC * 2);
    bf16* tmp_s = (bf16*)alloc((size_t)MT * 128 * 2);
    bf16* hbuf  = (bf16*)alloc((size_t)MT * FF * 2);
    bf16* ghout = (bf16*)alloc(MC * 2);
    // fp32 buffers
    float* xln    = (float*)alloc(MC * 4);
    float* rbuf   = (float*)alloc(MC * 4);
    float* kbuf   = (float*)alloc(MC * 4);
    float* vbuf   = (float*)alloc(MC * 4);
    float* abuf   = (float*)alloc(MC * 4);
    float* gbuf   = (float*)alloc(MC * 4);
    float* dbuf   = (float*)alloc(MC * 4);
    float* aab    = (float*)alloc(MC * 4);
    float* bbb    = (float*)alloc(MC * 4);
    float* ybuf   = (float*)alloc(MC * 4);
    float* vfirst = (float*)alloc(MC * 4);
    if (woff > ws_size) return;

    float* xcur = (float*)d_out;
    copy_f<<<MC / 256, 256, 0, stream>>>(xcur, x);

    // transposed-bf16 weight pointers inside the arena
    const __bf16* Wr_t  = (const __bf16*)(wbf + 0);
    const __bf16* Wk_t  = (const __bf16*)(wbf + 589824);
    const __bf16* Wv_t  = (const __bf16*)(wbf + 1179648);
    const __bf16* Wo_t  = (const __bf16*)(wbf + 1769472);
    const __bf16* w1_t  = (const __bf16*)(wbf + 2359296);
    const __bf16* w2_t  = (const __bf16*)(wbf + 2408448);
    const __bf16* a1_t  = (const __bf16*)(wbf + 2457600);
    const __bf16* a2_t  = (const __bf16*)(wbf + 2506752);
    const __bf16* v1_t  = (const __bf16*)(wbf + 2555904);
    const __bf16* v2_t  = (const __bf16*)(wbf + 2580480);
    const __bf16* g1_t  = (const __bf16*)(wbf + 2605056);
    const __bf16* g2_t  = (const __bf16*)(wbf + 2703360);
    const __bf16* Wck_t = (const __bf16*)(wbf + 2801664);
    const __bf16* Wcv_t = (const __bf16*)(wbf + 5160960);

    const int EW = (int)(MC / 256);

    for (int l = 0; l < LAYERS; ++l) {
        size_t oC = (size_t)l * CC;

        // convert this layer's weights to bf16 transposed
        WPtrs wp;
        wp.p[0]  = W_r  + (size_t)l * CC * CC;
        wp.p[1]  = W_k  + (size_t)l * CC * CC;
        wp.p[2]  = W_v  + (size_t)l * CC * CC;
        wp.p[3]  = W_o  + (size_t)l * CC * CC;
        wp.p[4]  = w1   + (size_t)l * CC * 64;
        wp.p[5]  = w2   + (size_t)l * 64 * CC;
        wp.p[6]  = a1   + (size_t)l * CC * 64;
        wp.p[7]  = a2   + (size_t)l * 64 * CC;
        wp.p[8]  = v1   + (size_t)l * CC * 32;
        wp.p[9]  = v2   + (size_t)l * 32 * CC;
        wp.p[10] = g1   + (size_t)l * CC * 128;
        wp.p[11] = g2   + (size_t)l * 128 * CC;
        wp.p[12] = W_ck + (size_t)l * CC * FF;
        wp.p[13] = W_cv + (size_t)l * FF * CC;
        convert_weights<<<dim3(2304, 14), 256, 0, stream>>>(wp, wbf);

        float* vptr = (l == 0) ? vfirst : vbuf;

        // ---- time mix ----
        ln_kernel<<<MT, 256, 0, stream>>>(xcur, ln1_w + oC, ln1_b + oC, xln);
        mix6_kernel<<<EW, 256, 0, stream>>>(xln, x_r + oC, x_w + oC, x_k + oC,
                                            x_v + oC, x_a + oC, x_g + oC,
                                            mx0, mx1, mx2, mx3, mx4, mx5);
        gemm_mfma<128, 128, 0><<<dim3(6, 8), 256, 0, stream>>>((const __bf16*)mx0, Wr_t, rbuf, nullptr, nullptr, nullptr, MT, CC, CC);
        gemm_mfma<128, 128, 0><<<dim3(6, 8), 256, 0, stream>>>((const __bf16*)mx2, Wk_t, kbuf, nullptr, nullptr, nullptr, MT, CC, CC);
        gemm_mfma<128, 128, 0><<<dim3(6, 8), 256, 0, stream>>>((const __bf16*)mx3, Wv_t, vptr, nullptr, nullptr, nullptr, MT, CC, CC);
        // w (decay) path
        gemm_mfma<64, 64, 2><<<dim3(1, 16), 256, 0, stream>>>((const __bf16*)mx1, w1_t, nullptr, tmp_s, nullptr, nullptr, MT, 64, CC);
        gemm_mfma<128, 128, 6><<<dim3(6, 8), 256, 0, stream>>>((const __bf16*)tmp_s, w2_t, dbuf, nullptr, w0 + oC, nullptr, MT, CC, 64);
        // a path
        gemm_mfma<64, 64, 1><<<dim3(1, 16), 256, 0, stream>>>((const __bf16*)mx4, a1_t, nullptr, tmp_s, nullptr, nullptr, MT, 64, CC);
        gemm_mfma<128, 128, 7><<<dim3(6, 8), 256, 0, stream>>>((const __bf16*)tmp_s, a2_t, abuf, nullptr, a0 + oC, nullptr, MT, CC, 64);
        // v blend path
        if (l > 0) {
            gemm_mfma<64, 32, 1><<<dim3(1, 16), 256, 0, stream>>>((const __bf16*)mx3, v1_t, nullptr, tmp_s, nullptr, nullptr, MT, 32, CC);
            gemm_mfma<128, 128, 8><<<dim3(6, 8), 256, 0, stream>>>((const __bf16*)tmp_s, v2_t, vbuf, nullptr, v0 + oC, vfirst, MT, CC, 32);
        }
        // g path
        gemm_mfma<64, 64, 3><<<dim3(2, 16), 256, 0, stream>>>((const __bf16*)mx5, g1_t, nullptr, tmp_s, nullptr, nullptr, MT, 128, CC);
        gemm_mfma<128, 128, 0><<<dim3(6, 8), 256, 0, stream>>>((const __bf16*)tmp_s, g2_t, gbuf, nullptr, nullptr, nullptr, MT, CC, 128);
        // kk / k update
        kk_kernel<<<MT * HH / 4, 256, 0, stream>>>(kbuf, abuf, k_k + oC, k_a + oC, aab, bbb);
        // scan
        wkv_kernel<<<BBATCH * HH, 64, 0, stream>>>(rbuf, dbuf, kbuf, vptr, aab, bbb, ybuf);
        // groupnorm + bonus + *g
        gnbonus_kernel<<<MT * HH / 4, 256, 0, stream>>>(ybuf, rbuf, kbuf, vptr,
                                                        r_k + (size_t)l * CC,
                                                        ln_x_w + oC, ln_x_b + oC, gbuf, ghout);
        gemm_mfma<128, 128, 5><<<dim3(6, 8), 256, 0, stream>>>((const __bf16*)ghout, Wo_t, xcur, nullptr, nullptr, nullptr, MT, CC, CC);

        // ---- channel mix ----
        ln_kernel<<<MT, 256, 0, stream>>>(xcur, ln2_w + oC, ln2_b + oC, xln);
        mixc_kernel<<<EW, 256, 0, stream>>>(xln, c_x_k + oC, mx0);
        gemm_mfma<128, 128, 4><<<dim3(24, 8), 256, 0, stream>>>((const __bf16*)mx0, Wck_t, nullptr, hbuf, nullptr, nullptr, MT, FF, CC);
        gemm_mfma<128, 128, 5><<<dim3(6, 8), 256, 0, stream>>>((const __bf16*)hbuf, Wcv_t, xcur, nullptr, nullptr, nullptr, MT, CC, FF);
    }
}

// Round 3
// 2763.084 us; speedup vs baseline: 4.2519x; 1.9687x over previous
//
#include <hip/hip_runtime.h>
#include <hip/hip_bf16.h>
#include <math.h>

#define LAYERS 6
#define BBATCH 2
#define TT 512
#define CC 768
#define HH 12
#define MT (BBATCH*TT)      // 1024 tokens
#define FF (4*CC)           // 3072
#define LCH 32
#define NC (TT/LCH)         // 16 chunks
#define BH (BBATCH*HH)      // 24
#define SPAD 68

typedef __hip_bfloat16 bf16;
typedef __bf16 bf16x8 __attribute__((ext_vector_type(8)));
typedef float f32x4 __attribute__((ext_vector_type(4)));

__device__ inline bf16 f2b(float f) { return __float2bfloat16(f); }

// ---------------- small utility kernels ----------------

__global__ __launch_bounds__(256) void copy_f(float* __restrict__ dst, const float* __restrict__ src) {
    size_t i = (size_t)blockIdx.x * 256 + threadIdx.x;
    dst[i] = src[i];
}

// ---------------- layernorm ----------------

__global__ __launch_bounds__(256) void ln_kernel(const float* __restrict__ x,
                                                 const float* __restrict__ w,
                                                 const float* __restrict__ b,
                                                 float* __restrict__ out) {
    int row = blockIdx.x;
    const float* xr = x + (size_t)row * CC;
    int t = threadIdx.x;
    float v0 = xr[t], v1 = xr[t + 256], v2 = xr[t + 512];
    float s  = v0 + v1 + v2;
    float sq = v0 * v0 + v1 * v1 + v2 * v2;
    for (int m = 1; m < 64; m <<= 1) { s += __shfl_xor(s, m); sq += __shfl_xor(sq, m); }
    __shared__ float ss[4], ssq[4];
    int wid = t >> 6;
    if ((t & 63) == 0) { ss[wid] = s; ssq[wid] = sq; }
    __syncthreads();
    s  = ss[0] + ss[1] + ss[2] + ss[3];
    sq = ssq[0] + ssq[1] + ssq[2] + ssq[3];
    float mean = s / (float)CC;
    float var  = sq / (float)CC - mean * mean;
    float inv  = rsqrtf(var + 1e-5f);
    float* orow = out + (size_t)row * CC;
    orow[t]       = (v0 - mean) * inv * w[t]       + b[t];
    orow[t + 256] = (v1 - mean) * inv * w[t + 256] + b[t + 256];
    orow[t + 512] = (v2 - mean) * inv * w[t + 512] + b[t + 512];
}

// ---------------- token-shift mixes (fp32 in, bf16 out) ----------------

__global__ __launch_bounds__(256) void mix6_kernel(const float* __restrict__ xln,
    const float* __restrict__ m0, const float* __restrict__ m1, const float* __restrict__ m2,
    const float* __restrict__ m3, const float* __restrict__ m4, const float* __restrict__ m5,
    bf16* __restrict__ o0, bf16* __restrict__ o1, bf16* __restrict__ o2,
    bf16* __restrict__ o3, bf16* __restrict__ o4, bf16* __restrict__ o5) {
    size_t i = (size_t)blockIdx.x * 256 + threadIdx.x;
    int c = (int)(i % CC);
    size_t bt = i / CC;
    int t = (int)(bt % TT);
    float cur  = xln[i];
    float prev = (t == 0) ? 0.f : xln[i - CC];
    float d = prev - cur;
    o0[i] = f2b(cur + d * m0[c]);
    o1[i] = f2b(cur + d * m1[c]);
    o2[i] = f2b(cur + d * m2[c]);
    o3[i] = f2b(cur + d * m3[c]);
    o4[i] = f2b(cur + d * m4[c]);
    o5[i] = f2b(cur + d * m5[c]);
}

__global__ __launch_bounds__(256) void mixc_kernel(const float* __restrict__ xln,
                                                   const float* __restrict__ mu,
                                                   bf16* __restrict__ o) {
    size_t i = (size_t)blockIdx.x * 256 + threadIdx.x;
    int c = (int)(i % CC);
    size_t bt = i / CC;
    int t = (int)(bt % TT);
    float cur  = xln[i];
    float prev = (t == 0) ? 0.f : xln[i - CC];
    o[i] = f2b(cur + (prev - cur) * mu[c]);
}

// ---------------- weight convert + transpose: W[K][N] f32 -> Wt[N][K] bf16 ----------------

struct WPtrs { const float* p[14]; };

__global__ __launch_bounds__(256) void convert_weights(WPtrs wp, bf16* __restrict__ dst) {
    const int KK_[14] = {768,768,768,768, 768,64, 768,64, 768,32, 768,128, 768,3072};
    const int NN_[14] = {768,768,768,768, 64,768, 64,768, 32,768, 128,768, 3072,768};
    const int OFF_[14] = {0,589824,1179648,1769472, 2359296,2408448, 2457600,2506752,
                          2555904,2580480, 2605056,2703360, 2801664,5160960};
    int m = blockIdx.y;
    int Kd = KK_[m], Nd = NN_[m];
    int ntn = Nd >> 5, ntk = Kd >> 5;
    int t = blockIdx.x;
    if (t >= ntn * ntk) return;
    int tn = (t % ntn) * 32, tk = (t / ntn) * 32;
    const float* src = wp.p[m];
    bf16* d = dst + OFF_[m];
    __shared__ float tile[32][33];
    int c = threadIdx.x & 31, r0 = threadIdx.x >> 5;
#pragma unroll
    for (int i = 0; i < 4; ++i) {
        int r = r0 + i * 8;
        tile[r][c] = src[(size_t)(tk + r) * Nd + tn + c];
    }
    __syncthreads();
#pragma unroll
    for (int i = 0; i < 4; ++i) {
        int r = r0 + i * 8;
        d[(size_t)(tn + r) * Kd + tk + c] = f2b(tile[c][r]);
    }
}

// ---------------- bf16 MFMA GEMM (unchanged from round 2) ----------------

template<int BM, int BN, int EPI>
__global__ __launch_bounds__(256) void gemm_mfma(const __bf16* __restrict__ A,
                                                 const __bf16* __restrict__ Bt,
                                                 float* __restrict__ outF,
                                                 bf16* __restrict__ outH,
                                                 const float* __restrict__ p1,
                                                 const float* __restrict__ p2,
                                                 int M, int N, int K) {
    constexpr int FM = BM / 32, FN = BN / 32;
    constexpr int ABYTES = BM * 64;
    constexpr int TOT = (BM + BN) * 64;
    constexpr int NCHUNK = (TOT + 4095) / 4096;
    __shared__ char smem[2][TOT];
    int tid = threadIdx.x;
    int lane = tid & 63, wid = tid >> 6;
    int bm = blockIdx.y * BM, bn = blockIdx.x * BN;
    int wm = (wid >> 1) * (BM / 2), wn = (wid & 1) * (BN / 2);
    f32x4 acc[FM][FN];
#pragma unroll
    for (int i = 0; i < FM; ++i)
#pragma unroll
        for (int j = 0; j < FN; ++j) acc[i][j] = (f32x4){0.f, 0.f, 0.f, 0.f};

    int nk = K >> 5;

    auto stage = [&](int buf, int k0) {
        char* sb = &smem[buf][0];
#pragma unroll
        for (int c = 0; c < NCHUNK; ++c) {
            int d = c * 4096 + tid * 16;
            if (d < TOT) {
                int isB = d >= ABYTES;
                int dd = isB ? d - ABYTES : d;
                int row = dd >> 6;
                int u = (dd >> 4) & 3;
                int su = u ^ (row & 3);
                const __bf16* src = isB ? (Bt + (size_t)(bn + row) * K + k0 + su * 8)
                                        : (A  + (size_t)(bm + row) * K + k0 + su * 8);
                char* ldst = sb + c * 4096 + (tid & 192) * 16;
                __builtin_amdgcn_global_load_lds(
                    (const __attribute__((address_space(1))) unsigned int*)src,
                    (__attribute__((address_space(3))) unsigned int*)ldst, 16, 0, 0);
            }
        }
    };

    stage(0, 0);
    __syncthreads();
    for (int t = 0; t < nk; ++t) {
        if (t + 1 < nk) stage((t + 1) & 1, (t + 1) * 32);
        const char* sA = &smem[t & 1][0];
        const char* sB = &smem[t & 1][ABYTES];
        int u = lane >> 4, r0 = lane & 15;
        bf16x8 af[FM], bfr[FN];
#pragma unroll
        for (int i = 0; i < FM; ++i) {
            int row = wm + i * 16 + r0;
            int su = u ^ (row & 3);
            af[i] = *(const bf16x8*)(sA + row * 64 + su * 16);
        }
#pragma unroll
        for (int j = 0; j < FN; ++j) {
            int row = wn + j * 16 + r0;
            int su = u ^ (row & 3);
            bfr[j] = *(const bf16x8*)(sB + row * 64 + su * 16);
        }
#pragma unroll
        for (int i = 0; i < FM; ++i)
#pragma unroll
            for (int j = 0; j < FN; ++j)
                acc[i][j] = __builtin_amdgcn_mfma_f32_16x16x32_bf16(af[i], bfr[j], acc[i][j], 0, 0, 0);
        __syncthreads();
    }

#pragma unroll
    for (int i = 0; i < FM; ++i) {
#pragma unroll
        for (int j = 0; j < FN; ++j) {
#pragma unroll
            for (int q = 0; q < 4; ++q) {
                int gm = bm + wm + i * 16 + (lane >> 4) * 4 + q;
                int gn = bn + wn + j * 16 + (lane & 15);
                size_t idx = (size_t)gm * N + gn;
                float v = acc[i][j][q];
                if constexpr (EPI == 0) {
                    outF[idx] = v;
                } else if constexpr (EPI == 1) {
                    outH[idx] = f2b(v);
                } else if constexpr (EPI == 2) {
                    outH[idx] = f2b(tanhf(v));
                } else if constexpr (EPI == 3) {
                    outH[idx] = f2b(1.f / (1.f + expf(-v)));
                } else if constexpr (EPI == 4) {
                    float r = fmaxf(v, 0.f);
                    outH[idx] = f2b(r * r);
                } else if constexpr (EPI == 5) {
                    outF[idx] += v;
                } else if constexpr (EPI == 6) {
                    float z = p1[gn] + v;
                    float nz = -z;
                    float sp = (nz > 20.f) ? nz : log1pf(expf(nz));
                    outF[idx] = expf(-expf(-sp - 0.5f));
                } else if constexpr (EPI == 7) {
                    outF[idx] = 1.f / (1.f + expf(-(p1[gn] + v)));
                } else if constexpr (EPI == 8) {
                    float vv = outF[idx];
                    float s = 1.f / (1.f + expf(-(p1[gn] + v)));
                    outF[idx] = vv + (p2[idx] - vv) * s;
                }
            }
        }
    }
}

// ---------------- kk normalize + k update ----------------

__global__ __launch_bounds__(256) void kk_kernel(float* __restrict__ k,
                                                 const float* __restrict__ a,
                                                 const float* __restrict__ kkw,
                                                 const float* __restrict__ kaw,
                                                 float* __restrict__ aaO,
                                                 float* __restrict__ bbO) {
    int hg   = blockIdx.x * 4 + (threadIdx.x >> 6);
    int lane = threadIdx.x & 63;
    int bt = hg / HH, h = hg % HH;
    int c = h * 64 + lane;
    size_t off = (size_t)bt * CC + c;
    float kv = k[off];
    float av = a[off];
    float kkv = kv * kkw[c];
    float s = kkv * kkv;
    for (int m = 1; m < 64; m <<= 1) s += __shfl_xor(s, m);
    float inv = 1.f / fmaxf(sqrtf(s), 1e-12f);
    kkv *= inv;
    aaO[off] = -kkv;
    bbO[off] = kkv * av;
    k[off] = kv * (1.f + (av - 1.f) * kaw[c]);
}

// ---------------- chunked WKV7, phase A: intra-chunk (fully parallel) ----------------
// Per (b,h,chunk): d = cumprod(w); Ahat=a*d_prev; Bhat=b/d; Khat=k/d; Rhat=r*d.
// G matrices (32x32): Gba/Gka strict-lower, Grb/Grk inclusive-lower.
// U = (I-Gba)^-1 Ahat (in place), Q = (I-Gba)^-1 (Gka V) (in place).
// Outputs: Yintra = Grk V + Grb Q; Zr = Rhat + Grb U;
//          M = diag(dL) + U^T (Bhat*dL); Zc = V^T (Khat*dL) + Q^T (Bhat*dL).

__global__ __launch_bounds__(256) void chunkA_kernel(
    const float* __restrict__ r, const float* __restrict__ wd,
    const float* __restrict__ k, const float* __restrict__ v,
    const float* __restrict__ aa, const float* __restrict__ bb,
    float* __restrict__ yintra, float* __restrict__ zrO,
    float* __restrict__ mmO, float* __restrict__ zcO) {
    int c = blockIdx.x, bh = blockIdx.y;
    int b = bh / HH, h = bh % HH;
    __shared__ float Di[LCH][SPAD];
    __shared__ float Ah[LCH][SPAD];   // Ahat -> U (in place)
    __shared__ float Bh[LCH][SPAD];
    __shared__ float Kh[LCH][SPAD];
    __shared__ float Rh[LCH][SPAD];
    __shared__ float Vt[LCH][SPAD];
    __shared__ float Qm[LCH][SPAD];   // GkaV -> Q (in place)
    __shared__ float Gba[LCH][LCH], Gka[LCH][LCH], Grb[LCH][LCH], Grk[LCH][LCH];
    int tid = threadIdx.x;
    int n = tid & 63, tq = tid >> 6;
    size_t base = ((size_t)(b * TT + c * LCH)) * CC + h * 64 + n;
#pragma unroll
    for (int e = 0; e < 8; ++e) {
        int t = tq * 8 + e;
        size_t off = base + (size_t)t * CC;
        Di[t][n] = wd[off];
        Ah[t][n] = aa[off];
        Bh[t][n] = bb[off];
        Kh[t][n] = k[off];
        Rh[t][n] = r[off];
        Vt[t][n] = v[off];
    }
    __syncthreads();
    if (tid < 64) {
        float d = 1.f;
        for (int t = 0; t < LCH; ++t) { d *= Di[t][tid]; Di[t][tid] = d; }
    }
    __syncthreads();
#pragma unroll
    for (int e = 0; e < 8; ++e) {
        int t = tq * 8 + e;
        float di = Di[t][n];
        float dp = (t == 0) ? 1.f : Di[t - 1][n];
        float inv = 1.f / di;
        Ah[t][n] *= dp;
        Bh[t][n] *= inv;
        Kh[t][n] *= inv;
        Rh[t][n] *= di;
    }
    __syncthreads();
    // G matrices
#pragma unroll
    for (int e = 0; e < 4; ++e) {
        int idx = tid + e * 256;
        int t = idx >> 5, s = idx & 31;
        float dba = 0.f, dka = 0.f, drb = 0.f, drk = 0.f;
        for (int j = 0; j < 64; ++j) {
            float at = Ah[t][j], rt = Rh[t][j];
            float bs = Bh[s][j], ks = Kh[s][j];
            dba = fmaf(at, bs, dba); dka = fmaf(at, ks, dka);
            drb = fmaf(rt, bs, drb); drk = fmaf(rt, ks, drk);
        }
        Gba[t][s] = (s < t)  ? dba : 0.f;
        Gka[t][s] = (s < t)  ? dka : 0.f;
        Grb[t][s] = (s <= t) ? drb : 0.f;
        Grk[t][s] = (s <= t) ? drk : 0.f;
    }
    __syncthreads();
    // P = Gka V -> Qm
#pragma unroll
    for (int e = 0; e < 8; ++e) {
        int t = tq * 8 + e;
        float acc = 0.f;
        for (int s = 0; s < LCH; ++s) acc = fmaf(Gka[t][s], Vt[s][n], acc);
        Qm[t][n] = acc;
    }
    __syncthreads();
    // forward substitution, in place: wave0 -> U in Ah, wave1 -> Q in Qm
    if (tq == 0) {
        for (int t = 1; t < LCH; ++t) {
            float acc = Ah[t][n];
            for (int s = 0; s < t; ++s) acc = fmaf(Gba[t][s], Ah[s][n], acc);
            Ah[t][n] = acc;
        }
    } else if (tq == 1) {
        for (int t = 1; t < LCH; ++t) {
            float acc = Qm[t][n];
            for (int s = 0; s < t; ++s) acc = fmaf(Gba[t][s], Qm[s][n], acc);
            Qm[t][n] = acc;
        }
    }
    __syncthreads();
    float dL_n = Di[LCH - 1][n];
    size_t obase = ((size_t)(bh * NC + c)) * LCH * 64;
#pragma unroll
    for (int e = 0; e < 8; ++e) {
        int t = tq * 8 + e;
        float accY = 0.f, accZ = Rh[t][n];
        for (int s = 0; s < LCH; ++s) {
            accY = fmaf(Grk[t][s], Vt[s][n], accY);
            accY = fmaf(Grb[t][s], Qm[s][n], accY);
            accZ = fmaf(Grb[t][s], Ah[s][n], accZ);
        }
        yintra[obase + t * 64 + n] = accY;
        zrO[obase + t * 64 + n] = accZ;
    }
    size_t mbase = ((size_t)(bh * NC + c)) * 4096;
#pragma unroll
    for (int e = 0; e < 16; ++e) {
        int p = tq * 16 + e;
        float accM = 0.f, accZc = 0.f;
        for (int s = 0; s < LCH; ++s) {
            accM  = fmaf(Ah[s][p], Bh[s][n], accM);
            accZc = fmaf(Vt[s][p], Kh[s][n], accZc);
            accZc = fmaf(Qm[s][p], Bh[s][n], accZc);
        }
        if (p == n) accM += 1.f;
        mmO[mbase + p * 64 + n] = dL_n * accM;
        zcO[mbase + p * 64 + n] = dL_n * accZc;
    }
}

// ---------------- chunked WKV7, phase B: sequential over chunks (persistent) ----------------
// One block per (b,h). S[64][64] in LDS. Per chunk: y = Zr S^T + Yintra; S = S M + Zc.

__global__ __launch_bounds__(256) void chunkB_kernel(
    const float* __restrict__ yintra, const float* __restrict__ zrI,
    const float* __restrict__ mmI, const float* __restrict__ zcI,
    float* __restrict__ y) {
    int bh = blockIdx.x;
    int b = bh / HH, h = bh % HH;
    __shared__ float S[64][SPAD];
    __shared__ float M[64][SPAD];
    __shared__ float Zr[LCH][SPAD];
    int tid = threadIdx.x;
#pragma unroll
    for (int e = 0; e < 16; ++e) {
        int idx = tid + e * 256;
        S[idx >> 6][idx & 63] = 0.f;
    }
    int i1 = tid & 63, tq = tid >> 6;
    int i2 = tid >> 2, jb = tid & 3;
    for (int c = 0; c < NC; ++c) {
        size_t mbase = ((size_t)(bh * NC + c)) * 4096;
        size_t obase = ((size_t)(bh * NC + c)) * LCH * 64;
#pragma unroll
        for (int e = 0; e < 16; ++e) {
            int idx = tid + e * 256;
            M[idx >> 6][idx & 63] = mmI[mbase + idx];
        }
#pragma unroll
        for (int e = 0; e < 8; ++e) {
            int idx = tid + e * 256;
            Zr[idx >> 6][idx & 63] = zrI[obase + idx];
        }
        __syncthreads();
        // y step: thread (tq, i1) over 8 t's
        float srow[64];
#pragma unroll
        for (int p = 0; p < 64; ++p) srow[p] = S[i1][p];
#pragma unroll
        for (int e = 0; e < 8; ++e) {
            int t = tq * 8 + e;
            float acc = yintra[obase + t * 64 + i1];
#pragma unroll
            for (int p = 0; p < 64; ++p) acc = fmaf(Zr[t][p], srow[p], acc);
            y[((size_t)(b * TT + c * LCH + t)) * CC + h * 64 + i1] = acc;
        }
        // state update: thread (i2, jb) computes S_new[i2][jb*16 .. +15]
        float acc2[16];
#pragma unroll
        for (int u = 0; u < 16; ++u) acc2[u] = zcI[mbase + i2 * 64 + jb * 16 + u];
        for (int p = 0; p < 64; ++p) {
            float s = S[i2][p];
#pragma unroll
            for (int u = 0; u < 16; ++u) acc2[u] = fmaf(s, M[p][jb * 16 + u], acc2[u]);
        }
        __syncthreads();  // all reads of S complete
#pragma unroll
        for (int u = 0; u < 16; ++u) S[i2][jb * 16 + u] = acc2[u];
        __syncthreads();  // S updated before next chunk
    }
}

// ---------------- groupnorm(heads) + bonus + *g  (bf16 out) ----------------

__global__ __launch_bounds__(256) void gnbonus_kernel(const float* __restrict__ y,
    const float* __restrict__ r, const float* __restrict__ k, const float* __restrict__ v,
    const float* __restrict__ rk, const float* __restrict__ lw, const float* __restrict__ lb,
    const float* __restrict__ g, bf16* __restrict__ out) {
    int hg   = blockIdx.x * 4 + (threadIdx.x >> 6);
    int lane = threadIdx.x & 63;
    int bt = hg / HH, h = hg % HH;
    int c = h * 64 + lane;
    size_t off = (size_t)bt * CC + c;
    float yv = y[off];
    float rv = r[off], kv = k[off], vv = v[off];
    float s1 = yv, s2 = yv * yv, s3 = rv * kv * rk[h * 64 + lane];
    for (int m = 1; m < 64; m <<= 1) {
        s1 += __shfl_xor(s1, m);
        s2 += __shfl_xor(s2, m);
        s3 += __shfl_xor(s3, m);
    }
    float mean = s1 * (1.f / 64.f);
    float var  = s2 * (1.f / 64.f) - mean * mean;
    float inv  = rsqrtf(var + 64e-5f);
    float val  = (yv - mean) * inv * lw[c] + lb[c] + s3 * vv;
    out[off] = f2b(val * g[off]);
}

// ---------------- host ----------------

extern "C" void kernel_launch(void* const* d_in, const int* in_sizes, int n_in,
                              void* d_out, int out_size, void* d_ws, size_t ws_size,
                              hipStream_t stream) {
    (void)in_sizes; (void)n_in; (void)out_size;
    const float* x    = (const float*)d_in[0];
    const float* x_r  = (const float*)d_in[1];
    const float* x_w  = (const float*)d_in[2];
    const float* x_k  = (const float*)d_in[3];
    const float* x_v  = (const float*)d_in[4];
    const float* x_a  = (const float*)d_in[5];
    const float* x_g  = (const float*)d_in[6];
    const float* w0   = (const float*)d_in[7];
    const float* w1   = (const float*)d_in[8];
    const float* w2   = (const float*)d_in[9];
    const float* a0   = (const float*)d_in[10];
    const float* a1   = (const float*)d_in[11];
    const float* a2   = (const float*)d_in[12];
    const float* v0   = (const float*)d_in[13];
    const float* v1   = (const float*)d_in[14];
    const float* v2   = (const float*)d_in[15];
    const float* g1   = (const float*)d_in[16];
    const float* g2   = (const float*)d_in[17];
    const float* k_k  = (const float*)d_in[18];
    const float* k_a  = (const float*)d_in[19];
    const float* r_k  = (const float*)d_in[20];
    const float* W_r  = (const float*)d_in[21];
    const float* W_k  = (const float*)d_in[22];
    const float* W_v  = (const float*)d_in[23];
    const float* W_o  = (const float*)d_in[24];
    const float* ln_x_w = (const float*)d_in[25];
    const float* ln_x_b = (const float*)d_in[26];
    const float* ln1_w  = (const float*)d_in[27];
    const float* ln1_b  = (const float*)d_in[28];
    const float* ln2_w  = (const float*)d_in[29];
    const float* ln2_b  = (const float*)d_in[30];
    const float* c_x_k  = (const float*)d_in[31];
    const float* W_ck   = (const float*)d_in[32];
    const float* W_cv   = (const float*)d_in[33];

    const size_t MC = (size_t)MT * CC;
    char* wsb = (char*)d_ws;
    size_t woff = 0;
    auto alloc = [&](size_t bytes) -> void* {
        void* p = wsb + woff;
        woff += (bytes + 255) & ~(size_t)255;
        return p;
    };
    const size_t WPL = 7520256;
    bf16* wbf = (bf16*)alloc(WPL * sizeof(bf16));
    bf16* mx0 = (bf16*)alloc(MC * 2);
    bf16* mx1 = (bf16*)alloc(MC * 2);
    bf16* mx2 = (bf16*)alloc(MC * 2);
    bf16* mx3 = (bf16*)alloc(MC * 2);
    bf16* mx4 = (bf16*)alloc(MC * 2);
    bf16* mx5 = (bf16*)alloc(MC * 2);
    bf16* tmp_s = (bf16*)alloc((size_t)MT * 128 * 2);
    bf16* hbuf  = (bf16*)alloc((size_t)MT * FF * 2);
    bf16* ghout = (bf16*)alloc(MC * 2);
    float* xln    = (float*)alloc(MC * 4);
    float* rbuf   = (float*)alloc(MC * 4);
    float* kbuf   = (float*)alloc(MC * 4);
    float* vbuf   = (float*)alloc(MC * 4);
    float* abuf   = (float*)alloc(MC * 4);
    float* gbuf   = (float*)alloc(MC * 4);
    float* dbuf   = (float*)alloc(MC * 4);
    float* aab    = (float*)alloc(MC * 4);
    float* bbb    = (float*)alloc(MC * 4);
    float* ybuf   = (float*)alloc(MC * 4);
    float* vfirst = (float*)alloc(MC * 4);
    // chunked-wkv scratch
    float* yintraW = (float*)alloc((size_t)BH * NC * LCH * 64 * 4);
    float* zrW     = (float*)alloc((size_t)BH * NC * LCH * 64 * 4);
    float* mmW     = (float*)alloc((size_t)BH * NC * 4096 * 4);
    float* zcW     = (float*)alloc((size_t)BH * NC * 4096 * 4);
    if (woff > ws_size) return;

    float* xcur = (float*)d_out;
    copy_f<<<MC / 256, 256, 0, stream>>>(xcur, x);

    const __bf16* Wr_t  = (const __bf16*)(wbf + 0);
    const __bf16* Wk_t  = (const __bf16*)(wbf + 589824);
    const __bf16* Wv_t  = (const __bf16*)(wbf + 1179648);
    const __bf16* Wo_t  = (const __bf16*)(wbf + 1769472);
    const __bf16* w1_t  = (const __bf16*)(wbf + 2359296);
    const __bf16* w2_t  = (const __bf16*)(wbf + 2408448);
    const __bf16* a1_t  = (const __bf16*)(wbf + 2457600);
    const __bf16* a2_t  = (const __bf16*)(wbf + 2506752);
    const __bf16* v1_t  = (const __bf16*)(wbf + 2555904);
    const __bf16* v2_t  = (const __bf16*)(wbf + 2580480);
    const __bf16* g1_t  = (const __bf16*)(wbf + 2605056);
    const __bf16* g2_t  = (const __bf16*)(wbf + 2703360);
    const __bf16* Wck_t = (const __bf16*)(wbf + 2801664);
    const __bf16* Wcv_t = (const __bf16*)(wbf + 5160960);

    const int EW = (int)(MC / 256);

    for (int l = 0; l < LAYERS; ++l) {
        size_t oC = (size_t)l * CC;

        WPtrs wp;
        wp.p[0]  = W_r  + (size_t)l * CC * CC;
        wp.p[1]  = W_k  + (size_t)l * CC * CC;
        wp.p[2]  = W_v  + (size_t)l * CC * CC;
        wp.p[3]  = W_o  + (size_t)l * CC * CC;
        wp.p[4]  = w1   + (size_t)l * CC * 64;
        wp.p[5]  = w2   + (size_t)l * 64 * CC;
        wp.p[6]  = a1   + (size_t)l * CC * 64;
        wp.p[7]  = a2   + (size_t)l * 64 * CC;
        wp.p[8]  = v1   + (size_t)l * CC * 32;
        wp.p[9]  = v2   + (size_t)l * 32 * CC;
        wp.p[10] = g1   + (size_t)l * CC * 128;
        wp.p[11] = g2   + (size_t)l * 128 * CC;
        wp.p[12] = W_ck + (size_t)l * CC * FF;
        wp.p[13] = W_cv + (size_t)l * FF * CC;
        convert_weights<<<dim3(2304, 14), 256, 0, stream>>>(wp, wbf);

        float* vptr = (l == 0) ? vfirst : vbuf;

        // ---- time mix ----
        ln_kernel<<<MT, 256, 0, stream>>>(xcur, ln1_w + oC, ln1_b + oC, xln);
        mix6_kernel<<<EW, 256, 0, stream>>>(xln, x_r + oC, x_w + oC, x_k + oC,
                                            x_v + oC, x_a + oC, x_g + oC,
                                            mx0, mx1, mx2, mx3, mx4, mx5);
        gemm_mfma<128, 128, 0><<<dim3(6, 8), 256, 0, stream>>>((const __bf16*)mx0, Wr_t, rbuf, nullptr, nullptr, nullptr, MT, CC, CC);
        gemm_mfma<128, 128, 0><<<dim3(6, 8), 256, 0, stream>>>((const __bf16*)mx2, Wk_t, kbuf, nullptr, nullptr, nullptr, MT, CC, CC);
        gemm_mfma<128, 128, 0><<<dim3(6, 8), 256, 0, stream>>>((const __bf16*)mx3, Wv_t, vptr, nullptr, nullptr, nullptr, MT, CC, CC);
        gemm_mfma<64, 64, 2><<<dim3(1, 16), 256, 0, stream>>>((const __bf16*)mx1, w1_t, nullptr, tmp_s, nullptr, nullptr, MT, 64, CC);
        gemm_mfma<128, 128, 6><<<dim3(6, 8), 256, 0, stream>>>((const __bf16*)tmp_s, w2_t, dbuf, nullptr, w0 + oC, nullptr, MT, CC, 64);
        gemm_mfma<64, 64, 1><<<dim3(1, 16), 256, 0, stream>>>((const __bf16*)mx4, a1_t, nullptr, tmp_s, nullptr, nullptr, MT, 64, CC);
        gemm_mfma<128, 128, 7><<<dim3(6, 8), 256, 0, stream>>>((const __bf16*)tmp_s, a2_t, abuf, nullptr, a0 + oC, nullptr, MT, CC, 64);
        if (l > 0) {
            gemm_mfma<64, 32, 1><<<dim3(1, 16), 256, 0, stream>>>((const __bf16*)mx3, v1_t, nullptr, tmp_s, nullptr, nullptr, MT, 32, CC);
            gemm_mfma<128, 128, 8><<<dim3(6, 8), 256, 0, stream>>>((const __bf16*)tmp_s, v2_t, vbuf, nullptr, v0 + oC, vfirst, MT, CC, 32);
        }
        gemm_mfma<64, 64, 3><<<dim3(2, 16), 256, 0, stream>>>((const __bf16*)mx5, g1_t, nullptr, tmp_s, nullptr, nullptr, MT, 128, CC);
        gemm_mfma<128, 128, 0><<<dim3(6, 8), 256, 0, stream>>>((const __bf16*)tmp_s, g2_t, gbuf, nullptr, nullptr, nullptr, MT, CC, 128);
        kk_kernel<<<MT * HH / 4, 256, 0, stream>>>(kbuf, abuf, k_k + oC, k_a + oC, aab, bbb);
        // chunked scan
        chunkA_kernel<<<dim3(NC, BH), 256, 0, stream>>>(rbuf, dbuf, kbuf, vptr, aab, bbb,
                                                        yintraW, zrW, mmW, zcW);
        chunkB_kernel<<<BH, 256, 0, stream>>>(yintraW, zrW, mmW, zcW, ybuf);
        gnbonus_kernel<<<MT * HH / 4, 256, 0, stream>>>(ybuf, rbuf, kbuf, vptr,
                                                        r_k + (size_t)l * CC,
                                                        ln_x_w + oC, ln_x_b + oC, gbuf, ghout);
        gemm_mfma<128, 128, 5><<<dim3(6, 8), 256, 0, stream>>>((const __bf16*)ghout, Wo_t, xcur, nullptr, nullptr, nullptr, MT, CC, CC);

        // ---- channel mix ----
        ln_kernel<<<MT, 256, 0, stream>>>(xcur, ln2_w + oC, ln2_b + oC, xln);
        mixc_kernel<<<EW, 256, 0, stream>>>(xln, c_x_k + oC, mx0);
        gemm_mfma<128, 128, 4><<<dim3(24, 8), 256, 0, stream>>>((const __bf16*)mx0, Wck_t, nullptr, hbuf, nullptr, nullptr, MT, FF, CC);
        gemm_mfma<128, 128, 5><<<dim3(6, 8), 256, 0, stream>>>((const __bf16*)hbuf, Wcv_t, xcur, nullptr, nullptr, nullptr, MT, CC, FF);
    }
}

// Round 4
// 1925.818 us; speedup vs baseline: 6.1004x; 1.4348x over previous
//
#include <hip/hip_runtime.h>
#include <hip/hip_bf16.h>
#include <math.h>

#define LAYERS 6
#define BBATCH 2
#define TT 512
#define CC 768
#define HH 12
#define MT (BBATCH*TT)      // 1024 tokens
#define FF (4*CC)           // 3072
#define LCH 32
#define NC (TT/LCH)         // 16 chunks
#define BH (BBATCH*HH)      // 24
#define SPAD 65

typedef __hip_bfloat16 bf16;
typedef __bf16 bf16x8 __attribute__((ext_vector_type(8)));
typedef float f32x4 __attribute__((ext_vector_type(4)));

__device__ inline bf16 f2b(float f) { return __float2bfloat16(f); }
__device__ inline float b2f(bf16 h) { return __bfloat162float(h); }

// ---------------- utility ----------------

__global__ __launch_bounds__(256) void copy_f(float* __restrict__ dst, const float* __restrict__ src) {
    size_t i = (size_t)blockIdx.x * 256 + threadIdx.x;
    dst[i] = src[i];
}

// ---------------- fused layernorm + token-shift-diff, bf16 concat output ----------------
// out[row][0:768]   = LN(x[row])
// out[row][768:1536]= LN(x[row-1]) - LN(x[row])   (0 - LN(x[row]) at t==0)

__global__ __launch_bounds__(256) void ln_shift_kernel(const float* __restrict__ x,
                                                       const float* __restrict__ w,
                                                       const float* __restrict__ b,
                                                       bf16* __restrict__ out) {
    int row = blockIdx.x;
    int t = row % TT;
    const float* xr = x + (size_t)row * CC;
    const float* xp = xr - CC;
    int tid = threadIdx.x;
    float c0 = xr[tid], c1 = xr[tid + 256], c2 = xr[tid + 512];
    float p0 = 0.f, p1 = 0.f, p2 = 0.f;
    if (t > 0) { p0 = xp[tid]; p1 = xp[tid + 256]; p2 = xp[tid + 512]; }
    float s  = c0 + c1 + c2, q  = c0 * c0 + c1 * c1 + c2 * c2;
    float sp = p0 + p1 + p2, qp = p0 * p0 + p1 * p1 + p2 * p2;
    for (int m = 1; m < 64; m <<= 1) {
        s += __shfl_xor(s, m); q += __shfl_xor(q, m);
        sp += __shfl_xor(sp, m); qp += __shfl_xor(qp, m);
    }
    __shared__ float rs[4], rq[4], rsp[4], rqp[4];
    int wid = tid >> 6;
    if ((tid & 63) == 0) { rs[wid] = s; rq[wid] = q; rsp[wid] = sp; rqp[wid] = qp; }
    __syncthreads();
    s  = rs[0] + rs[1] + rs[2] + rs[3];   q  = rq[0] + rq[1] + rq[2] + rq[3];
    sp = rsp[0] + rsp[1] + rsp[2] + rsp[3]; qp = rqp[0] + rqp[1] + rqp[2] + rqp[3];
    float meanC = s * (1.f / CC);
    float invC  = rsqrtf(q * (1.f / CC) - meanC * meanC + 1e-5f);
    float meanP = sp * (1.f / CC);
    float invP  = rsqrtf(qp * (1.f / CC) - meanP * meanP + 1e-5f);
    bf16* orow = out + (size_t)row * 1536;
    float cv[3] = {c0, c1, c2};
    float pv[3] = {p0, p1, p2};
#pragma unroll
    for (int j = 0; j < 3; ++j) {
        int cc = tid + j * 256;
        float lnc = (cv[j] - meanC) * invC * w[cc] + b[cc];
        float lnp = (t > 0) ? (pv[j] - meanP) * invP * w[cc] + b[cc] : 0.f;
        orow[cc] = f2b(lnc);
        orow[768 + cc] = f2b(lnp - lnc);
    }
}

// ---------------- weight convert: build transposed bf16 (optionally mix-folded concat) ----------------
// concat entry (Kdst = 2*Ksrc): dst[n][k] = W[k][n] (k<Ksrc) | mix[k-Ksrc]*W[k-Ksrc][n]
// plain entry  (Kdst = Ksrc):   dst[n][k] = W[k][n]

struct CEntry { const float* W; const float* mix; bf16* dst; int Ksrc, Nsrc, Npad, Kdst; };
struct CArgs { CEntry e[14]; };

__global__ __launch_bounds__(256) void convert_weights(CArgs ca) {
    CEntry E = ca.e[blockIdx.y];
    int ntN = E.Npad >> 5, ntK = E.Kdst >> 5;
    int t = blockIdx.x;
    if (t >= ntN * ntK) return;
    int tn = (t % ntN) * 32, tk = (t / ntN) * 32;
    __shared__ float tile[32][33];
    int c = threadIdx.x & 31, r0 = threadIdx.x >> 5;
    int ks = tk;
    const float* mixp = nullptr;
    if (tk >= E.Ksrc) { ks = tk - E.Ksrc; mixp = E.mix; }
#pragma unroll
    for (int i = 0; i < 4; ++i) {
        int r = r0 + i * 8;
        float v = (tn + c < E.Nsrc) ? E.W[(size_t)(ks + r) * E.Nsrc + tn + c] : 0.f;
        if (mixp) v *= mixp[ks + r];
        tile[r][c] = v;
    }
    __syncthreads();
#pragma unroll
    for (int i = 0; i < 4; ++i) {
        int r = r0 + i * 8;
        E.dst[(size_t)(tn + r) * E.Kdst + tk + c] = f2b(tile[c][r]);
    }
}

// ---------------- epilogues ----------------

struct EpiG {
    float* outF; bf16* outH;
    const float* p1; const float* p2;
    int epi, ld, ntrue;
};
struct EpiArgs { EpiG g[7]; int nb[8]; };

__device__ inline void epi_store(const EpiG& E, size_t idx, int lc, float v) {
    switch (E.epi) {
        case 0: E.outF[idx] = v; break;
        case 1: E.outH[idx] = f2b(v); break;
        case 2: E.outH[idx] = f2b(tanhf(v)); break;
        case 3: E.outH[idx] = f2b(1.f / (1.f + expf(-v))); break;
        case 4: { float t = fmaxf(v, 0.f); E.outH[idx] = f2b(t * t); } break;
        case 5: E.outF[idx] += v; break;
        case 6: { float z = E.p1[lc] + v; float nz = -z;
                  float sp = (nz > 20.f) ? nz : log1pf(expf(nz));
                  E.outF[idx] = expf(-expf(-sp - 0.5f)); } break;
        case 7: E.outF[idx] = 1.f / (1.f + expf(-(E.p1[lc] + v))); break;
        case 8: { float vv = E.outF[idx];
                  float s = 1.f / (1.f + expf(-(E.p1[lc] + v)));
                  E.outF[idx] = vv + (E.p2[idx] - vv) * s; } break;
    }
}

// ---------------- bf16 MFMA GEMM with grouped-column epilogue ----------------
// C[M, Npad] = A[M,K] @ Bt[Npad,K]^T ; grid = (Npad/BN, M/BM)

template<int BM, int BN>
__global__ __launch_bounds__(256) void gemm_multi(const __bf16* __restrict__ A,
                                                  const __bf16* __restrict__ Bt,
                                                  int K, EpiArgs ea) {
    constexpr int FM = BM / 32, FN = BN / 32;
    constexpr int ABYTES = BM * 64;
    constexpr int TOT = (BM + BN) * 64;
    constexpr int NCHUNK = TOT / 4096;
    __shared__ __align__(16) char smem[2][TOT];
    int tid = threadIdx.x;
    int lane = tid & 63, wid = tid >> 6;
    int bm = blockIdx.y * BM, bn = blockIdx.x * BN;
    int wm = (wid >> 1) * (BM / 2), wn = (wid & 1) * (BN / 2);
    f32x4 acc[FM][FN];
#pragma unroll
    for (int i = 0; i < FM; ++i)
#pragma unroll
        for (int j = 0; j < FN; ++j) acc[i][j] = (f32x4){0.f, 0.f, 0.f, 0.f};

    int nk = K >> 5;
    auto stage = [&](int buf, int k0) {
        char* sb = &smem[buf][0];
#pragma unroll
        for (int c = 0; c < NCHUNK; ++c) {
            int d = c * 4096 + tid * 16;
            int isB = d >= ABYTES;
            int dd = isB ? d - ABYTES : d;
            int row = dd >> 6;
            int u = (dd >> 4) & 3;
            int su = u ^ (row & 3);
            const __bf16* src = isB ? (Bt + (size_t)(bn + row) * K + k0 + su * 8)
                                    : (A  + (size_t)(bm + row) * K + k0 + su * 8);
            char* ldst = sb + c * 4096 + (tid & 192) * 16;
            __builtin_amdgcn_global_load_lds(
                (const __attribute__((address_space(1))) unsigned int*)src,
                (__attribute__((address_space(3))) unsigned int*)ldst, 16, 0, 0);
        }
    };

    stage(0, 0);
    __syncthreads();
    for (int t = 0; t < nk; ++t) {
        if (t + 1 < nk) stage((t + 1) & 1, (t + 1) * 32);
        const char* sA = &smem[t & 1][0];
        const char* sB = &smem[t & 1][ABYTES];
        int u = lane >> 4, r0 = lane & 15;
        bf16x8 af[FM], bfr[FN];
#pragma unroll
        for (int i = 0; i < FM; ++i) {
            int row = wm + i * 16 + r0;
            int su = u ^ (row & 3);
            af[i] = *(const bf16x8*)(sA + row * 64 + su * 16);
        }
#pragma unroll
        for (int j = 0; j < FN; ++j) {
            int row = wn + j * 16 + r0;
            int su = u ^ (row & 3);
            bfr[j] = *(const bf16x8*)(sB + row * 64 + su * 16);
        }
#pragma unroll
        for (int i = 0; i < FM; ++i)
#pragma unroll
            for (int j = 0; j < FN; ++j)
                acc[i][j] = __builtin_amdgcn_mfma_f32_16x16x32_bf16(af[i], bfr[j], acc[i][j], 0, 0, 0);
        __syncthreads();
    }

    int gid = 0;
#pragma unroll 1
    while (bn >= ea.nb[gid + 1]) ++gid;
    EpiG E = ea.g[gid];
    int colBase = ea.nb[gid];
#pragma unroll
    for (int i = 0; i < FM; ++i) {
#pragma unroll
        for (int j = 0; j < FN; ++j) {
#pragma unroll
            for (int q = 0; q < 4; ++q) {
                int gm = bm + wm + i * 16 + (lane >> 4) * 4 + q;
                int lc = bn + wn + j * 16 + (lane & 15) - colBase;
                if (lc < E.ntrue)
                    epi_store(E, (size_t)gm * E.ld + lc, lc, acc[i][j][q]);
            }
        }
    }
}

// ---------------- grouped low-rank GEMM: per-z group with own A/Bt/K/epi, N=768 ----------------

struct G2G { const __bf16* A; const __bf16* Bt; float* outF; const float* p1; const float* p2; int K; int epi; };
struct G2Args { G2G g[4]; };

template<int BM, int BN>
__global__ __launch_bounds__(256) void gemm_g2(G2Args ga) {
    G2G G = ga.g[blockIdx.z];
    const __bf16* A = G.A;
    const __bf16* Bt = G.Bt;
    int K = G.K;
    constexpr int FM = BM / 32, FN = BN / 32;
    constexpr int ABYTES = BM * 64;
    constexpr int TOT = (BM + BN) * 64;
    constexpr int NCHUNK = TOT / 4096;
    __shared__ __align__(16) char smem[2][TOT];
    int tid = threadIdx.x;
    int lane = tid & 63, wid = tid >> 6;
    int bm = blockIdx.y * BM, bn = blockIdx.x * BN;
    int wm = (wid >> 1) * (BM / 2), wn = (wid & 1) * (BN / 2);
    f32x4 acc[FM][FN];
#pragma unroll
    for (int i = 0; i < FM; ++i)
#pragma unroll
        for (int j = 0; j < FN; ++j) acc[i][j] = (f32x4){0.f, 0.f, 0.f, 0.f};

    int nk = K >> 5;
    auto stage = [&](int buf, int k0) {
        char* sb = &smem[buf][0];
#pragma unroll
        for (int c = 0; c < NCHUNK; ++c) {
            int d = c * 4096 + tid * 16;
            int isB = d >= ABYTES;
            int dd = isB ? d - ABYTES : d;
            int row = dd >> 6;
            int u = (dd >> 4) & 3;
            int su = u ^ (row & 3);
            const __bf16* src = isB ? (Bt + (size_t)(bn + row) * K + k0 + su * 8)
                                    : (A  + (size_t)(bm + row) * K + k0 + su * 8);
            char* ldst = sb + c * 4096 + (tid & 192) * 16;
            __builtin_amdgcn_global_load_lds(
                (const __attribute__((address_space(1))) unsigned int*)src,
                (__attribute__((address_space(3))) unsigned int*)ldst, 16, 0, 0);
        }
    };

    stage(0, 0);
    __syncthreads();
    for (int t = 0; t < nk; ++t) {
        if (t + 1 < nk) stage((t + 1) & 1, (t + 1) * 32);
        const char* sA = &smem[t & 1][0];
        const char* sB = &smem[t & 1][ABYTES];
        int u = lane >> 4, r0 = lane & 15;
        bf16x8 af[FM], bfr[FN];
#pragma unroll
        for (int i = 0; i < FM; ++i) {
            int row = wm + i * 16 + r0;
            int su = u ^ (row & 3);
            af[i] = *(const bf16x8*)(sA + row * 64 + su * 16);
        }
#pragma unroll
        for (int j = 0; j < FN; ++j) {
            int row = wn + j * 16 + r0;
            int su = u ^ (row & 3);
            bfr[j] = *(const bf16x8*)(sB + row * 64 + su * 16);
        }
#pragma unroll
        for (int i = 0; i < FM; ++i)
#pragma unroll
            for (int j = 0; j < FN; ++j)
                acc[i][j] = __builtin_amdgcn_mfma_f32_16x16x32_bf16(af[i], bfr[j], acc[i][j], 0, 0, 0);
        __syncthreads();
    }

    EpiG E;
    E.outF = G.outF; E.outH = nullptr; E.p1 = G.p1; E.p2 = G.p2;
    E.epi = G.epi; E.ld = 768; E.ntrue = 768;
#pragma unroll
    for (int i = 0; i < FM; ++i) {
#pragma unroll
        for (int j = 0; j < FN; ++j) {
#pragma unroll
            for (int q = 0; q < 4; ++q) {
                int gm = bm + wm + i * 16 + (lane >> 4) * 4 + q;
                int lc = bn + wn + j * 16 + (lane & 15);
                epi_store(E, (size_t)gm * 768 + lc, lc, acc[i][j][q]);
            }
        }
    }
}

// ---------------- chunked WKV7, phase A: intra-chunk, with fused kk-normalize ----------------

__global__ __launch_bounds__(256) void chunkA_kernel(
    const float* __restrict__ r, const float* __restrict__ wd,
    const float* __restrict__ kraw, const float* __restrict__ av_,
    const float* __restrict__ v,
    const float* __restrict__ kkw, const float* __restrict__ kaw,
    float* __restrict__ kupd,
    float* __restrict__ yintra, float* __restrict__ zrO,
    float* __restrict__ mmO, float* __restrict__ zcO) {
    int c = blockIdx.x, bh = blockIdx.y;
    int b = bh / HH, h = bh % HH;
    __shared__ float Di[LCH][SPAD];
    __shared__ float Ah[LCH][SPAD];
    __shared__ float Bh[LCH][SPAD];
    __shared__ float Kh[LCH][SPAD];
    __shared__ float Rh[LCH][SPAD];
    __shared__ float Vt[LCH][SPAD];
    __shared__ float Qm[LCH][SPAD];
    __shared__ float Gba[LCH][LCH], Gka[LCH][LCH], Grb[LCH][LCH], Grk[LCH][LCH];
    int tid = threadIdx.x;
    int n = tid & 63, tq = tid >> 6;
    size_t base = ((size_t)(b * TT + c * LCH)) * CC + h * 64 + n;
    int cvec = h * 64 + n;
    float kkwv = kkw[cvec], kawv = kaw[cvec];
#pragma unroll
    for (int e = 0; e < 8; ++e) {
        int t = tq * 8 + e;
        size_t off = base + (size_t)t * CC;
        float kr = kraw[off];
        float aval = av_[off];
        float kk0 = kr * kkwv;
        float ss = kk0 * kk0;
        for (int m = 1; m < 64; m <<= 1) ss += __shfl_xor(ss, m);
        float rinv = 1.f / fmaxf(sqrtf(ss), 1e-12f);
        float kkv = kk0 * rinv;
        float ku = kr * (1.f + (aval - 1.f) * kawv);
        kupd[off] = ku;
        Di[t][n] = wd[off];
        Ah[t][n] = -kkv;
        Bh[t][n] = kkv * aval;
        Kh[t][n] = ku;
        Rh[t][n] = r[off];
        Vt[t][n] = v[off];
    }
    __syncthreads();
    if (tid < 64) {
        float d = 1.f;
        for (int t = 0; t < LCH; ++t) { d *= Di[t][tid]; Di[t][tid] = d; }
    }
    __syncthreads();
#pragma unroll
    for (int e = 0; e < 8; ++e) {
        int t = tq * 8 + e;
        float di = Di[t][n];
        float dp = (t == 0) ? 1.f : Di[t - 1][n];
        float inv = 1.f / di;
        Ah[t][n] *= dp;
        Bh[t][n] *= inv;
        Kh[t][n] *= inv;
        Rh[t][n] *= di;
    }
    __syncthreads();
#pragma unroll
    for (int e = 0; e < 4; ++e) {
        int idx = tid + e * 256;
        int t = idx >> 5, s = idx & 31;
        float dba = 0.f, dka = 0.f, drb = 0.f, drk = 0.f;
        for (int j = 0; j < 64; ++j) {
            float at = Ah[t][j], rt = Rh[t][j];
            float bs = Bh[s][j], ks = Kh[s][j];
            dba = fmaf(at, bs, dba); dka = fmaf(at, ks, dka);
            drb = fmaf(rt, bs, drb); drk = fmaf(rt, ks, drk);
        }
        Gba[t][s] = (s < t)  ? dba : 0.f;
        Gka[t][s] = (s < t)  ? dka : 0.f;
        Grb[t][s] = (s <= t) ? drb : 0.f;
        Grk[t][s] = (s <= t) ? drk : 0.f;
    }
    __syncthreads();
#pragma unroll
    for (int e = 0; e < 8; ++e) {
        int t = tq * 8 + e;
        float acc = 0.f;
        for (int s = 0; s < LCH; ++s) acc = fmaf(Gka[t][s], Vt[s][n], acc);
        Qm[t][n] = acc;
    }
    __syncthreads();
    if (tq == 0) {
        for (int t = 1; t < LCH; ++t) {
            float acc = Ah[t][n];
            for (int s = 0; s < t; ++s) acc = fmaf(Gba[t][s], Ah[s][n], acc);
            Ah[t][n] = acc;
        }
    } else if (tq == 1) {
        for (int t = 1; t < LCH; ++t) {
            float acc = Qm[t][n];
            for (int s = 0; s < t; ++s) acc = fmaf(Gba[t][s], Qm[s][n], acc);
            Qm[t][n] = acc;
        }
    }
    __syncthreads();
    float dL_n = Di[LCH - 1][n];
    size_t obase = ((size_t)(bh * NC + c)) * LCH * 64;
#pragma unroll
    for (int e = 0; e < 8; ++e) {
        int t = tq * 8 + e;
        float accY = 0.f, accZ = Rh[t][n];
        for (int s = 0; s < LCH; ++s) {
            accY = fmaf(Grk[t][s], Vt[s][n], accY);
            accY = fmaf(Grb[t][s], Qm[s][n], accY);
            accZ = fmaf(Grb[t][s], Ah[s][n], accZ);
        }
        yintra[obase + t * 64 + n] = accY;
        zrO[obase + t * 64 + n] = accZ;
    }
    size_t mbase = ((size_t)(bh * NC + c)) * 4096;
#pragma unroll
    for (int e = 0; e < 16; ++e) {
        int p = tq * 16 + e;
        float accM = 0.f, accZc = 0.f;
        for (int s = 0; s < LCH; ++s) {
            accM  = fmaf(Ah[s][p], Bh[s][n], accM);
            accZc = fmaf(Vt[s][p], Kh[s][n], accZc);
            accZc = fmaf(Qm[s][p], Bh[s][n], accZc);
        }
        if (p == n) accM += 1.f;
        mmO[mbase + p * 64 + n] = dL_n * accM;
        zcO[mbase + p * 64 + n] = dL_n * accZc;
    }
}

// ---------------- phase B1: sequential state chain only (24 blocks, prefetched) ----------------
// S_entry(c+1) = S_entry(c) @ M_c + Zc_c ; writes checkpoints for c = 1..15.

__global__ __launch_bounds__(256) void chunkB1_kernel(const float* __restrict__ mm,
                                                      const float* __restrict__ zc,
                                                      float* __restrict__ schk) {
    int bh = blockIdx.x;
    int tid = threadIdx.x;
    int i4 = tid >> 4, j4 = tid & 15;
    __shared__ float S[64][SPAD];
    __shared__ __align__(16) float Mb[2][64][64];
#pragma unroll
    for (int e = 0; e < 16; ++e) {
        int idx = tid + e * 256;
        S[idx >> 6][idx & 63] = 0.f;
    }
    const float* mbase = mm + (size_t)bh * NC * 4096;
    const float* zbase = zc + (size_t)bh * NC * 4096;
    float* sbase = schk + (size_t)bh * NC * 4096;
#pragma unroll
    for (int s = 0; s < 4; ++s) {
        __builtin_amdgcn_global_load_lds(
            (const __attribute__((address_space(1))) unsigned int*)(mbase + s * 1024 + tid * 4),
            (__attribute__((address_space(3))) unsigned int*)((char*)&Mb[0][0][0] + s * 4096 + (tid & 192) * 16),
            16, 0, 0);
    }
    f32x4 zcur[4], znxt[4];
#pragma unroll
    for (int d = 0; d < 4; ++d)
        zcur[d] = *(const f32x4*)(zbase + (i4 * 4 + d) * 64 + j4 * 4);
    __syncthreads();
#pragma unroll 1
    for (int c = 0; c < NC - 1; ++c) {
        int cb = c & 1;
        if (c < NC - 2) {
#pragma unroll
            for (int s = 0; s < 4; ++s) {
                __builtin_amdgcn_global_load_lds(
                    (const __attribute__((address_space(1))) unsigned int*)(mbase + (size_t)(c + 1) * 4096 + s * 1024 + tid * 4),
                    (__attribute__((address_space(3))) unsigned int*)((char*)&Mb[cb ^ 1][0][0] + s * 4096 + (tid & 192) * 16),
                    16, 0, 0);
            }
#pragma unroll
            for (int d = 0; d < 4; ++d)
                znxt[d] = *(const f32x4*)(zbase + (size_t)(c + 1) * 4096 + (i4 * 4 + d) * 64 + j4 * 4);
        }
        f32x4 acc0 = zcur[0], acc1 = zcur[1], acc2 = zcur[2], acc3 = zcur[3];
        for (int p = 0; p < 64; ++p) {
            f32x4 mrow = *(const f32x4*)&Mb[cb][p][j4 * 4];
            float s0 = S[i4 * 4 + 0][p];
            float s1 = S[i4 * 4 + 1][p];
            float s2 = S[i4 * 4 + 2][p];
            float s3 = S[i4 * 4 + 3][p];
#pragma unroll
            for (int u = 0; u < 4; ++u) {
                acc0[u] = fmaf(s0, mrow[u], acc0[u]);
                acc1[u] = fmaf(s1, mrow[u], acc1[u]);
                acc2[u] = fmaf(s2, mrow[u], acc2[u]);
                acc3[u] = fmaf(s3, mrow[u], acc3[u]);
            }
        }
        __syncthreads();   // all reads of S done
        float* cp = sbase + (size_t)(c + 1) * 4096;
#pragma unroll
        for (int u = 0; u < 4; ++u) {
            S[i4 * 4 + 0][j4 * 4 + u] = acc0[u];
            S[i4 * 4 + 1][j4 * 4 + u] = acc1[u];
            S[i4 * 4 + 2][j4 * 4 + u] = acc2[u];
            S[i4 * 4 + 3][j4 * 4 + u] = acc3[u];
        }
        *(f32x4*)(cp + (i4 * 4 + 0) * 64 + j4 * 4) = acc0;
        *(f32x4*)(cp + (i4 * 4 + 1) * 64 + j4 * 4) = acc1;
        *(f32x4*)(cp + (i4 * 4 + 2) * 64 + j4 * 4) = acc2;
        *(f32x4*)(cp + (i4 * 4 + 3) * 64 + j4 * 4) = acc3;
#pragma unroll
        for (int d = 0; d < 4; ++d) zcur[d] = znxt[d];
        __syncthreads();   // S visible before next chunk
    }
}

// ---------------- phase Y: y = Yintra + Zr S^T, fused groupnorm + bonus + gate ----------------

__global__ __launch_bounds__(256) void chunkY_kernel(
    const float* __restrict__ yintra, const float* __restrict__ zrI,
    const float* __restrict__ schk,
    const float* __restrict__ r, const float* __restrict__ kupd,
    const float* __restrict__ v, const float* __restrict__ g,
    const float* __restrict__ rk, const float* __restrict__ lw,
    const float* __restrict__ lb, bf16* __restrict__ out) {
    int c = blockIdx.x, bh = blockIdx.y;
    int b = bh / HH, h = bh % HH;
    __shared__ float Y[LCH][SPAD];
    __shared__ float Zr[LCH][SPAD];
    __shared__ float Sh[64][SPAD];
    int tid = threadIdx.x;
    int n = tid & 63, tq = tid >> 6;
    size_t obase = ((size_t)(bh * NC + c)) * LCH * 64;
#pragma unroll
    for (int e = 0; e < 8; ++e) {
        int idx = tid + e * 256;
        int row = idx >> 6, col = idx & 63;
        Y[row][col] = yintra[obase + idx];
        Zr[row][col] = zrI[obase + idx];
    }
    if (c > 0) {
        size_t sbase = ((size_t)(bh * NC + c)) * 4096;
#pragma unroll
        for (int e = 0; e < 16; ++e) {
            int idx = tid + e * 256;
            Sh[idx >> 6][idx & 63] = schk[sbase + idx];
        }
    }
    __syncthreads();
    if (c > 0) {
        float acc[8];
#pragma unroll
        for (int e = 0; e < 8; ++e) acc[e] = 0.f;
        for (int p = 0; p < 64; ++p) {
            float sv = Sh[n][p];
#pragma unroll
            for (int e = 0; e < 8; ++e)
                acc[e] = fmaf(Zr[tq * 8 + e][p], sv, acc[e]);
        }
#pragma unroll
        for (int e = 0; e < 8; ++e) Y[tq * 8 + e][n] += acc[e];
    }
    size_t rowbase = ((size_t)(b * TT + c * LCH)) * CC + h * 64 + n;
    float rkv = rk[h * 64 + n];
    float lwv = lw[h * 64 + n], lbv = lb[h * 64 + n];
#pragma unroll
    for (int e = 0; e < 8; ++e) {
        int t = tq * 8 + e;
        size_t off = rowbase + (size_t)t * CC;
        float yv = Y[t][n];
        float rv = r[off], kv = kupd[off], vv = v[off];
        float s1 = yv, s2 = yv * yv, s3 = rv * kv * rkv;
        for (int m = 1; m < 64; m <<= 1) {
            s1 += __shfl_xor(s1, m);
            s2 += __shfl_xor(s2, m);
            s3 += __shfl_xor(s3, m);
        }
        float mean = s1 * (1.f / 64.f);
        float var  = s2 * (1.f / 64.f) - mean * mean;
        float inv  = rsqrtf(var + 64e-5f);
        float val  = (yv - mean) * inv * lwv + lbv + s3 * vv;
        out[off] = f2b(val * g[off]);
    }
}

// ---------------- host ----------------

extern "C" void kernel_launch(void* const* d_in, const int* in_sizes, int n_in,
                              void* d_out, int out_size, void* d_ws, size_t ws_size,
                              hipStream_t stream) {
    (void)in_sizes; (void)n_in; (void)out_size;
    const float* x    = (const float*)d_in[0];
    const float* x_r  = (const float*)d_in[1];
    const float* x_w  = (const float*)d_in[2];
    const float* x_k  = (const float*)d_in[3];
    const float* x_v  = (const float*)d_in[4];
    const float* x_a  = (const float*)d_in[5];
    const float* x_g  = (const float*)d_in[6];
    const float* w0   = (const float*)d_in[7];
    const float* w1   = (const float*)d_in[8];
    const float* w2   = (const float*)d_in[9];
    const float* a0   = (const float*)d_in[10];
    const float* a1   = (const float*)d_in[11];
    const float* a2   = (const float*)d_in[12];
    const float* v0   = (const float*)d_in[13];
    const float* v1   = (const float*)d_in[14];
    const float* v2   = (const float*)d_in[15];
    const float* g1   = (const float*)d_in[16];
    const float* g2   = (const float*)d_in[17];
    const float* k_k  = (const float*)d_in[18];
    const float* k_a  = (const float*)d_in[19];
    const float* r_k  = (const float*)d_in[20];
    const float* W_r  = (const float*)d_in[21];
    const float* W_k  = (const float*)d_in[22];
    const float* W_v  = (const float*)d_in[23];
    const float* W_o  = (const float*)d_in[24];
    const float* ln_x_w = (const float*)d_in[25];
    const float* ln_x_b = (const float*)d_in[26];
    const float* ln1_w  = (const float*)d_in[27];
    const float* ln1_b  = (const float*)d_in[28];
    const float* ln2_w  = (const float*)d_in[29];
    const float* ln2_b  = (const float*)d_in[30];
    const float* c_x_k  = (const float*)d_in[31];
    const float* W_ck   = (const float*)d_in[32];
    const float* W_cv   = (const float*)d_in[33];

    const size_t MC = (size_t)MT * CC;
    char* wsb = (char*)d_ws;
    size_t woff = 0;
    auto alloc = [&](size_t bytes) -> void* {
        void* p = wsb + woff;
        woff += (bytes + 255) & ~(size_t)255;
        return p;
    };
    // bf16 weight arenas (rebuilt per layer)
    bf16* Bcat  = (bf16*)alloc((size_t)2624 * 1536 * 2);
    bf16* Bck   = (bf16*)alloc((size_t)3072 * 1536 * 2);
    bf16* w2t   = (bf16*)alloc((size_t)768 * 64 * 2);
    bf16* a2t   = (bf16*)alloc((size_t)768 * 64 * 2);
    bf16* v2t   = (bf16*)alloc((size_t)768 * 32 * 2);
    bf16* g2t   = (bf16*)alloc((size_t)768 * 128 * 2);
    bf16* Wo_t  = (bf16*)alloc((size_t)768 * 768 * 2);
    bf16* Wcv_t = (bf16*)alloc((size_t)768 * 3072 * 2);
    // activations
    bf16* A1    = (bf16*)alloc((size_t)MT * 1536 * 2);
    float* rbuf  = (float*)alloc(MC * 4);
    float* kraw  = (float*)alloc(MC * 4);
    float* kupd  = (float*)alloc(MC * 4);
    float* vbuf  = (float*)alloc(MC * 4);
    float* vfirst= (float*)alloc(MC * 4);
    float* abuf  = (float*)alloc(MC * 4);
    float* dbuf  = (float*)alloc(MC * 4);
    float* gbuf  = (float*)alloc(MC * 4);
    bf16* w1o   = (bf16*)alloc((size_t)MT * 64 * 2);
    bf16* a1o   = (bf16*)alloc((size_t)MT * 64 * 2);
    bf16* v1o   = (bf16*)alloc((size_t)MT * 32 * 2);
    bf16* g1o   = (bf16*)alloc((size_t)MT * 128 * 2);
    bf16* hbuf  = (bf16*)alloc((size_t)MT * FF * 2);
    bf16* ghout = (bf16*)alloc(MC * 2);
    float* yintraW = (float*)alloc((size_t)BH * NC * LCH * 64 * 4);
    float* zrW     = (float*)alloc((size_t)BH * NC * LCH * 64 * 4);
    float* mmW     = (float*)alloc((size_t)BH * NC * 4096 * 4);
    float* zcW     = (float*)alloc((size_t)BH * NC * 4096 * 4);
    float* schkW   = (float*)alloc((size_t)BH * NC * 4096 * 4);
    if (woff > ws_size) return;

    float* xcur = (float*)d_out;
    copy_f<<<MC / 256, 256, 0, stream>>>(xcur, x);

    for (int l = 0; l < LAYERS; ++l) {
        size_t oC = (size_t)l * CC;
        float* vptr = (l == 0) ? vfirst : vbuf;

        // ---- weight conversion (mix-folded concats + plain transposes) ----
        CArgs ca;
        ca.e[0]  = {W_r  + (size_t)l * 589824, x_r + oC, Bcat,               768, 768, 768, 1536};
        ca.e[1]  = {W_k  + (size_t)l * 589824, x_k + oC, Bcat + (size_t)768  * 1536, 768, 768, 768, 1536};
        ca.e[2]  = {W_v  + (size_t)l * 589824, x_v + oC, Bcat + (size_t)1536 * 1536, 768, 768, 768, 1536};
        ca.e[3]  = {w1   + (size_t)l * 49152,  x_w + oC, Bcat + (size_t)2304 * 1536, 768, 64, 64, 1536};
        ca.e[4]  = {a1   + (size_t)l * 49152,  x_a + oC, Bcat + (size_t)2368 * 1536, 768, 64, 64, 1536};
        ca.e[5]  = {g1   + (size_t)l * 98304,  x_g + oC, Bcat + (size_t)2432 * 1536, 768, 128, 128, 1536};
        ca.e[6]  = {v1   + (size_t)l * 24576,  x_v + oC, Bcat + (size_t)2560 * 1536, 768, 32, 64, 1536};
        ca.e[7]  = {W_ck + (size_t)l * 2359296, c_x_k + oC, Bck, 768, 3072, 3072, 1536};
        ca.e[8]  = {w2   + (size_t)l * 49152,  nullptr, w2t,   64, 768, 768, 64};
        ca.e[9]  = {a2   + (size_t)l * 49152,  nullptr, a2t,   64, 768, 768, 64};
        ca.e[10] = {v2   + (size_t)l * 24576,  nullptr, v2t,   32, 768, 768, 32};
        ca.e[11] = {g2   + (size_t)l * 98304,  nullptr, g2t,  128, 768, 768, 128};
        ca.e[12] = {W_o  + (size_t)l * 589824, nullptr, Wo_t, 768, 768, 768, 768};
        ca.e[13] = {W_cv + (size_t)l * 2359296, nullptr, Wcv_t, 3072, 768, 768, 3072};
        convert_weights<<<dim3(4608, 14), 256, 0, stream>>>(ca);

        // ---- time mix ----
        ln_shift_kernel<<<MT, 256, 0, stream>>>(xcur, ln1_w + oC, ln1_b + oC, A1);

        EpiArgs e1;
        e1.g[0] = {rbuf,  nullptr, nullptr, nullptr, 0, 768, 768};
        e1.g[1] = {kraw,  nullptr, nullptr, nullptr, 0, 768, 768};
        e1.g[2] = {vptr,  nullptr, nullptr, nullptr, 0, 768, 768};
        e1.g[3] = {nullptr, w1o, nullptr, nullptr, 2, 64, 64};
        e1.g[4] = {nullptr, a1o, nullptr, nullptr, 1, 64, 64};
        e1.g[5] = {nullptr, g1o, nullptr, nullptr, 3, 128, 128};
        e1.g[6] = {nullptr, v1o, nullptr, nullptr, 1, 32, 32};
        int nb1[8] = {0, 768, 1536, 2304, 2368, 2432, 2560, 2624};
        for (int i = 0; i < 8; ++i) e1.nb[i] = nb1[i];
        gemm_multi<128, 64><<<dim3(41, 8), 256, 0, stream>>>((const __bf16*)A1, (const __bf16*)Bcat, 1536, e1);

        G2Args g2a;
        g2a.g[0] = {(const __bf16*)w1o, (const __bf16*)w2t, dbuf, w0 + oC, nullptr, 64, 6};
        g2a.g[1] = {(const __bf16*)a1o, (const __bf16*)a2t, abuf, a0 + oC, nullptr, 64, 7};
        g2a.g[2] = {(const __bf16*)g1o, (const __bf16*)g2t, gbuf, nullptr, nullptr, 128, 0};
        g2a.g[3] = {(const __bf16*)v1o, (const __bf16*)v2t, vbuf, v0 + oC, vfirst, 32, 8};
        gemm_g2<128, 64><<<dim3(12, 8, (l == 0) ? 3 : 4), 256, 0, stream>>>(g2a);

        // ---- chunked scan ----
        chunkA_kernel<<<dim3(NC, BH), 256, 0, stream>>>(rbuf, dbuf, kraw, abuf, vptr,
                                                        k_k + oC, k_a + oC, kupd,
                                                        yintraW, zrW, mmW, zcW);
        chunkB1_kernel<<<BH, 256, 0, stream>>>(mmW, zcW, schkW);
        chunkY_kernel<<<dim3(NC, BH), 256, 0, stream>>>(yintraW, zrW, schkW,
                                                        rbuf, kupd, vptr, gbuf,
                                                        r_k + (size_t)l * 768,
                                                        ln_x_w + oC, ln_x_b + oC, ghout);

        EpiArgs eo;
        eo.g[0] = {xcur, nullptr, nullptr, nullptr, 5, 768, 768};
        eo.nb[0] = 0; for (int i = 1; i < 8; ++i) eo.nb[i] = 1 << 30;
        eo.nb[1] = 768;
        gemm_multi<64, 64><<<dim3(12, 16), 256, 0, stream>>>((const __bf16*)ghout, (const __bf16*)Wo_t, 768, eo);

        // ---- channel mix ----
        ln_shift_kernel<<<MT, 256, 0, stream>>>(xcur, ln2_w + oC, ln2_b + oC, A1);

        EpiArgs ec;
        ec.g[0] = {nullptr, hbuf, nullptr, nullptr, 4, 3072, 3072};
        ec.nb[0] = 0; for (int i = 1; i < 8; ++i) ec.nb[i] = 1 << 30;
        ec.nb[1] = 3072;
        gemm_multi<128, 64><<<dim3(48, 8), 256, 0, stream>>>((const __bf16*)A1, (const __bf16*)Bck, 1536, ec);

        EpiArgs ev;
        ev.g[0] = {xcur, nullptr, nullptr, nullptr, 5, 768, 768};
        ev.nb[0] = 0; for (int i = 1; i < 8; ++i) ev.nb[i] = 1 << 30;
        ev.nb[1] = 768;
        gemm_multi<64, 64><<<dim3(12, 16), 256, 0, stream>>>((const __bf16*)hbuf, (const __bf16*)Wcv_t, 3072, ev);
    }
}

// Round 5
// 1546.054 us; speedup vs baseline: 7.5989x; 1.2456x over previous
//
#include <hip/hip_runtime.h>
#include <hip/hip_bf16.h>
#include <math.h>

#define LAYERS 6
#define BBATCH 2
#define TT 512
#define CC 768
#define HH 12
#define MT (BBATCH*TT)      // 1024 tokens
#define FF (4*CC)           // 3072
#define LCH 32
#define NC (TT/LCH)         // 16 chunks
#define BH (BBATCH*HH)      // 24
#define SPAD 65

typedef __hip_bfloat16 bf16;
typedef __bf16 bf16x8 __attribute__((ext_vector_type(8)));
typedef float f32x4 __attribute__((ext_vector_type(4)));

__device__ inline bf16 f2b(float f) { return __float2bfloat16(f); }

// ---------------- utility ----------------

__global__ __launch_bounds__(256) void copy_f(float* __restrict__ dst, const float* __restrict__ src) {
    size_t i = (size_t)blockIdx.x * 256 + threadIdx.x;
    dst[i] = src[i];
}

// ---------------- fused layernorm + token-shift-diff, bf16 concat output ----------------

__global__ __launch_bounds__(256) void ln_shift_kernel(const float* __restrict__ x,
                                                       const float* __restrict__ w,
                                                       const float* __restrict__ b,
                                                       bf16* __restrict__ out) {
    int row = blockIdx.x;
    int t = row % TT;
    const float* xr = x + (size_t)row * CC;
    const float* xp = xr - CC;
    int tid = threadIdx.x;
    float c0 = xr[tid], c1 = xr[tid + 256], c2 = xr[tid + 512];
    float p0 = 0.f, p1 = 0.f, p2 = 0.f;
    if (t > 0) { p0 = xp[tid]; p1 = xp[tid + 256]; p2 = xp[tid + 512]; }
    float s  = c0 + c1 + c2, q  = c0 * c0 + c1 * c1 + c2 * c2;
    float sp = p0 + p1 + p2, qp = p0 * p0 + p1 * p1 + p2 * p2;
    for (int m = 1; m < 64; m <<= 1) {
        s += __shfl_xor(s, m); q += __shfl_xor(q, m);
        sp += __shfl_xor(sp, m); qp += __shfl_xor(qp, m);
    }
    __shared__ float rs[4], rq[4], rsp[4], rqp[4];
    int wid = tid >> 6;
    if ((tid & 63) == 0) { rs[wid] = s; rq[wid] = q; rsp[wid] = sp; rqp[wid] = qp; }
    __syncthreads();
    s  = rs[0] + rs[1] + rs[2] + rs[3];   q  = rq[0] + rq[1] + rq[2] + rq[3];
    sp = rsp[0] + rsp[1] + rsp[2] + rsp[3]; qp = rqp[0] + rqp[1] + rqp[2] + rqp[3];
    float meanC = s * (1.f / CC);
    float invC  = rsqrtf(q * (1.f / CC) - meanC * meanC + 1e-5f);
    float meanP = sp * (1.f / CC);
    float invP  = rsqrtf(qp * (1.f / CC) - meanP * meanP + 1e-5f);
    bf16* orow = out + (size_t)row * 1536;
    float cv[3] = {c0, c1, c2};
    float pv[3] = {p0, p1, p2};
#pragma unroll
    for (int j = 0; j < 3; ++j) {
        int cc = tid + j * 256;
        float lnc = (cv[j] - meanC) * invC * w[cc] + b[cc];
        float lnp = (t > 0) ? (pv[j] - meanP) * invP * w[cc] + b[cc] : 0.f;
        orow[cc] = f2b(lnc);
        orow[768 + cc] = f2b(lnp - lnc);
    }
}

// ---------------- weight convert (packed 1D grid) ----------------

struct CEntry { const float* W; const float* mix; bf16* dst; int Ksrc, Nsrc, Npad, Kdst, bstart; };
struct CArgs { CEntry e[14]; };

__global__ __launch_bounds__(256) void convert_weights(CArgs ca) {
    int bid = blockIdx.x;
    int idx = 0;
#pragma unroll
    for (int i = 1; i < 14; ++i) if (bid >= ca.e[i].bstart) idx = i;
    CEntry E = ca.e[idx];
    int t = bid - E.bstart;
    int ntN = E.Npad >> 5;
    int tn = (t % ntN) * 32, tk = (t / ntN) * 32;
    __shared__ float tile[32][33];
    int c = threadIdx.x & 31, r0 = threadIdx.x >> 5;
    int ks = tk;
    const float* mixp = nullptr;
    if (tk >= E.Ksrc) { ks = tk - E.Ksrc; mixp = E.mix; }
#pragma unroll
    for (int i = 0; i < 4; ++i) {
        int r = r0 + i * 8;
        float v = (tn + c < E.Nsrc) ? E.W[(size_t)(ks + r) * E.Nsrc + tn + c] : 0.f;
        if (mixp) v *= mixp[ks + r];
        tile[r][c] = v;
    }
    __syncthreads();
#pragma unroll
    for (int i = 0; i < 4; ++i) {
        int r = r0 + i * 8;
        E.dst[(size_t)(tn + r) * E.Kdst + tk + c] = f2b(tile[c][r]);
    }
}

// ---------------- epilogues ----------------

struct EpiG {
    float* outF; bf16* outH;
    const float* p1; const float* p2;
    int epi, ld, ntrue;
};
struct EpiArgs { EpiG g[7]; int nb[8]; };

__device__ inline void epi_store(const EpiG& E, size_t idx, int lc, float v) {
    switch (E.epi) {
        case 0: E.outF[idx] = v; break;
        case 1: E.outH[idx] = f2b(v); break;
        case 2: E.outH[idx] = f2b(tanhf(v)); break;
        case 3: E.outH[idx] = f2b(1.f / (1.f + expf(-v))); break;
        case 4: { float t = fmaxf(v, 0.f); E.outH[idx] = f2b(t * t); } break;
        case 5: E.outF[idx] += v; break;
        case 6: { float z = E.p1[lc] + v; float nz = -z;
                  float sp = (nz > 20.f) ? nz : log1pf(expf(nz));
                  E.outF[idx] = expf(-expf(-sp - 0.5f)); } break;
        case 7: E.outF[idx] = 1.f / (1.f + expf(-(E.p1[lc] + v))); break;
        case 8: { float vv = E.outF[idx];
                  float s = 1.f / (1.f + expf(-(E.p1[lc] + v)));
                  E.outF[idx] = vv + (E.p2[idx] - vv) * s; } break;
    }
}

// ---------------- bf16 MFMA GEMM with grouped-column epilogue ----------------

template<int BM, int BN>
__global__ __launch_bounds__(256) void gemm_multi(const __bf16* __restrict__ A,
                                                  const __bf16* __restrict__ Bt,
                                                  int K, EpiArgs ea) {
    constexpr int FM = BM / 32, FN = BN / 32;
    constexpr int ABYTES = BM * 64;
    constexpr int TOT = (BM + BN) * 64;
    constexpr int NCHUNK = TOT / 4096;
    __shared__ __align__(16) char smem[2][TOT];
    int tid = threadIdx.x;
    int lane = tid & 63, wid = tid >> 6;
    int bm = blockIdx.y * BM, bn = blockIdx.x * BN;
    int wm = (wid >> 1) * (BM / 2), wn = (wid & 1) * (BN / 2);
    f32x4 acc[FM][FN];
#pragma unroll
    for (int i = 0; i < FM; ++i)
#pragma unroll
        for (int j = 0; j < FN; ++j) acc[i][j] = (f32x4){0.f, 0.f, 0.f, 0.f};

    int nk = K >> 5;
    auto stage = [&](int buf, int k0) {
        char* sb = &smem[buf][0];
#pragma unroll
        for (int c = 0; c < NCHUNK; ++c) {
            int d = c * 4096 + tid * 16;
            int isB = d >= ABYTES;
            int dd = isB ? d - ABYTES : d;
            int row = dd >> 6;
            int u = (dd >> 4) & 3;
            int su = u ^ (row & 3);
            const __bf16* src = isB ? (Bt + (size_t)(bn + row) * K + k0 + su * 8)
                                    : (A  + (size_t)(bm + row) * K + k0 + su * 8);
            char* ldst = sb + c * 4096 + (tid & 192) * 16;
            __builtin_amdgcn_global_load_lds(
                (const __attribute__((address_space(1))) unsigned int*)src,
                (__attribute__((address_space(3))) unsigned int*)ldst, 16, 0, 0);
        }
    };

    stage(0, 0);
    __syncthreads();
    for (int t = 0; t < nk; ++t) {
        if (t + 1 < nk) stage((t + 1) & 1, (t + 1) * 32);
        const char* sA = &smem[t & 1][0];
        const char* sB = &smem[t & 1][ABYTES];
        int u = lane >> 4, r0 = lane & 15;
        bf16x8 af[FM], bfr[FN];
#pragma unroll
        for (int i = 0; i < FM; ++i) {
            int row = wm + i * 16 + r0;
            int su = u ^ (row & 3);
            af[i] = *(const bf16x8*)(sA + row * 64 + su * 16);
        }
#pragma unroll
        for (int j = 0; j < FN; ++j) {
            int row = wn + j * 16 + r0;
            int su = u ^ (row & 3);
            bfr[j] = *(const bf16x8*)(sB + row * 64 + su * 16);
        }
#pragma unroll
        for (int i = 0; i < FM; ++i)
#pragma unroll
            for (int j = 0; j < FN; ++j)
                acc[i][j] = __builtin_amdgcn_mfma_f32_16x16x32_bf16(af[i], bfr[j], acc[i][j], 0, 0, 0);
        __syncthreads();
    }

    int gid = 0;
#pragma unroll 1
    while (bn >= ea.nb[gid + 1]) ++gid;
    EpiG E = ea.g[gid];
    int colBase = ea.nb[gid];
#pragma unroll
    for (int i = 0; i < FM; ++i) {
#pragma unroll
        for (int j = 0; j < FN; ++j) {
#pragma unroll
            for (int q = 0; q < 4; ++q) {
                int gm = bm + wm + i * 16 + (lane >> 4) * 4 + q;
                int lc = bn + wn + j * 16 + (lane & 15) - colBase;
                if (lc < E.ntrue)
                    epi_store(E, (size_t)gm * E.ld + lc, lc, acc[i][j][q]);
            }
        }
    }
}

// ---------------- grouped low-rank GEMM ----------------

struct G2G { const __bf16* A; const __bf16* Bt; float* outF; const float* p1; const float* p2; int K; int epi; };
struct G2Args { G2G g[4]; };

template<int BM, int BN>
__global__ __launch_bounds__(256) void gemm_g2(G2Args ga) {
    G2G G = ga.g[blockIdx.z];
    const __bf16* A = G.A;
    const __bf16* Bt = G.Bt;
    int K = G.K;
    constexpr int FM = BM / 32, FN = BN / 32;
    constexpr int ABYTES = BM * 64;
    constexpr int TOT = (BM + BN) * 64;
    constexpr int NCHUNK = TOT / 4096;
    __shared__ __align__(16) char smem[2][TOT];
    int tid = threadIdx.x;
    int lane = tid & 63, wid = tid >> 6;
    int bm = blockIdx.y * BM, bn = blockIdx.x * BN;
    int wm = (wid >> 1) * (BM / 2), wn = (wid & 1) * (BN / 2);
    f32x4 acc[FM][FN];
#pragma unroll
    for (int i = 0; i < FM; ++i)
#pragma unroll
        for (int j = 0; j < FN; ++j) acc[i][j] = (f32x4){0.f, 0.f, 0.f, 0.f};

    int nk = K >> 5;
    auto stage = [&](int buf, int k0) {
        char* sb = &smem[buf][0];
#pragma unroll
        for (int c = 0; c < NCHUNK; ++c) {
            int d = c * 4096 + tid * 16;
            int isB = d >= ABYTES;
            int dd = isB ? d - ABYTES : d;
            int row = dd >> 6;
            int u = (dd >> 4) & 3;
            int su = u ^ (row & 3);
            const __bf16* src = isB ? (Bt + (size_t)(bn + row) * K + k0 + su * 8)
                                    : (A  + (size_t)(bm + row) * K + k0 + su * 8);
            char* ldst = sb + c * 4096 + (tid & 192) * 16;
            __builtin_amdgcn_global_load_lds(
                (const __attribute__((address_space(1))) unsigned int*)src,
                (__attribute__((address_space(3))) unsigned int*)ldst, 16, 0, 0);
        }
    };

    stage(0, 0);
    __syncthreads();
    for (int t = 0; t < nk; ++t) {
        if (t + 1 < nk) stage((t + 1) & 1, (t + 1) * 32);
        const char* sA = &smem[t & 1][0];
        const char* sB = &smem[t & 1][ABYTES];
        int u = lane >> 4, r0 = lane & 15;
        bf16x8 af[FM], bfr[FN];
#pragma unroll
        for (int i = 0; i < FM; ++i) {
            int row = wm + i * 16 + r0;
            int su = u ^ (row & 3);
            af[i] = *(const bf16x8*)(sA + row * 64 + su * 16);
        }
#pragma unroll
        for (int j = 0; j < FN; ++j) {
            int row = wn + j * 16 + r0;
            int su = u ^ (row & 3);
            bfr[j] = *(const bf16x8*)(sB + row * 64 + su * 16);
        }
#pragma unroll
        for (int i = 0; i < FM; ++i)
#pragma unroll
            for (int j = 0; j < FN; ++j)
                acc[i][j] = __builtin_amdgcn_mfma_f32_16x16x32_bf16(af[i], bfr[j], acc[i][j], 0, 0, 0);
        __syncthreads();
    }

    EpiG E;
    E.outF = G.outF; E.outH = nullptr; E.p1 = G.p1; E.p2 = G.p2;
    E.epi = G.epi; E.ld = 768; E.ntrue = 768;
#pragma unroll
    for (int i = 0; i < FM; ++i) {
#pragma unroll
        for (int j = 0; j < FN; ++j) {
#pragma unroll
            for (int q = 0; q < 4; ++q) {
                int gm = bm + wm + i * 16 + (lane >> 4) * 4 + q;
                int lc = bn + wn + j * 16 + (lane & 15);
                epi_store(E, (size_t)gm * 768 + lc, lc, acc[i][j][q]);
            }
        }
    }
}

// ---------------- chunked WKV7, phase A (register-tiled) ----------------

__global__ __launch_bounds__(256) void chunkA_kernel(
    const float* __restrict__ r, const float* __restrict__ wd,
    const float* __restrict__ kraw, const float* __restrict__ av_,
    const float* __restrict__ v,
    const float* __restrict__ kkw, const float* __restrict__ kaw,
    float* __restrict__ kupd,
    float* __restrict__ yintra, float* __restrict__ zrO,
    float* __restrict__ mmO, float* __restrict__ zcO) {
    int c = blockIdx.x, bh = blockIdx.y;
    int b = bh / HH, h = bh % HH;
    __shared__ float Di[LCH][SPAD];
    __shared__ float Ah[LCH][SPAD];
    __shared__ float Bh[LCH][SPAD];
    __shared__ float Kh[LCH][SPAD];
    __shared__ float Rh[LCH][SPAD];
    __shared__ float Vt[LCH][SPAD];
    __shared__ float Qm[LCH][SPAD];
    __shared__ float Gba[LCH][LCH], Gka[LCH][LCH], Grb[LCH][LCH], Grk[LCH][LCH];
    int tid = threadIdx.x;
    int n = tid & 63, tq = tid >> 6;
    size_t base = ((size_t)(b * TT + c * LCH)) * CC + h * 64 + n;
    int cvec = h * 64 + n;
    float kkwv = kkw[cvec], kawv = kaw[cvec];
#pragma unroll
    for (int e = 0; e < 8; ++e) {
        int t = tq * 8 + e;
        size_t off = base + (size_t)t * CC;
        float kr = kraw[off];
        float aval = av_[off];
        float kk0 = kr * kkwv;
        float ss = kk0 * kk0;
        for (int m = 1; m < 64; m <<= 1) ss += __shfl_xor(ss, m);
        float rinv = 1.f / fmaxf(sqrtf(ss), 1e-12f);
        float kkv = kk0 * rinv;
        float ku = kr * (1.f + (aval - 1.f) * kawv);
        kupd[off] = ku;
        Di[t][n] = wd[off];
        Ah[t][n] = -kkv;
        Bh[t][n] = kkv * aval;
        Kh[t][n] = ku;
        Rh[t][n] = r[off];
        Vt[t][n] = v[off];
    }
    __syncthreads();
    if (tid < 64) {
        float d = 1.f;
        for (int t = 0; t < LCH; ++t) { d *= Di[t][tid]; Di[t][tid] = d; }
    }
    __syncthreads();
#pragma unroll
    for (int e = 0; e < 8; ++e) {
        int t = tq * 8 + e;
        float di = Di[t][n];
        float dp = (t == 0) ? 1.f : Di[t - 1][n];
        float inv = 1.f / di;
        Ah[t][n] *= dp;
        Bh[t][n] *= inv;
        Kh[t][n] *= inv;
        Rh[t][n] *= di;
    }
    __syncthreads();
    // ---- G phase: 2x2 (t,s) tiles, 16 accumulators, 8 reads / 16 FMA per j ----
    {
        int tp = tid >> 4, sp = tid & 15;
        int t0 = 2 * tp, s0 = 2 * sp;
        float gba00 = 0.f, gba01 = 0.f, gba10 = 0.f, gba11 = 0.f;
        float gka00 = 0.f, gka01 = 0.f, gka10 = 0.f, gka11 = 0.f;
        float grb00 = 0.f, grb01 = 0.f, grb10 = 0.f, grb11 = 0.f;
        float grk00 = 0.f, grk01 = 0.f, grk10 = 0.f, grk11 = 0.f;
#pragma unroll 4
        for (int j = 0; j < 64; ++j) {
            float a0 = Ah[t0][j], a1 = Ah[t0 + 1][j];
            float r0 = Rh[t0][j], r1 = Rh[t0 + 1][j];
            float b0 = Bh[s0][j], b1 = Bh[s0 + 1][j];
            float k0 = Kh[s0][j], k1 = Kh[s0 + 1][j];
            gba00 = fmaf(a0, b0, gba00); gba01 = fmaf(a0, b1, gba01);
            gba10 = fmaf(a1, b0, gba10); gba11 = fmaf(a1, b1, gba11);
            gka00 = fmaf(a0, k0, gka00); gka01 = fmaf(a0, k1, gka01);
            gka10 = fmaf(a1, k0, gka10); gka11 = fmaf(a1, k1, gka11);
            grb00 = fmaf(r0, b0, grb00); grb01 = fmaf(r0, b1, grb01);
            grb10 = fmaf(r1, b0, grb10); grb11 = fmaf(r1, b1, grb11);
            grk00 = fmaf(r0, k0, grk00); grk01 = fmaf(r0, k1, grk01);
            grk10 = fmaf(r1, k0, grk10); grk11 = fmaf(r1, k1, grk11);
        }
#pragma unroll
        for (int dt = 0; dt < 2; ++dt) {
            int t = t0 + dt;
#pragma unroll
            for (int ds = 0; ds < 2; ++ds) {
                int s = s0 + ds;
                float vba = dt ? (ds ? gba11 : gba10) : (ds ? gba01 : gba00);
                float vka = dt ? (ds ? gka11 : gka10) : (ds ? gka01 : gka00);
                float vrb = dt ? (ds ? grb11 : grb10) : (ds ? grb01 : grb00);
                float vrk = dt ? (ds ? grk11 : grk10) : (ds ? grk01 : grk00);
                Gba[t][s] = (s < t)  ? vba : 0.f;
                Gka[t][s] = (s < t)  ? vka : 0.f;
                Grb[t][s] = (s <= t) ? vrb : 0.f;
                Grk[t][s] = (s <= t) ? vrk : 0.f;
            }
        }
    }
    __syncthreads();
    // ---- Qm = Gka V (s-outer) ----
    {
        float acc[8];
#pragma unroll
        for (int e = 0; e < 8; ++e) acc[e] = 0.f;
        for (int s = 0; s < LCH; ++s) {
            float vs = Vt[s][n];
#pragma unroll
            for (int e = 0; e < 8; ++e)
                acc[e] = fmaf(Gka[tq * 8 + e][s], vs, acc[e]);
        }
#pragma unroll
        for (int e = 0; e < 8; ++e) Qm[tq * 8 + e][n] = acc[e];
    }
    __syncthreads();
    // ---- forward substitution (wave0: U in Ah, wave1: Q in Qm) ----
    if (tq == 0) {
        for (int t = 1; t < LCH; ++t) {
            float acc = Ah[t][n];
            for (int s = 0; s < t; ++s) acc = fmaf(Gba[t][s], Ah[s][n], acc);
            Ah[t][n] = acc;
        }
    } else if (tq == 1) {
        for (int t = 1; t < LCH; ++t) {
            float acc = Qm[t][n];
            for (int s = 0; s < t; ++s) acc = fmaf(Gba[t][s], Qm[s][n], acc);
            Qm[t][n] = acc;
        }
    }
    __syncthreads();
    float dL_n = Di[LCH - 1][n];
    size_t obase = ((size_t)(bh * NC + c)) * LCH * 64;
    // ---- yintra / zr (s-outer) ----
    {
        float accY[8], accZ[8];
#pragma unroll
        for (int e = 0; e < 8; ++e) { accY[e] = 0.f; accZ[e] = Rh[tq * 8 + e][n]; }
        for (int s = 0; s < LCH; ++s) {
            float vs = Vt[s][n], qs = Qm[s][n], us = Ah[s][n];
#pragma unroll
            for (int e = 0; e < 8; ++e) {
                int t = tq * 8 + e;
                float grk_ = Grk[t][s], grb_ = Grb[t][s];
                accY[e] = fmaf(grk_, vs, fmaf(grb_, qs, accY[e]));
                accZ[e] = fmaf(grb_, us, accZ[e]);
            }
        }
#pragma unroll
        for (int e = 0; e < 8; ++e) {
            int t = tq * 8 + e;
            yintra[obase + t * 64 + n] = accY[e];
            zrO[obase + t * 64 + n] = accZ[e];
        }
    }
    // ---- M / Zc (4x4 (p,n) tiles, s-outer) ----
    {
        int pi = tid >> 4, ni = tid & 15;
        float accM[4][4], accZc[4][4];
#pragma unroll
        for (int dp = 0; dp < 4; ++dp)
#pragma unroll
            for (int dn = 0; dn < 4; ++dn) { accM[dp][dn] = 0.f; accZc[dp][dn] = 0.f; }
        for (int s = 0; s < LCH; ++s) {
            float aa[4], vv[4], qq[4], bb[4], kk[4];
#pragma unroll
            for (int d = 0; d < 4; ++d) {
                aa[d] = Ah[s][4 * pi + d];
                vv[d] = Vt[s][4 * pi + d];
                qq[d] = Qm[s][4 * pi + d];
                bb[d] = Bh[s][4 * ni + d];
                kk[d] = Kh[s][4 * ni + d];
            }
#pragma unroll
            for (int dp = 0; dp < 4; ++dp)
#pragma unroll
                for (int dn = 0; dn < 4; ++dn) {
                    accM[dp][dn]  = fmaf(aa[dp], bb[dn], accM[dp][dn]);
                    accZc[dp][dn] = fmaf(vv[dp], kk[dn], fmaf(qq[dp], bb[dn], accZc[dp][dn]));
                }
        }
        size_t mbase = ((size_t)(bh * NC + c)) * 4096;
        float dl[4];
#pragma unroll
        for (int dn = 0; dn < 4; ++dn) dl[dn] = Di[LCH - 1][4 * ni + dn];
#pragma unroll
        for (int dp = 0; dp < 4; ++dp) {
            int p = 4 * pi + dp;
            f32x4 m4, z4;
#pragma unroll
            for (int dn = 0; dn < 4; ++dn) {
                int nn = 4 * ni + dn;
                float mm = accM[dp][dn] + ((p == nn) ? 1.f : 0.f);
                m4[dn] = dl[dn] * mm;
                z4[dn] = dl[dn] * accZc[dp][dn];
            }
            *(f32x4*)(mmO + mbase + p * 64 + 4 * ni) = m4;
            *(f32x4*)(zcO + mbase + p * 64 + 4 * ni) = z4;
        }
    }
}

// ---------------- phase B1: sequential state chain (unchanged) ----------------

__global__ __launch_bounds__(256) void chunkB1_kernel(const float* __restrict__ mm,
                                                      const float* __restrict__ zc,
                                                      float* __restrict__ schk) {
    int bh = blockIdx.x;
    int tid = threadIdx.x;
    int i4 = tid >> 4, j4 = tid & 15;
    __shared__ float S[64][SPAD];
    __shared__ __align__(16) float Mb[2][64][64];
#pragma unroll
    for (int e = 0; e < 16; ++e) {
        int idx = tid + e * 256;
        S[idx >> 6][idx & 63] = 0.f;
    }
    const float* mbase = mm + (size_t)bh * NC * 4096;
    const float* zbase = zc + (size_t)bh * NC * 4096;
    float* sbase = schk + (size_t)bh * NC * 4096;
#pragma unroll
    for (int s = 0; s < 4; ++s) {
        __builtin_amdgcn_global_load_lds(
            (const __attribute__((address_space(1))) unsigned int*)(mbase + s * 1024 + tid * 4),
            (__attribute__((address_space(3))) unsigned int*)((char*)&Mb[0][0][0] + s * 4096 + (tid & 192) * 16),
            16, 0, 0);
    }
    f32x4 zcur[4], znxt[4];
#pragma unroll
    for (int d = 0; d < 4; ++d)
        zcur[d] = *(const f32x4*)(zbase + (i4 * 4 + d) * 64 + j4 * 4);
    __syncthreads();
#pragma unroll 1
    for (int c = 0; c < NC - 1; ++c) {
        int cb = c & 1;
        if (c < NC - 2) {
#pragma unroll
            for (int s = 0; s < 4; ++s) {
                __builtin_amdgcn_global_load_lds(
                    (const __attribute__((address_space(1))) unsigned int*)(mbase + (size_t)(c + 1) * 4096 + s * 1024 + tid * 4),
                    (__attribute__((address_space(3))) unsigned int*)((char*)&Mb[cb ^ 1][0][0] + s * 4096 + (tid & 192) * 16),
                    16, 0, 0);
            }
#pragma unroll
            for (int d = 0; d < 4; ++d)
                znxt[d] = *(const f32x4*)(zbase + (size_t)(c + 1) * 4096 + (i4 * 4 + d) * 64 + j4 * 4);
        }
        f32x4 acc0 = zcur[0], acc1 = zcur[1], acc2 = zcur[2], acc3 = zcur[3];
        for (int p = 0; p < 64; ++p) {
            f32x4 mrow = *(const f32x4*)&Mb[cb][p][j4 * 4];
            float s0 = S[i4 * 4 + 0][p];
            float s1 = S[i4 * 4 + 1][p];
            float s2 = S[i4 * 4 + 2][p];
            float s3 = S[i4 * 4 + 3][p];
#pragma unroll
            for (int u = 0; u < 4; ++u) {
                acc0[u] = fmaf(s0, mrow[u], acc0[u]);
                acc1[u] = fmaf(s1, mrow[u], acc1[u]);
                acc2[u] = fmaf(s2, mrow[u], acc2[u]);
                acc3[u] = fmaf(s3, mrow[u], acc3[u]);
            }
        }
        __syncthreads();
        float* cp = sbase + (size_t)(c + 1) * 4096;
#pragma unroll
        for (int u = 0; u < 4; ++u) {
            S[i4 * 4 + 0][j4 * 4 + u] = acc0[u];
            S[i4 * 4 + 1][j4 * 4 + u] = acc1[u];
            S[i4 * 4 + 2][j4 * 4 + u] = acc2[u];
            S[i4 * 4 + 3][j4 * 4 + u] = acc3[u];
        }
        *(f32x4*)(cp + (i4 * 4 + 0) * 64 + j4 * 4) = acc0;
        *(f32x4*)(cp + (i4 * 4 + 1) * 64 + j4 * 4) = acc1;
        *(f32x4*)(cp + (i4 * 4 + 2) * 64 + j4 * 4) = acc2;
        *(f32x4*)(cp + (i4 * 4 + 3) * 64 + j4 * 4) = acc3;
#pragma unroll
        for (int d = 0; d < 4; ++d) zcur[d] = znxt[d];
        __syncthreads();
    }
}

// ---------------- phase Y (unchanged) ----------------

__global__ __launch_bounds__(256) void chunkY_kernel(
    const float* __restrict__ yintra, const float* __restrict__ zrI,
    const float* __restrict__ schk,
    const float* __restrict__ r, const float* __restrict__ kupd,
    const float* __restrict__ v, const float* __restrict__ g,
    const float* __restrict__ rk, const float* __restrict__ lw,
    const float* __restrict__ lb, bf16* __restrict__ out) {
    int c = blockIdx.x, bh = blockIdx.y;
    int b = bh / HH, h = bh % HH;
    __shared__ float Y[LCH][SPAD];
    __shared__ float Zr[LCH][SPAD];
    __shared__ float Sh[64][SPAD];
    int tid = threadIdx.x;
    int n = tid & 63, tq = tid >> 6;
    size_t obase = ((size_t)(bh * NC + c)) * LCH * 64;
#pragma unroll
    for (int e = 0; e < 8; ++e) {
        int idx = tid + e * 256;
        int row = idx >> 6, col = idx & 63;
        Y[row][col] = yintra[obase + idx];
        Zr[row][col] = zrI[obase + idx];
    }
    if (c > 0) {
        size_t sbase = ((size_t)(bh * NC + c)) * 4096;
#pragma unroll
        for (int e = 0; e < 16; ++e) {
            int idx = tid + e * 256;
            Sh[idx >> 6][idx & 63] = schk[sbase + idx];
        }
    }
    __syncthreads();
    if (c > 0) {
        float acc[8];
#pragma unroll
        for (int e = 0; e < 8; ++e) acc[e] = 0.f;
        for (int p = 0; p < 64; ++p) {
            float sv = Sh[n][p];
#pragma unroll
            for (int e = 0; e < 8; ++e)
                acc[e] = fmaf(Zr[tq * 8 + e][p], sv, acc[e]);
        }
#pragma unroll
        for (int e = 0; e < 8; ++e) Y[tq * 8 + e][n] += acc[e];
    }
    size_t rowbase = ((size_t)(b * TT + c * LCH)) * CC + h * 64 + n;
    float rkv = rk[h * 64 + n];
    float lwv = lw[h * 64 + n], lbv = lb[h * 64 + n];
#pragma unroll
    for (int e = 0; e < 8; ++e) {
        int t = tq * 8 + e;
        size_t off = rowbase + (size_t)t * CC;
        float yv = Y[t][n];
        float rv = r[off], kv = kupd[off], vv = v[off];
        float s1 = yv, s2 = yv * yv, s3 = rv * kv * rkv;
        for (int m = 1; m < 64; m <<= 1) {
            s1 += __shfl_xor(s1, m);
            s2 += __shfl_xor(s2, m);
            s3 += __shfl_xor(s3, m);
        }
        float mean = s1 * (1.f / 64.f);
        float var  = s2 * (1.f / 64.f) - mean * mean;
        float inv  = rsqrtf(var + 64e-5f);
        float val  = (yv - mean) * inv * lwv + lbv + s3 * vv;
        out[off] = f2b(val * g[off]);
    }
}

// ---------------- host ----------------

extern "C" void kernel_launch(void* const* d_in, const int* in_sizes, int n_in,
                              void* d_out, int out_size, void* d_ws, size_t ws_size,
                              hipStream_t stream) {
    (void)in_sizes; (void)n_in; (void)out_size;
    const float* x    = (const float*)d_in[0];
    const float* x_r  = (const float*)d_in[1];
    const float* x_w  = (const float*)d_in[2];
    const float* x_k  = (const float*)d_in[3];
    const float* x_v  = (const float*)d_in[4];
    const float* x_a  = (const float*)d_in[5];
    const float* x_g  = (const float*)d_in[6];
    const float* w0   = (const float*)d_in[7];
    const float* w1   = (const float*)d_in[8];
    const float* w2   = (const float*)d_in[9];
    const float* a0   = (const float*)d_in[10];
    const float* a1   = (const float*)d_in[11];
    const float* a2   = (const float*)d_in[12];
    const float* v0   = (const float*)d_in[13];
    const float* v1   = (const float*)d_in[14];
    const float* v2   = (const float*)d_in[15];
    const float* g1   = (const float*)d_in[16];
    const float* g2   = (const float*)d_in[17];
    const float* k_k  = (const float*)d_in[18];
    const float* k_a  = (const float*)d_in[19];
    const float* r_k  = (const float*)d_in[20];
    const float* W_r  = (const float*)d_in[21];
    const float* W_k  = (const float*)d_in[22];
    const float* W_v  = (const float*)d_in[23];
    const float* W_o  = (const float*)d_in[24];
    const float* ln_x_w = (const float*)d_in[25];
    const float* ln_x_b = (const float*)d_in[26];
    const float* ln1_w  = (const float*)d_in[27];
    const float* ln1_b  = (const float*)d_in[28];
    const float* ln2_w  = (const float*)d_in[29];
    const float* ln2_b  = (const float*)d_in[30];
    const float* c_x_k  = (const float*)d_in[31];
    const float* W_ck   = (const float*)d_in[32];
    const float* W_cv   = (const float*)d_in[33];

    const size_t MC = (size_t)MT * CC;
    char* wsb = (char*)d_ws;
    size_t woff = 0;
    auto alloc = [&](size_t bytes) -> void* {
        void* p = wsb + woff;
        woff += (bytes + 255) & ~(size_t)255;
        return p;
    };
    bf16* Bcat  = (bf16*)alloc((size_t)2624 * 1536 * 2);
    bf16* Bck   = (bf16*)alloc((size_t)3072 * 1536 * 2);
    bf16* w2t   = (bf16*)alloc((size_t)768 * 64 * 2);
    bf16* a2t   = (bf16*)alloc((size_t)768 * 64 * 2);
    bf16* v2t   = (bf16*)alloc((size_t)768 * 32 * 2);
    bf16* g2t   = (bf16*)alloc((size_t)768 * 128 * 2);
    bf16* Wo_t  = (bf16*)alloc((size_t)768 * 768 * 2);
    bf16* Wcv_t = (bf16*)alloc((size_t)768 * 3072 * 2);
    bf16* A1    = (bf16*)alloc((size_t)MT * 1536 * 2);
    float* rbuf  = (float*)alloc(MC * 4);
    float* kraw  = (float*)alloc(MC * 4);
    float* kupd  = (float*)alloc(MC * 4);
    float* vbuf  = (float*)alloc(MC * 4);
    float* vfirst= (float*)alloc(MC * 4);
    float* abuf  = (float*)alloc(MC * 4);
    float* dbuf  = (float*)alloc(MC * 4);
    float* gbuf  = (float*)alloc(MC * 4);
    bf16* w1o   = (bf16*)alloc((size_t)MT * 64 * 2);
    bf16* a1o   = (bf16*)alloc((size_t)MT * 64 * 2);
    bf16* v1o   = (bf16*)alloc((size_t)MT * 32 * 2);
    bf16* g1o   = (bf16*)alloc((size_t)MT * 128 * 2);
    bf16* hbuf  = (bf16*)alloc((size_t)MT * FF * 2);
    bf16* ghout = (bf16*)alloc(MC * 2);
    float* yintraW = (float*)alloc((size_t)BH * NC * LCH * 64 * 4);
    float* zrW     = (float*)alloc((size_t)BH * NC * LCH * 64 * 4);
    float* mmW     = (float*)alloc((size_t)BH * NC * 4096 * 4);
    float* zcW     = (float*)alloc((size_t)BH * NC * 4096 * 4);
    float* schkW   = (float*)alloc((size_t)BH * NC * 4096 * 4);
    if (woff > ws_size) return;

    float* xcur = (float*)d_out;
    copy_f<<<MC / 256, 256, 0, stream>>>(xcur, x);

    for (int l = 0; l < LAYERS; ++l) {
        size_t oC = (size_t)l * CC;
        float* vptr = (l == 0) ? vfirst : vbuf;

        CArgs ca;
        ca.e[0]  = {W_r  + (size_t)l * 589824, x_r + oC, Bcat,               768, 768, 768, 1536, 0};
        ca.e[1]  = {W_k  + (size_t)l * 589824, x_k + oC, Bcat + (size_t)768  * 1536, 768, 768, 768, 1536, 0};
        ca.e[2]  = {W_v  + (size_t)l * 589824, x_v + oC, Bcat + (size_t)1536 * 1536, 768, 768, 768, 1536, 0};
        ca.e[3]  = {w1   + (size_t)l * 49152,  x_w + oC, Bcat + (size_t)2304 * 1536, 768, 64, 64, 1536, 0};
        ca.e[4]  = {a1   + (size_t)l * 49152,  x_a + oC, Bcat + (size_t)2368 * 1536, 768, 64, 64, 1536, 0};
        ca.e[5]  = {g1   + (size_t)l * 98304,  x_g + oC, Bcat + (size_t)2432 * 1536, 768, 128, 128, 1536, 0};
        ca.e[6]  = {v1   + (size_t)l * 24576,  x_v + oC, Bcat + (size_t)2560 * 1536, 768, 32, 64, 1536, 0};
        ca.e[7]  = {W_ck + (size_t)l * 2359296, c_x_k + oC, Bck, 768, 3072, 3072, 1536, 0};
        ca.e[8]  = {w2   + (size_t)l * 49152,  nullptr, w2t,   64, 768, 768, 64, 0};
        ca.e[9]  = {a2   + (size_t)l * 49152,  nullptr, a2t,   64, 768, 768, 64, 0};
        ca.e[10] = {v2   + (size_t)l * 24576,  nullptr, v2t,   32, 768, 768, 32, 0};
        ca.e[11] = {g2   + (size_t)l * 98304,  nullptr, g2t,  128, 768, 768, 128, 0};
        ca.e[12] = {W_o  + (size_t)l * 589824, nullptr, Wo_t, 768, 768, 768, 768, 0};
        ca.e[13] = {W_cv + (size_t)l * 2359296, nullptr, Wcv_t, 3072, 768, 768, 3072, 0};
        int btot = 0;
        for (int i = 0; i < 14; ++i) {
            ca.e[i].bstart = btot;
            btot += (ca.e[i].Npad >> 5) * (ca.e[i].Kdst >> 5);
        }
        convert_weights<<<btot, 256, 0, stream>>>(ca);

        // ---- time mix ----
        ln_shift_kernel<<<MT, 256, 0, stream>>>(xcur, ln1_w + oC, ln1_b + oC, A1);

        EpiArgs e1;
        e1.g[0] = {rbuf,  nullptr, nullptr, nullptr, 0, 768, 768};
        e1.g[1] = {kraw,  nullptr, nullptr, nullptr, 0, 768, 768};
        e1.g[2] = {vptr,  nullptr, nullptr, nullptr, 0, 768, 768};
        e1.g[3] = {nullptr, w1o, nullptr, nullptr, 2, 64, 64};
        e1.g[4] = {nullptr, a1o, nullptr, nullptr, 1, 64, 64};
        e1.g[5] = {nullptr, g1o, nullptr, nullptr, 3, 128, 128};
        e1.g[6] = {nullptr, v1o, nullptr, nullptr, 1, 32, 32};
        int nb1[8] = {0, 768, 1536, 2304, 2368, 2432, 2560, 2624};
        for (int i = 0; i < 8; ++i) e1.nb[i] = nb1[i];
        gemm_multi<128, 64><<<dim3(41, 8), 256, 0, stream>>>((const __bf16*)A1, (const __bf16*)Bcat, 1536, e1);

        G2Args g2a;
        g2a.g[0] = {(const __bf16*)w1o, (const __bf16*)w2t, dbuf, w0 + oC, nullptr, 64, 6};
        g2a.g[1] = {(const __bf16*)a1o, (const __bf16*)a2t, abuf, a0 + oC, nullptr, 64, 7};
        g2a.g[2] = {(const __bf16*)g1o, (const __bf16*)g2t, gbuf, nullptr, nullptr, 128, 0};
        g2a.g[3] = {(const __bf16*)v1o, (const __bf16*)v2t, vbuf, v0 + oC, vfirst, 32, 8};
        gemm_g2<128, 64><<<dim3(12, 8, (l == 0) ? 3 : 4), 256, 0, stream>>>(g2a);

        // ---- chunked scan ----
        chunkA_kernel<<<dim3(NC, BH), 256, 0, stream>>>(rbuf, dbuf, kraw, abuf, vptr,
                                                        k_k + oC, k_a + oC, kupd,
                                                        yintraW, zrW, mmW, zcW);
        chunkB1_kernel<<<BH, 256, 0, stream>>>(mmW, zcW, schkW);
        chunkY_kernel<<<dim3(NC, BH), 256, 0, stream>>>(yintraW, zrW, schkW,
                                                        rbuf, kupd, vptr, gbuf,
                                                        r_k + (size_t)l * 768,
                                                        ln_x_w + oC, ln_x_b + oC, ghout);

        EpiArgs eo;
        eo.g[0] = {xcur, nullptr, nullptr, nullptr, 5, 768, 768};
        eo.nb[0] = 0; for (int i = 1; i < 8; ++i) eo.nb[i] = 1 << 30;
        eo.nb[1] = 768;
        gemm_multi<64, 64><<<dim3(12, 16), 256, 0, stream>>>((const __bf16*)ghout, (const __bf16*)Wo_t, 768, eo);

        // ---- channel mix ----
        ln_shift_kernel<<<MT, 256, 0, stream>>>(xcur, ln2_w + oC, ln2_b + oC, A1);

        EpiArgs ec;
        ec.g[0] = {nullptr, hbuf, nullptr, nullptr, 4, 3072, 3072};
        ec.nb[0] = 0; for (int i = 1; i < 8; ++i) ec.nb[i] = 1 << 30;
        ec.nb[1] = 3072;
        gemm_multi<128, 64><<<dim3(48, 8), 256, 0, stream>>>((const __bf16*)A1, (const __bf16*)Bck, 1536, ec);

        EpiArgs ev;
        ev.g[0] = {xcur, nullptr, nullptr, nullptr, 5, 768, 768};
        ev.nb[0] = 0; for (int i = 1; i < 8; ++i) ev.nb[i] = 1 << 30;
        ev.nb[1] = 768;
        gemm_multi<64, 64><<<dim3(12, 16), 256, 0, stream>>>((const __bf16*)hbuf, (const __bf16*)Wcv_t, 3072, ev);
    }
}

// Round 6
// 1506.218 us; speedup vs baseline: 7.7998x; 1.0264x over previous
//
#include <hip/hip_runtime.h>
#include <hip/hip_bf16.h>
#include <math.h>

#define LAYERS 6
#define BBATCH 2
#define TT 512
#define CC 768
#define HH 12
#define MT (BBATCH*TT)      // 1024 tokens
#define FF (4*CC)           // 3072
#define LCH 32
#define NC (TT/LCH)         // 16 chunks
#define BH (BBATCH*HH)      // 24
#define SPAD 65
#define BPAD 68             // f32x4-aligned padded stride for chunkB1 S

typedef __hip_bfloat16 bf16;
typedef __bf16 bf16x8 __attribute__((ext_vector_type(8)));
typedef float f32x4 __attribute__((ext_vector_type(4)));

__device__ inline bf16 f2b(float f) { return __float2bfloat16(f); }

// ---------------- utility ----------------

__global__ __launch_bounds__(256) void copy_f(float* __restrict__ dst, const float* __restrict__ src) {
    size_t i = (size_t)blockIdx.x * 256 + threadIdx.x;
    dst[i] = src[i];
}

// ---------------- fused layernorm + token-shift-diff, bf16 concat output ----------------

__global__ __launch_bounds__(256) void ln_shift_kernel(const float* __restrict__ x,
                                                       const float* __restrict__ w,
                                                       const float* __restrict__ b,
                                                       bf16* __restrict__ out) {
    int row = blockIdx.x;
    int t = row % TT;
    const float* xr = x + (size_t)row * CC;
    const float* xp = xr - CC;
    int tid = threadIdx.x;
    float c0 = xr[tid], c1 = xr[tid + 256], c2 = xr[tid + 512];
    float p0 = 0.f, p1 = 0.f, p2 = 0.f;
    if (t > 0) { p0 = xp[tid]; p1 = xp[tid + 256]; p2 = xp[tid + 512]; }
    float s  = c0 + c1 + c2, q  = c0 * c0 + c1 * c1 + c2 * c2;
    float sp = p0 + p1 + p2, qp = p0 * p0 + p1 * p1 + p2 * p2;
    for (int m = 1; m < 64; m <<= 1) {
        s += __shfl_xor(s, m); q += __shfl_xor(q, m);
        sp += __shfl_xor(sp, m); qp += __shfl_xor(qp, m);
    }
    __shared__ float rs[4], rq[4], rsp[4], rqp[4];
    int wid = tid >> 6;
    if ((tid & 63) == 0) { rs[wid] = s; rq[wid] = q; rsp[wid] = sp; rqp[wid] = qp; }
    __syncthreads();
    s  = rs[0] + rs[1] + rs[2] + rs[3];   q  = rq[0] + rq[1] + rq[2] + rq[3];
    sp = rsp[0] + rsp[1] + rsp[2] + rsp[3]; qp = rqp[0] + rqp[1] + rqp[2] + rqp[3];
    float meanC = s * (1.f / CC);
    float invC  = rsqrtf(q * (1.f / CC) - meanC * meanC + 1e-5f);
    float meanP = sp * (1.f / CC);
    float invP  = rsqrtf(qp * (1.f / CC) - meanP * meanP + 1e-5f);
    bf16* orow = out + (size_t)row * 1536;
    float cv[3] = {c0, c1, c2};
    float pv[3] = {p0, p1, p2};
#pragma unroll
    for (int j = 0; j < 3; ++j) {
        int cc = tid + j * 256;
        float lnc = (cv[j] - meanC) * invC * w[cc] + b[cc];
        float lnp = (t > 0) ? (pv[j] - meanP) * invP * w[cc] + b[cc] : 0.f;
        orow[cc] = f2b(lnc);
        orow[768 + cc] = f2b(lnp - lnc);
    }
}

// ---------------- weight convert (packed 1D grid) ----------------

struct CEntry { const float* W; const float* mix; bf16* dst; int Ksrc, Nsrc, Npad, Kdst, bstart; };
struct CArgs { CEntry e[14]; };

__global__ __launch_bounds__(256) void convert_weights(CArgs ca) {
    int bid = blockIdx.x;
    int idx = 0;
#pragma unroll
    for (int i = 1; i < 14; ++i) if (bid >= ca.e[i].bstart) idx = i;
    CEntry E = ca.e[idx];
    int t = bid - E.bstart;
    int ntN = E.Npad >> 5;
    int tn = (t % ntN) * 32, tk = (t / ntN) * 32;
    __shared__ float tile[32][33];
    int c = threadIdx.x & 31, r0 = threadIdx.x >> 5;
    int ks = tk;
    const float* mixp = nullptr;
    if (tk >= E.Ksrc) { ks = tk - E.Ksrc; mixp = E.mix; }
#pragma unroll
    for (int i = 0; i < 4; ++i) {
        int r = r0 + i * 8;
        float v = (tn + c < E.Nsrc) ? E.W[(size_t)(ks + r) * E.Nsrc + tn + c] : 0.f;
        if (mixp) v *= mixp[ks + r];
        tile[r][c] = v;
    }
    __syncthreads();
#pragma unroll
    for (int i = 0; i < 4; ++i) {
        int r = r0 + i * 8;
        E.dst[(size_t)(tn + r) * E.Kdst + tk + c] = f2b(tile[c][r]);
    }
}

// ---------------- epilogues ----------------

struct EpiG {
    float* outF; bf16* outH;
    const float* p1; const float* p2;
    int epi, ld, ntrue;
};
struct EpiArgs { EpiG g[7]; int nb[8]; };

__device__ inline void epi_store(const EpiG& E, size_t idx, int lc, float v) {
    switch (E.epi) {
        case 0: E.outF[idx] = v; break;
        case 1: E.outH[idx] = f2b(v); break;
        case 2: E.outH[idx] = f2b(tanhf(v)); break;
        case 3: E.outH[idx] = f2b(1.f / (1.f + expf(-v))); break;
        case 4: { float t = fmaxf(v, 0.f); E.outH[idx] = f2b(t * t); } break;
        case 5: E.outF[idx] += v; break;
        case 6: { float z = E.p1[lc] + v; float nz = -z;
                  float sp = (nz > 20.f) ? nz : log1pf(expf(nz));
                  E.outF[idx] = expf(-expf(-sp - 0.5f)); } break;
        case 7: E.outF[idx] = 1.f / (1.f + expf(-(E.p1[lc] + v))); break;
        case 8: { float vv = E.outF[idx];
                  float s = 1.f / (1.f + expf(-(E.p1[lc] + v)));
                  E.outF[idx] = vv + (E.p2[idx] - vv) * s; } break;
    }
}

// ---------------- bf16 MFMA GEMM with grouped-column epilogue ----------------

template<int BM, int BN>
__global__ __launch_bounds__(256) void gemm_multi(const __bf16* __restrict__ A,
                                                  const __bf16* __restrict__ Bt,
                                                  int K, EpiArgs ea) {
    constexpr int FM = BM / 32, FN = BN / 32;
    constexpr int ABYTES = BM * 64;
    constexpr int TOT = (BM + BN) * 64;
    constexpr int NCHUNK = TOT / 4096;
    __shared__ __align__(16) char smem[2][TOT];
    int tid = threadIdx.x;
    int lane = tid & 63, wid = tid >> 6;
    int bm = blockIdx.y * BM, bn = blockIdx.x * BN;
    int wm = (wid >> 1) * (BM / 2), wn = (wid & 1) * (BN / 2);
    f32x4 acc[FM][FN];
#pragma unroll
    for (int i = 0; i < FM; ++i)
#pragma unroll
        for (int j = 0; j < FN; ++j) acc[i][j] = (f32x4){0.f, 0.f, 0.f, 0.f};

    int nk = K >> 5;
    auto stage = [&](int buf, int k0) {
        char* sb = &smem[buf][0];
#pragma unroll
        for (int c = 0; c < NCHUNK; ++c) {
            int d = c * 4096 + tid * 16;
            int isB = d >= ABYTES;
            int dd = isB ? d - ABYTES : d;
            int row = dd >> 6;
            int u = (dd >> 4) & 3;
            int su = u ^ (row & 3);
            const __bf16* src = isB ? (Bt + (size_t)(bn + row) * K + k0 + su * 8)
                                    : (A  + (size_t)(bm + row) * K + k0 + su * 8);
            char* ldst = sb + c * 4096 + (tid & 192) * 16;
            __builtin_amdgcn_global_load_lds(
                (const __attribute__((address_space(1))) unsigned int*)src,
                (__attribute__((address_space(3))) unsigned int*)ldst, 16, 0, 0);
        }
    };

    stage(0, 0);
    __syncthreads();
    for (int t = 0; t < nk; ++t) {
        if (t + 1 < nk) stage((t + 1) & 1, (t + 1) * 32);
        const char* sA = &smem[t & 1][0];
        const char* sB = &smem[t & 1][ABYTES];
        int u = lane >> 4, r0 = lane & 15;
        bf16x8 af[FM], bfr[FN];
#pragma unroll
        for (int i = 0; i < FM; ++i) {
            int row = wm + i * 16 + r0;
            int su = u ^ (row & 3);
            af[i] = *(const bf16x8*)(sA + row * 64 + su * 16);
        }
#pragma unroll
        for (int j = 0; j < FN; ++j) {
            int row = wn + j * 16 + r0;
            int su = u ^ (row & 3);
            bfr[j] = *(const bf16x8*)(sB + row * 64 + su * 16);
        }
#pragma unroll
        for (int i = 0; i < FM; ++i)
#pragma unroll
            for (int j = 0; j < FN; ++j)
                acc[i][j] = __builtin_amdgcn_mfma_f32_16x16x32_bf16(af[i], bfr[j], acc[i][j], 0, 0, 0);
        __syncthreads();
    }

    int gid = 0;
#pragma unroll 1
    while (bn >= ea.nb[gid + 1]) ++gid;
    EpiG E = ea.g[gid];
    int colBase = ea.nb[gid];
#pragma unroll
    for (int i = 0; i < FM; ++i) {
#pragma unroll
        for (int j = 0; j < FN; ++j) {
#pragma unroll
            for (int q = 0; q < 4; ++q) {
                int gm = bm + wm + i * 16 + (lane >> 4) * 4 + q;
                int lc = bn + wn + j * 16 + (lane & 15) - colBase;
                if (lc < E.ntrue)
                    epi_store(E, (size_t)gm * E.ld + lc, lc, acc[i][j][q]);
            }
        }
    }
}

// ---------------- grouped low-rank GEMM ----------------

struct G2G { const __bf16* A; const __bf16* Bt; float* outF; const float* p1; const float* p2; int K; int epi; };
struct G2Args { G2G g[4]; };

template<int BM, int BN>
__global__ __launch_bounds__(256) void gemm_g2(G2Args ga) {
    G2G G = ga.g[blockIdx.z];
    const __bf16* A = G.A;
    const __bf16* Bt = G.Bt;
    int K = G.K;
    constexpr int FM = BM / 32, FN = BN / 32;
    constexpr int ABYTES = BM * 64;
    constexpr int TOT = (BM + BN) * 64;
    constexpr int NCHUNK = TOT / 4096;
    __shared__ __align__(16) char smem[2][TOT];
    int tid = threadIdx.x;
    int lane = tid & 63, wid = tid >> 6;
    int bm = blockIdx.y * BM, bn = blockIdx.x * BN;
    int wm = (wid >> 1) * (BM / 2), wn = (wid & 1) * (BN / 2);
    f32x4 acc[FM][FN];
#pragma unroll
    for (int i = 0; i < FM; ++i)
#pragma unroll
        for (int j = 0; j < FN; ++j) acc[i][j] = (f32x4){0.f, 0.f, 0.f, 0.f};

    int nk = K >> 5;
    auto stage = [&](int buf, int k0) {
        char* sb = &smem[buf][0];
#pragma unroll
        for (int c = 0; c < NCHUNK; ++c) {
            int d = c * 4096 + tid * 16;
            int isB = d >= ABYTES;
            int dd = isB ? d - ABYTES : d;
            int row = dd >> 6;
            int u = (dd >> 4) & 3;
            int su = u ^ (row & 3);
            const __bf16* src = isB ? (Bt + (size_t)(bn + row) * K + k0 + su * 8)
                                    : (A  + (size_t)(bm + row) * K + k0 + su * 8);
            char* ldst = sb + c * 4096 + (tid & 192) * 16;
            __builtin_amdgcn_global_load_lds(
                (const __attribute__((address_space(1))) unsigned int*)src,
                (__attribute__((address_space(3))) unsigned int*)ldst, 16, 0, 0);
        }
    };

    stage(0, 0);
    __syncthreads();
    for (int t = 0; t < nk; ++t) {
        if (t + 1 < nk) stage((t + 1) & 1, (t + 1) * 32);
        const char* sA = &smem[t & 1][0];
        const char* sB = &smem[t & 1][ABYTES];
        int u = lane >> 4, r0 = lane & 15;
        bf16x8 af[FM], bfr[FN];
#pragma unroll
        for (int i = 0; i < FM; ++i) {
            int row = wm + i * 16 + r0;
            int su = u ^ (row & 3);
            af[i] = *(const bf16x8*)(sA + row * 64 + su * 16);
        }
#pragma unroll
        for (int j = 0; j < FN; ++j) {
            int row = wn + j * 16 + r0;
            int su = u ^ (row & 3);
            bfr[j] = *(const bf16x8*)(sB + row * 64 + su * 16);
        }
#pragma unroll
        for (int i = 0; i < FM; ++i)
#pragma unroll
            for (int j = 0; j < FN; ++j)
                acc[i][j] = __builtin_amdgcn_mfma_f32_16x16x32_bf16(af[i], bfr[j], acc[i][j], 0, 0, 0);
        __syncthreads();
    }

    EpiG E;
    E.outF = G.outF; E.outH = nullptr; E.p1 = G.p1; E.p2 = G.p2;
    E.epi = G.epi; E.ld = 768; E.ntrue = 768;
#pragma unroll
    for (int i = 0; i < FM; ++i) {
#pragma unroll
        for (int j = 0; j < FN; ++j) {
#pragma unroll
            for (int q = 0; q < 4; ++q) {
                int gm = bm + wm + i * 16 + (lane >> 4) * 4 + q;
                int lc = bn + wn + j * 16 + (lane & 15);
                epi_store(E, (size_t)gm * 768 + lc, lc, acc[i][j][q]);
            }
        }
    }
}

// ---------------- chunked WKV7, phase A (register-tiled) ----------------

__global__ __launch_bounds__(256) void chunkA_kernel(
    const float* __restrict__ r, const float* __restrict__ wd,
    const float* __restrict__ kraw, const float* __restrict__ av_,
    const float* __restrict__ v,
    const float* __restrict__ kkw, const float* __restrict__ kaw,
    float* __restrict__ kupd,
    float* __restrict__ yintra, float* __restrict__ zrO,
    float* __restrict__ mmO, float* __restrict__ zcO) {
    int c = blockIdx.x, bh = blockIdx.y;
    int b = bh / HH, h = bh % HH;
    __shared__ float Di[LCH][SPAD];
    __shared__ float Ah[LCH][SPAD];
    __shared__ float Bh[LCH][SPAD];
    __shared__ float Kh[LCH][SPAD];
    __shared__ float Rh[LCH][SPAD];
    __shared__ float Vt[LCH][SPAD];
    __shared__ float Qm[LCH][SPAD];
    __shared__ float Gba[LCH][LCH], Gka[LCH][LCH], Grb[LCH][LCH], Grk[LCH][LCH];
    int tid = threadIdx.x;
    int n = tid & 63, tq = tid >> 6;
    size_t base = ((size_t)(b * TT + c * LCH)) * CC + h * 64 + n;
    int cvec = h * 64 + n;
    float kkwv = kkw[cvec], kawv = kaw[cvec];
#pragma unroll
    for (int e = 0; e < 8; ++e) {
        int t = tq * 8 + e;
        size_t off = base + (size_t)t * CC;
        float kr = kraw[off];
        float aval = av_[off];
        float kk0 = kr * kkwv;
        float ss = kk0 * kk0;
        for (int m = 1; m < 64; m <<= 1) ss += __shfl_xor(ss, m);
        float rinv = 1.f / fmaxf(sqrtf(ss), 1e-12f);
        float kkv = kk0 * rinv;
        float ku = kr * (1.f + (aval - 1.f) * kawv);
        kupd[off] = ku;
        Di[t][n] = wd[off];
        Ah[t][n] = -kkv;
        Bh[t][n] = kkv * aval;
        Kh[t][n] = ku;
        Rh[t][n] = r[off];
        Vt[t][n] = v[off];
    }
    __syncthreads();
    if (tid < 64) {
        float d = 1.f;
        for (int t = 0; t < LCH; ++t) { d *= Di[t][tid]; Di[t][tid] = d; }
    }
    __syncthreads();
#pragma unroll
    for (int e = 0; e < 8; ++e) {
        int t = tq * 8 + e;
        float di = Di[t][n];
        float dp = (t == 0) ? 1.f : Di[t - 1][n];
        float inv = 1.f / di;
        Ah[t][n] *= dp;
        Bh[t][n] *= inv;
        Kh[t][n] *= inv;
        Rh[t][n] *= di;
    }
    __syncthreads();
    // ---- G phase: 2x2 (t,s) tiles ----
    {
        int tp = tid >> 4, sp = tid & 15;
        int t0 = 2 * tp, s0 = 2 * sp;
        float gba00 = 0.f, gba01 = 0.f, gba10 = 0.f, gba11 = 0.f;
        float gka00 = 0.f, gka01 = 0.f, gka10 = 0.f, gka11 = 0.f;
        float grb00 = 0.f, grb01 = 0.f, grb10 = 0.f, grb11 = 0.f;
        float grk00 = 0.f, grk01 = 0.f, grk10 = 0.f, grk11 = 0.f;
#pragma unroll 4
        for (int j = 0; j < 64; ++j) {
            float a0 = Ah[t0][j], a1 = Ah[t0 + 1][j];
            float r0 = Rh[t0][j], r1 = Rh[t0 + 1][j];
            float b0 = Bh[s0][j], b1 = Bh[s0 + 1][j];
            float k0 = Kh[s0][j], k1 = Kh[s0 + 1][j];
            gba00 = fmaf(a0, b0, gba00); gba01 = fmaf(a0, b1, gba01);
            gba10 = fmaf(a1, b0, gba10); gba11 = fmaf(a1, b1, gba11);
            gka00 = fmaf(a0, k0, gka00); gka01 = fmaf(a0, k1, gka01);
            gka10 = fmaf(a1, k0, gka10); gka11 = fmaf(a1, k1, gka11);
            grb00 = fmaf(r0, b0, grb00); grb01 = fmaf(r0, b1, grb01);
            grb10 = fmaf(r1, b0, grb10); grb11 = fmaf(r1, b1, grb11);
            grk00 = fmaf(r0, k0, grk00); grk01 = fmaf(r0, k1, grk01);
            grk10 = fmaf(r1, k0, grk10); grk11 = fmaf(r1, k1, grk11);
        }
#pragma unroll
        for (int dt = 0; dt < 2; ++dt) {
            int t = t0 + dt;
#pragma unroll
            for (int ds = 0; ds < 2; ++ds) {
                int s = s0 + ds;
                float vba = dt ? (ds ? gba11 : gba10) : (ds ? gba01 : gba00);
                float vka = dt ? (ds ? gka11 : gka10) : (ds ? gka01 : gka00);
                float vrb = dt ? (ds ? grb11 : grb10) : (ds ? grb01 : grb00);
                float vrk = dt ? (ds ? grk11 : grk10) : (ds ? grk01 : grk00);
                Gba[t][s] = (s < t)  ? vba : 0.f;
                Gka[t][s] = (s < t)  ? vka : 0.f;
                Grb[t][s] = (s <= t) ? vrb : 0.f;
                Grk[t][s] = (s <= t) ? vrk : 0.f;
            }
        }
    }
    __syncthreads();
    // ---- Qm = Gka V (s-outer) ----
    {
        float acc[8];
#pragma unroll
        for (int e = 0; e < 8; ++e) acc[e] = 0.f;
        for (int s = 0; s < LCH; ++s) {
            float vs = Vt[s][n];
#pragma unroll
            for (int e = 0; e < 8; ++e)
                acc[e] = fmaf(Gka[tq * 8 + e][s], vs, acc[e]);
        }
#pragma unroll
        for (int e = 0; e < 8; ++e) Qm[tq * 8 + e][n] = acc[e];
    }
    __syncthreads();
    // ---- forward substitution ----
    if (tq == 0) {
        for (int t = 1; t < LCH; ++t) {
            float acc = Ah[t][n];
            for (int s = 0; s < t; ++s) acc = fmaf(Gba[t][s], Ah[s][n], acc);
            Ah[t][n] = acc;
        }
    } else if (tq == 1) {
        for (int t = 1; t < LCH; ++t) {
            float acc = Qm[t][n];
            for (int s = 0; s < t; ++s) acc = fmaf(Gba[t][s], Qm[s][n], acc);
            Qm[t][n] = acc;
        }
    }
    __syncthreads();
    float dL_n = Di[LCH - 1][n];
    size_t obase = ((size_t)(bh * NC + c)) * LCH * 64;
    // ---- yintra / zr (s-outer) ----
    {
        float accY[8], accZ[8];
#pragma unroll
        for (int e = 0; e < 8; ++e) { accY[e] = 0.f; accZ[e] = Rh[tq * 8 + e][n]; }
        for (int s = 0; s < LCH; ++s) {
            float vs = Vt[s][n], qs = Qm[s][n], us = Ah[s][n];
#pragma unroll
            for (int e = 0; e < 8; ++e) {
                int t = tq * 8 + e;
                float grk_ = Grk[t][s], grb_ = Grb[t][s];
                accY[e] = fmaf(grk_, vs, fmaf(grb_, qs, accY[e]));
                accZ[e] = fmaf(grb_, us, accZ[e]);
            }
        }
#pragma unroll
        for (int e = 0; e < 8; ++e) {
            int t = tq * 8 + e;
            yintra[obase + t * 64 + n] = accY[e];
            zrO[obase + t * 64 + n] = accZ[e];
        }
    }
    // ---- M / Zc (4x4 tiles, s-outer) ----
    {
        int pi = tid >> 4, ni = tid & 15;
        float accM[4][4], accZc[4][4];
#pragma unroll
        for (int dp = 0; dp < 4; ++dp)
#pragma unroll
            for (int dn = 0; dn < 4; ++dn) { accM[dp][dn] = 0.f; accZc[dp][dn] = 0.f; }
        for (int s = 0; s < LCH; ++s) {
            float aa[4], vv[4], qq[4], bb[4], kk[4];
#pragma unroll
            for (int d = 0; d < 4; ++d) {
                aa[d] = Ah[s][4 * pi + d];
                vv[d] = Vt[s][4 * pi + d];
                qq[d] = Qm[s][4 * pi + d];
                bb[d] = Bh[s][4 * ni + d];
                kk[d] = Kh[s][4 * ni + d];
            }
#pragma unroll
            for (int dp = 0; dp < 4; ++dp)
#pragma unroll
                for (int dn = 0; dn < 4; ++dn) {
                    accM[dp][dn]  = fmaf(aa[dp], bb[dn], accM[dp][dn]);
                    accZc[dp][dn] = fmaf(vv[dp], kk[dn], fmaf(qq[dp], bb[dn], accZc[dp][dn]));
                }
        }
        size_t mbase = ((size_t)(bh * NC + c)) * 4096;
        float dl[4];
#pragma unroll
        for (int dn = 0; dn < 4; ++dn) dl[dn] = Di[LCH - 1][4 * ni + dn];
#pragma unroll
        for (int dp = 0; dp < 4; ++dp) {
            int p = 4 * pi + dp;
            f32x4 m4, z4;
#pragma unroll
            for (int dn = 0; dn < 4; ++dn) {
                int nn = 4 * ni + dn;
                float mm = accM[dp][dn] + ((p == nn) ? 1.f : 0.f);
                m4[dn] = dl[dn] * mm;
                z4[dn] = dl[dn] * accZc[dp][dn];
            }
            *(f32x4*)(mmO + mbase + p * 64 + 4 * ni) = m4;
            *(f32x4*)(zcO + mbase + p * 64 + 4 * ni) = z4;
        }
    }
}

// ---------------- phase B1: sequential state chain (512 threads, vectorized) ----------------
// Thread tile: rows {i2*2, i2*2+1} (i2 = tid>>4), cols j4*4..+3 (j4 = tid&15).
// S in LDS [64][BPAD] (16B-aligned rows, conflict-free); M double-buffered via global_load_lds.

__global__ __launch_bounds__(512) void chunkB1_kernel(const float* __restrict__ mm,
                                                      const float* __restrict__ zc,
                                                      float* __restrict__ schk) {
    int bh = blockIdx.x;
    int tid = threadIdx.x;
    int i2 = tid >> 4, j4 = tid & 15;
    int r0 = i2 * 2;
    __shared__ __align__(16) float S[64][BPAD];
    __shared__ __align__(16) float Mb[2][64][64];
    for (int idx = tid; idx < 64 * BPAD; idx += 512)
        (&S[0][0])[idx] = 0.f;
    const float* mbase = mm + (size_t)bh * NC * 4096;
    const float* zbase = zc + (size_t)bh * NC * 4096;
    float* sbase = schk + (size_t)bh * NC * 4096;
    // stage M_0 into buffer 0: 512 threads x 16B x 2 passes
#pragma unroll
    for (int s = 0; s < 2; ++s) {
        __builtin_amdgcn_global_load_lds(
            (const __attribute__((address_space(1))) unsigned int*)(mbase + s * 2048 + tid * 4),
            (__attribute__((address_space(3))) unsigned int*)((char*)&Mb[0][0][0] + s * 8192 + (tid & ~63) * 16),
            16, 0, 0);
    }
    f32x4 zcur0 = *(const f32x4*)(zbase + (r0 + 0) * 64 + j4 * 4);
    f32x4 zcur1 = *(const f32x4*)(zbase + (r0 + 1) * 64 + j4 * 4);
    f32x4 znxt0, znxt1;
    __syncthreads();
#pragma unroll 1
    for (int c = 0; c < NC - 1; ++c) {
        int cb = c & 1;
        if (c < NC - 2) {
#pragma unroll
            for (int s = 0; s < 2; ++s) {
                __builtin_amdgcn_global_load_lds(
                    (const __attribute__((address_space(1))) unsigned int*)(mbase + (size_t)(c + 1) * 4096 + s * 2048 + tid * 4),
                    (__attribute__((address_space(3))) unsigned int*)((char*)&Mb[cb ^ 1][0][0] + s * 8192 + (tid & ~63) * 16),
                    16, 0, 0);
            }
            znxt0 = *(const f32x4*)(zbase + (size_t)(c + 1) * 4096 + (r0 + 0) * 64 + j4 * 4);
            znxt1 = *(const f32x4*)(zbase + (size_t)(c + 1) * 4096 + (r0 + 1) * 64 + j4 * 4);
        }
        f32x4 acc0 = zcur0, acc1 = zcur1;
#pragma unroll 4
        for (int p0 = 0; p0 < 64; p0 += 4) {
            f32x4 sa = *(const f32x4*)&S[r0 + 0][p0];
            f32x4 sb = *(const f32x4*)&S[r0 + 1][p0];
            f32x4 m0 = *(const f32x4*)&Mb[cb][p0 + 0][j4 * 4];
            f32x4 m1 = *(const f32x4*)&Mb[cb][p0 + 1][j4 * 4];
            f32x4 m2 = *(const f32x4*)&Mb[cb][p0 + 2][j4 * 4];
            f32x4 m3 = *(const f32x4*)&Mb[cb][p0 + 3][j4 * 4];
#pragma unroll
            for (int u = 0; u < 4; ++u) {
                acc0[u] = fmaf(sa[0], m0[u], acc0[u]);
                acc0[u] = fmaf(sa[1], m1[u], acc0[u]);
                acc0[u] = fmaf(sa[2], m2[u], acc0[u]);
                acc0[u] = fmaf(sa[3], m3[u], acc0[u]);
                acc1[u] = fmaf(sb[0], m0[u], acc1[u]);
                acc1[u] = fmaf(sb[1], m1[u], acc1[u]);
                acc1[u] = fmaf(sb[2], m2[u], acc1[u]);
                acc1[u] = fmaf(sb[3], m3[u], acc1[u]);
            }
        }
        __syncthreads();   // all reads of S done
        *(f32x4*)&S[r0 + 0][j4 * 4] = acc0;
        *(f32x4*)&S[r0 + 1][j4 * 4] = acc1;
        float* cp = sbase + (size_t)(c + 1) * 4096;
        *(f32x4*)(cp + (r0 + 0) * 64 + j4 * 4) = acc0;
        *(f32x4*)(cp + (r0 + 1) * 64 + j4 * 4) = acc1;
        zcur0 = znxt0; zcur1 = znxt1;
        __syncthreads();   // S visible + M buffer ready before next chunk
    }
}

// ---------------- phase Y (unchanged) ----------------

__global__ __launch_bounds__(256) void chunkY_kernel(
    const float* __restrict__ yintra, const float* __restrict__ zrI,
    const float* __restrict__ schk,
    const float* __restrict__ r, const float* __restrict__ kupd,
    const float* __restrict__ v, const float* __restrict__ g,
    const float* __restrict__ rk, const float* __restrict__ lw,
    const float* __restrict__ lb, bf16* __restrict__ out) {
    int c = blockIdx.x, bh = blockIdx.y;
    int b = bh / HH, h = bh % HH;
    __shared__ float Y[LCH][SPAD];
    __shared__ float Zr[LCH][SPAD];
    __shared__ float Sh[64][SPAD];
    int tid = threadIdx.x;
    int n = tid & 63, tq = tid >> 6;
    size_t obase = ((size_t)(bh * NC + c)) * LCH * 64;
#pragma unroll
    for (int e = 0; e < 8; ++e) {
        int idx = tid + e * 256;
        int row = idx >> 6, col = idx & 63;
        Y[row][col] = yintra[obase + idx];
        Zr[row][col] = zrI[obase + idx];
    }
    if (c > 0) {
        size_t sbase = ((size_t)(bh * NC + c)) * 4096;
#pragma unroll
        for (int e = 0; e < 16; ++e) {
            int idx = tid + e * 256;
            Sh[idx >> 6][idx & 63] = schk[sbase + idx];
        }
    }
    __syncthreads();
    if (c > 0) {
        float acc[8];
#pragma unroll
        for (int e = 0; e < 8; ++e) acc[e] = 0.f;
        for (int p = 0; p < 64; ++p) {
            float sv = Sh[n][p];
#pragma unroll
            for (int e = 0; e < 8; ++e)
                acc[e] = fmaf(Zr[tq * 8 + e][p], sv, acc[e]);
        }
#pragma unroll
        for (int e = 0; e < 8; ++e) Y[tq * 8 + e][n] += acc[e];
    }
    size_t rowbase = ((size_t)(b * TT + c * LCH)) * CC + h * 64 + n;
    float rkv = rk[h * 64 + n];
    float lwv = lw[h * 64 + n], lbv = lb[h * 64 + n];
#pragma unroll
    for (int e = 0; e < 8; ++e) {
        int t = tq * 8 + e;
        size_t off = rowbase + (size_t)t * CC;
        float yv = Y[t][n];
        float rv = r[off], kv = kupd[off], vv = v[off];
        float s1 = yv, s2 = yv * yv, s3 = rv * kv * rkv;
        for (int m = 1; m < 64; m <<= 1) {
            s1 += __shfl_xor(s1, m);
            s2 += __shfl_xor(s2, m);
            s3 += __shfl_xor(s3, m);
        }
        float mean = s1 * (1.f / 64.f);
        float var  = s2 * (1.f / 64.f) - mean * mean;
        float inv  = rsqrtf(var + 64e-5f);
        float val  = (yv - mean) * inv * lwv + lbv + s3 * vv;
        out[off] = f2b(val * g[off]);
    }
}

// ---------------- host ----------------

extern "C" void kernel_launch(void* const* d_in, const int* in_sizes, int n_in,
                              void* d_out, int out_size, void* d_ws, size_t ws_size,
                              hipStream_t stream) {
    (void)in_sizes; (void)n_in; (void)out_size;
    const float* x    = (const float*)d_in[0];
    const float* x_r  = (const float*)d_in[1];
    const float* x_w  = (const float*)d_in[2];
    const float* x_k  = (const float*)d_in[3];
    const float* x_v  = (const float*)d_in[4];
    const float* x_a  = (const float*)d_in[5];
    const float* x_g  = (const float*)d_in[6];
    const float* w0   = (const float*)d_in[7];
    const float* w1   = (const float*)d_in[8];
    const float* w2   = (const float*)d_in[9];
    const float* a0   = (const float*)d_in[10];
    const float* a1   = (const float*)d_in[11];
    const float* a2   = (const float*)d_in[12];
    const float* v0   = (const float*)d_in[13];
    const float* v1   = (const float*)d_in[14];
    const float* v2   = (const float*)d_in[15];
    const float* g1   = (const float*)d_in[16];
    const float* g2   = (const float*)d_in[17];
    const float* k_k  = (const float*)d_in[18];
    const float* k_a  = (const float*)d_in[19];
    const float* r_k  = (const float*)d_in[20];
    const float* W_r  = (const float*)d_in[21];
    const float* W_k  = (const float*)d_in[22];
    const float* W_v  = (const float*)d_in[23];
    const float* W_o  = (const float*)d_in[24];
    const float* ln_x_w = (const float*)d_in[25];
    const float* ln_x_b = (const float*)d_in[26];
    const float* ln1_w  = (const float*)d_in[27];
    const float* ln1_b  = (const float*)d_in[28];
    const float* ln2_w  = (const float*)d_in[29];
    const float* ln2_b  = (const float*)d_in[30];
    const float* c_x_k  = (const float*)d_in[31];
    const float* W_ck   = (const float*)d_in[32];
    const float* W_cv   = (const float*)d_in[33];

    const size_t MC = (size_t)MT * CC;
    char* wsb = (char*)d_ws;
    size_t woff = 0;
    auto alloc = [&](size_t bytes) -> void* {
        void* p = wsb + woff;
        woff += (bytes + 255) & ~(size_t)255;
        return p;
    };
    bf16* Bcat  = (bf16*)alloc((size_t)2624 * 1536 * 2);
    bf16* Bck   = (bf16*)alloc((size_t)3072 * 1536 * 2);
    bf16* w2t   = (bf16*)alloc((size_t)768 * 64 * 2);
    bf16* a2t   = (bf16*)alloc((size_t)768 * 64 * 2);
    bf16* v2t   = (bf16*)alloc((size_t)768 * 32 * 2);
    bf16* g2t   = (bf16*)alloc((size_t)768 * 128 * 2);
    bf16* Wo_t  = (bf16*)alloc((size_t)768 * 768 * 2);
    bf16* Wcv_t = (bf16*)alloc((size_t)768 * 3072 * 2);
    bf16* A1    = (bf16*)alloc((size_t)MT * 1536 * 2);
    float* rbuf  = (float*)alloc(MC * 4);
    float* kraw  = (float*)alloc(MC * 4);
    float* kupd  = (float*)alloc(MC * 4);
    float* vbuf  = (float*)alloc(MC * 4);
    float* vfirst= (float*)alloc(MC * 4);
    float* abuf  = (float*)alloc(MC * 4);
    float* dbuf  = (float*)alloc(MC * 4);
    float* gbuf  = (float*)alloc(MC * 4);
    bf16* w1o   = (bf16*)alloc((size_t)MT * 64 * 2);
    bf16* a1o   = (bf16*)alloc((size_t)MT * 64 * 2);
    bf16* v1o   = (bf16*)alloc((size_t)MT * 32 * 2);
    bf16* g1o   = (bf16*)alloc((size_t)MT * 128 * 2);
    bf16* hbuf  = (bf16*)alloc((size_t)MT * FF * 2);
    bf16* ghout = (bf16*)alloc(MC * 2);
    float* yintraW = (float*)alloc((size_t)BH * NC * LCH * 64 * 4);
    float* zrW     = (float*)alloc((size_t)BH * NC * LCH * 64 * 4);
    float* mmW     = (float*)alloc((size_t)BH * NC * 4096 * 4);
    float* zcW     = (float*)alloc((size_t)BH * NC * 4096 * 4);
    float* schkW   = (float*)alloc((size_t)BH * NC * 4096 * 4);
    if (woff > ws_size) return;

    float* xcur = (float*)d_out;
    copy_f<<<MC / 256, 256, 0, stream>>>(xcur, x);

    for (int l = 0; l < LAYERS; ++l) {
        size_t oC = (size_t)l * CC;
        float* vptr = (l == 0) ? vfirst : vbuf;

        CArgs ca;
        ca.e[0]  = {W_r  + (size_t)l * 589824, x_r + oC, Bcat,               768, 768, 768, 1536, 0};
        ca.e[1]  = {W_k  + (size_t)l * 589824, x_k + oC, Bcat + (size_t)768  * 1536, 768, 768, 768, 1536, 0};
        ca.e[2]  = {W_v  + (size_t)l * 589824, x_v + oC, Bcat + (size_t)1536 * 1536, 768, 768, 768, 1536, 0};
        ca.e[3]  = {w1   + (size_t)l * 49152,  x_w + oC, Bcat + (size_t)2304 * 1536, 768, 64, 64, 1536, 0};
        ca.e[4]  = {a1   + (size_t)l * 49152,  x_a + oC, Bcat + (size_t)2368 * 1536, 768, 64, 64, 1536, 0};
        ca.e[5]  = {g1   + (size_t)l * 98304,  x_g + oC, Bcat + (size_t)2432 * 1536, 768, 128, 128, 1536, 0};
        ca.e[6]  = {v1   + (size_t)l * 24576,  x_v + oC, Bcat + (size_t)2560 * 1536, 768, 32, 64, 1536, 0};
        ca.e[7]  = {W_ck + (size_t)l * 2359296, c_x_k + oC, Bck, 768, 3072, 3072, 1536, 0};
        ca.e[8]  = {w2   + (size_t)l * 49152,  nullptr, w2t,   64, 768, 768, 64, 0};
        ca.e[9]  = {a2   + (size_t)l * 49152,  nullptr, a2t,   64, 768, 768, 64, 0};
        ca.e[10] = {v2   + (size_t)l * 24576,  nullptr, v2t,   32, 768, 768, 32, 0};
        ca.e[11] = {g2   + (size_t)l * 98304,  nullptr, g2t,  128, 768, 768, 128, 0};
        ca.e[12] = {W_o  + (size_t)l * 589824, nullptr, Wo_t, 768, 768, 768, 768, 0};
        ca.e[13] = {W_cv + (size_t)l * 2359296, nullptr, Wcv_t, 3072, 768, 768, 3072, 0};
        int btot = 0;
        for (int i = 0; i < 14; ++i) {
            ca.e[i].bstart = btot;
            btot += (ca.e[i].Npad >> 5) * (ca.e[i].Kdst >> 5);
        }
        convert_weights<<<btot, 256, 0, stream>>>(ca);

        // ---- time mix ----
        ln_shift_kernel<<<MT, 256, 0, stream>>>(xcur, ln1_w + oC, ln1_b + oC, A1);

        EpiArgs e1;
        e1.g[0] = {rbuf,  nullptr, nullptr, nullptr, 0, 768, 768};
        e1.g[1] = {kraw,  nullptr, nullptr, nullptr, 0, 768, 768};
        e1.g[2] = {vptr,  nullptr, nullptr, nullptr, 0, 768, 768};
        e1.g[3] = {nullptr, w1o, nullptr, nullptr, 2, 64, 64};
        e1.g[4] = {nullptr, a1o, nullptr, nullptr, 1, 64, 64};
        e1.g[5] = {nullptr, g1o, nullptr, nullptr, 3, 128, 128};
        e1.g[6] = {nullptr, v1o, nullptr, nullptr, 1, 32, 32};
        int nb1[8] = {0, 768, 1536, 2304, 2368, 2432, 2560, 2624};
        for (int i = 0; i < 8; ++i) e1.nb[i] = nb1[i];
        gemm_multi<128, 64><<<dim3(41, 8), 256, 0, stream>>>((const __bf16*)A1, (const __bf16*)Bcat, 1536, e1);

        G2Args g2a;
        g2a.g[0] = {(const __bf16*)w1o, (const __bf16*)w2t, dbuf, w0 + oC, nullptr, 64, 6};
        g2a.g[1] = {(const __bf16*)a1o, (const __bf16*)a2t, abuf, a0 + oC, nullptr, 64, 7};
        g2a.g[2] = {(const __bf16*)g1o, (const __bf16*)g2t, gbuf, nullptr, nullptr, 128, 0};
        g2a.g[3] = {(const __bf16*)v1o, (const __bf16*)v2t, vbuf, v0 + oC, vfirst, 32, 8};
        gemm_g2<128, 64><<<dim3(12, 8, (l == 0) ? 3 : 4), 256, 0, stream>>>(g2a);

        // ---- chunked scan ----
        chunkA_kernel<<<dim3(NC, BH), 256, 0, stream>>>(rbuf, dbuf, kraw, abuf, vptr,
                                                        k_k + oC, k_a + oC, kupd,
                                                        yintraW, zrW, mmW, zcW);
        chunkB1_kernel<<<BH, 512, 0, stream>>>(mmW, zcW, schkW);
        chunkY_kernel<<<dim3(NC, BH), 256, 0, stream>>>(yintraW, zrW, schkW,
                                                        rbuf, kupd, vptr, gbuf,
                                                        r_k + (size_t)l * 768,
                                                        ln_x_w + oC, ln_x_b + oC, ghout);

        EpiArgs eo;
        eo.g[0] = {xcur, nullptr, nullptr, nullptr, 5, 768, 768};
        eo.nb[0] = 0; for (int i = 1; i < 8; ++i) eo.nb[i] = 1 << 30;
        eo.nb[1] = 768;
        gemm_multi<64, 64><<<dim3(12, 16), 256, 0, stream>>>((const __bf16*)ghout, (const __bf16*)Wo_t, 768, eo);

        // ---- channel mix ----
        ln_shift_kernel<<<MT, 256, 0, stream>>>(xcur, ln2_w + oC, ln2_b + oC, A1);

        EpiArgs ec;
        ec.g[0] = {nullptr, hbuf, nullptr, nullptr, 4, 3072, 3072};
        ec.nb[0] = 0; for (int i = 1; i < 8; ++i) ec.nb[i] = 1 << 30;
        ec.nb[1] = 3072;
        gemm_multi<128, 64><<<dim3(48, 8), 256, 0, stream>>>((const __bf16*)A1, (const __bf16*)Bck, 1536, ec);

        EpiArgs ev;
        ev.g[0] = {xcur, nullptr, nullptr, nullptr, 5, 768, 768};
        ev.nb[0] = 0; for (int i = 1; i < 8; ++i) ev.nb[i] = 1 << 30;
        ev.nb[1] = 768;
        gemm_multi<64, 64><<<dim3(12, 16), 256, 0, stream>>>((const __bf16*)hbuf, (const __bf16*)Wcv_t, 3072, ev);
    }
}